// Round 1
// baseline (1573.022 us; speedup 1.0000x reference)
//
#include <hip/hip_runtime.h>
#include <math.h>

#define EPS 1e-5f

constexpr int Bb = 128;
constexpr int C  = 256;
constexpr int Nz = 169;   // 13*13
constexpr int Nx = 625;   // 25*25

// ---------------------------------------------------------------------------
// Unified conv1x1 GEMM: Y[b,o,n] = act( sum_c W[o,c]*X(b,c,n) + bias[o] )
// X(c) read from X1 for c<K1, else X2[c-K1] (for the concat in the final conv).
// W: [O,K] row-major. DO_BN=1 applies inference BN + ReLU.
// Tile: 64(o) x 64(n), K-chunks of 16. 256 threads, 4x4 per thread.
// ---------------------------------------------------------------------------
template<int DO_BN>
__global__ __launch_bounds__(256)
void conv_gemm(const float* __restrict__ X1, const float* __restrict__ X2,
               const float* __restrict__ W, const float* __restrict__ bias,
               const float* __restrict__ gamma, const float* __restrict__ beta,
               const float* __restrict__ mean, const float* __restrict__ var,
               float* __restrict__ Y, int N, int K1, int K, int O)
{
    __shared__ float Wt[64][17];   // [o][k], padded
    __shared__ float Xs[16][64];   // [k][n]

    const int b  = blockIdx.z;
    const int n0 = blockIdx.x * 64;
    const int o0 = blockIdx.y * 64;
    const int tid = threadIdx.x;
    const int tx = tid & 15, ty = tid >> 4;

    const float* X1b = X1 + (size_t)b * K1 * N;
    const float* X2b = X2 ? (X2 + (size_t)b * (K - K1) * N) : nullptr;

    float acc[4][4] = {};

    for (int kc = 0; kc < K; kc += 16) {
        #pragma unroll
        for (int i = 0; i < 4; ++i) {
            int e = tid + 256 * i;
            int o = e >> 4, k = e & 15;
            Wt[o][k] = W[(size_t)(o0 + o) * K + (kc + k)];
        }
        #pragma unroll
        for (int i = 0; i < 4; ++i) {
            int e = tid + 256 * i;
            int k = e >> 6, n = e & 63;
            int gk = kc + k, gn = n0 + n;
            float v = 0.f;
            if (gn < N)
                v = (gk < K1) ? X1b[(size_t)gk * N + gn]
                              : X2b[(size_t)(gk - K1) * N + gn];
            Xs[k][n] = v;
        }
        __syncthreads();
        #pragma unroll
        for (int k = 0; k < 16; ++k) {
            float a[4], bv[4];
            #pragma unroll
            for (int i = 0; i < 4; ++i) a[i] = Wt[ty * 4 + i][k];
            #pragma unroll
            for (int j = 0; j < 4; ++j) bv[j] = Xs[k][tx * 4 + j];
            #pragma unroll
            for (int i = 0; i < 4; ++i)
                #pragma unroll
                for (int j = 0; j < 4; ++j)
                    acc[i][j] = fmaf(a[i], bv[j], acc[i][j]);
        }
        __syncthreads();
    }

    float* Yb = Y + (size_t)b * O * N;
    #pragma unroll
    for (int i = 0; i < 4; ++i) {
        int go = o0 + ty * 4 + i;
        float bi = bias[go];
        float inv = 1.f, sh = 0.f;
        if (DO_BN) {
            inv = gamma[go] * rsqrtf(var[go] + EPS);
            sh  = beta[go] - mean[go] * inv;
        }
        #pragma unroll
        for (int j = 0; j < 4; ++j) {
            int gn = n0 + tx * 4 + j;
            if (gn < N) {
                float v = acc[i][j] + bi;
                if (DO_BN) v = fmaxf(fmaf(v, inv, sh), 0.f);
                Yb[(size_t)go * N + gn] = v;
            }
        }
    }
}

// ---------------------------------------------------------------------------
// similar[b,n,m] = sum_c xf_trans[b,c,n] * zf_trans[b,c,m]
// A^T B with A=[C,Nx], B=[C,Nz]. Tile 64(n) x 64(m), K-chunks of 16.
// ---------------------------------------------------------------------------
__global__ __launch_bounds__(256)
void sim_gemm(const float* __restrict__ A, const float* __restrict__ Bz,
              float* __restrict__ S)
{
    __shared__ float At[16][64];   // [c][n]
    __shared__ float Bt[16][64];   // [c][m]

    const int b  = blockIdx.z;
    const int m0 = blockIdx.x * 64;
    const int n0 = blockIdx.y * 64;
    const int tid = threadIdx.x;
    const int tx = tid & 15, ty = tid >> 4;

    const float* Ab = A  + (size_t)b * C * Nx;
    const float* Zb = Bz + (size_t)b * C * Nz;

    float acc[4][4] = {};

    for (int kc = 0; kc < C; kc += 16) {
        #pragma unroll
        for (int i = 0; i < 4; ++i) {
            int e = tid + 256 * i;
            int k = e >> 6, n = e & 63;
            int gn = n0 + n;
            At[k][n] = (gn < Nx) ? Ab[(size_t)(kc + k) * Nx + gn] : 0.f;
            int gm = m0 + n;
            Bt[k][n] = (gm < Nz) ? Zb[(size_t)(kc + k) * Nz + gm] : 0.f;
        }
        __syncthreads();
        #pragma unroll
        for (int k = 0; k < 16; ++k) {
            float a[4], bv[4];
            #pragma unroll
            for (int i = 0; i < 4; ++i) a[i] = At[k][ty * 4 + i];
            #pragma unroll
            for (int j = 0; j < 4; ++j) bv[j] = Bt[k][tx * 4 + j];
            #pragma unroll
            for (int i = 0; i < 4; ++i)
                #pragma unroll
                for (int j = 0; j < 4; ++j)
                    acc[i][j] = fmaf(a[i], bv[j], acc[i][j]);
        }
        __syncthreads();
    }

    float* Sb = S + (size_t)b * Nx * Nz;
    #pragma unroll
    for (int i = 0; i < 4; ++i) {
        int gn = n0 + ty * 4 + i;
        #pragma unroll
        for (int j = 0; j < 4; ++j) {
            int gm = m0 + tx * 4 + j;
            if (gn < Nx && gm < Nz)
                Sb[(size_t)gn * Nz + gm] = acc[i][j];
        }
    }
}

// ---------------------------------------------------------------------------
// Sparsemax over each row of S (length Nz=169), in place.
// tau solves sum(max(x - tau, 0)) = 1 : Newton on convex piecewise-linear f,
// starting at tau = max(x) - 1; monotone, finite convergence (support ~1-2).
// One wave per row, 4 waves per block.
// ---------------------------------------------------------------------------
__global__ __launch_bounds__(256)
void sparsemax_rows(float* __restrict__ S, int rows)
{
    const int wid  = threadIdx.x >> 6;
    const int lane = threadIdx.x & 63;
    const int row  = blockIdx.x * 4 + wid;
    if (row >= rows) return;

    float* x = S + (size_t)row * Nz;
    float v[3];
    #pragma unroll
    for (int t = 0; t < 3; ++t) {
        int m = lane + 64 * t;
        v[t] = (m < Nz) ? x[m] : -1e30f;
    }

    float mx = fmaxf(v[0], fmaxf(v[1], v[2]));
    #pragma unroll
    for (int off = 32; off; off >>= 1) mx = fmaxf(mx, __shfl_xor(mx, off));

    float tau = mx - 1.0f;
    for (int it = 0; it < 64; ++it) {
        float s = 0.f, cnt = 0.f;
        #pragma unroll
        for (int t = 0; t < 3; ++t)
            if (v[t] > tau) { s += v[t]; cnt += 1.f; }
        #pragma unroll
        for (int off = 32; off; off >>= 1) {
            s   += __shfl_xor(s, off);
            cnt += __shfl_xor(cnt, off);
        }
        float nt = (s - 1.0f) / cnt;
        if (!(nt > tau)) break;   // converged (exact on final linear segment)
        tau = nt;
    }

    #pragma unroll
    for (int t = 0; t < 3; ++t) {
        int m = lane + 64 * t;
        if (m < Nz) x[m] = fmaxf(v[t] - tau, 0.f);
    }
}

// ---------------------------------------------------------------------------
// embedding[b,c,n] = sum_m zf_g[b,c,m] * score[b,n,m]   (K = Nz = 169)
// Tile 64(c) x 64(n). Both operands staged [row][k] with +1-pad.
// ---------------------------------------------------------------------------
__global__ __launch_bounds__(256)
void emb_gemm(const float* __restrict__ G, const float* __restrict__ P,
              float* __restrict__ E)
{
    __shared__ float Gt[64][17];   // [c][m]
    __shared__ float Pt[64][17];   // [n][m]

    const int b  = blockIdx.z;
    const int n0 = blockIdx.x * 64;
    const int c0 = blockIdx.y * 64;
    const int tid = threadIdx.x;
    const int tx = tid & 15, ty = tid >> 4;

    const float* Gb = G + (size_t)b * C * Nz;
    const float* Pb = P + (size_t)b * Nx * Nz;

    float acc[4][4] = {};

    for (int kc = 0; kc < 176; kc += 16) {   // 11 chunks cover 169
        #pragma unroll
        for (int i = 0; i < 4; ++i) {
            int e = tid + 256 * i;
            int r = e >> 4, m = e & 15;
            int gm = kc + m;
            Gt[r][m] = (gm < Nz) ? Gb[(size_t)(c0 + r) * Nz + gm] : 0.f;
            int gn = n0 + r;
            Pt[r][m] = (gm < Nz && gn < Nx) ? Pb[(size_t)gn * Nz + gm] : 0.f;
        }
        __syncthreads();
        #pragma unroll
        for (int k = 0; k < 16; ++k) {
            float a[4], bv[4];
            #pragma unroll
            for (int i = 0; i < 4; ++i) a[i] = Gt[ty * 4 + i][k];
            #pragma unroll
            for (int j = 0; j < 4; ++j) bv[j] = Pt[tx * 4 + j][k];
            #pragma unroll
            for (int i = 0; i < 4; ++i)
                #pragma unroll
                for (int j = 0; j < 4; ++j)
                    acc[i][j] = fmaf(a[i], bv[j], acc[i][j]);
        }
        __syncthreads();
    }

    float* Eb = E + (size_t)b * C * Nx;
    #pragma unroll
    for (int i = 0; i < 4; ++i) {
        int gc = c0 + ty * 4 + i;
        #pragma unroll
        for (int j = 0; j < 4; ++j) {
            int gn = n0 + tx * 4 + j;
            if (gn < Nx) Eb[(size_t)gc * Nx + gn] = acc[i][j];
        }
    }
}

// ---------------------------------------------------------------------------
extern "C" void kernel_launch(void* const* d_in, const int* in_sizes, int n_in,
                              void* d_out, int out_size, void* d_ws, size_t ws_size,
                              hipStream_t stream)
{
    const float* zf      = (const float*)d_in[0];
    const float* xf      = (const float*)d_in[1];
    const float* Wq      = (const float*)d_in[2];
    const float* bq      = (const float*)d_in[3];
    const float* Ws_     = (const float*)d_in[4];
    const float* bs      = (const float*)d_in[5];
    const float* Wg      = (const float*)d_in[6];
    const float* bg      = (const float*)d_in[7];
    const float* g_gamma = (const float*)d_in[8];
    const float* g_beta  = (const float*)d_in[9];
    const float* g_mean  = (const float*)d_in[10];
    const float* g_var   = (const float*)d_in[11];
    const float* Wf      = (const float*)d_in[12];
    const float* bf      = (const float*)d_in[13];
    const float* f_gamma = (const float*)d_in[14];
    const float* f_beta  = (const float*)d_in[15];
    const float* f_mean  = (const float*)d_in[16];
    const float* f_var   = (const float*)d_in[17];
    float* out = (float*)d_out;

    float* ws = (float*)d_ws;
    float* xf_trans = ws;                                   // [B,C,Nx] (reused as emb)
    float* xf_g     = xf_trans + (size_t)Bb * C * Nx;       // [B,C,Nx]
    float* zf_trans = xf_g     + (size_t)Bb * C * Nx;       // [B,C,Nz]
    float* zf_g     = zf_trans + (size_t)Bb * C * Nz;       // [B,C,Nz]
    float* sim      = zf_g     + (size_t)Bb * C * Nz;       // [B,Nx,Nz] (scores in place)

    dim3 blk(256);
    const int gx_x = (Nx + 63) / 64;   // 10
    const int gx_z = (Nz + 63) / 64;   // 3

    // query / support transforms (precision-sensitive path)
    conv_gemm<0><<<dim3(gx_x, C / 64, Bb), blk, 0, stream>>>(
        xf, nullptr, Wq, bq, nullptr, nullptr, nullptr, nullptr,
        xf_trans, Nx, C, C, C);
    conv_gemm<0><<<dim3(gx_z, C / 64, Bb), blk, 0, stream>>>(
        zf, nullptr, Ws_, bs, nullptr, nullptr, nullptr, nullptr,
        zf_trans, Nz, C, C, C);

    // g-branch: conv + BN + ReLU
    conv_gemm<1><<<dim3(gx_x, C / 64, Bb), blk, 0, stream>>>(
        xf, nullptr, Wg, bg, g_gamma, g_beta, g_mean, g_var,
        xf_g, Nx, C, C, C);
    conv_gemm<1><<<dim3(gx_z, C / 64, Bb), blk, 0, stream>>>(
        zf, nullptr, Wg, bg, g_gamma, g_beta, g_mean, g_var,
        zf_g, Nz, C, C, C);

    // attention scores
    sim_gemm<<<dim3(gx_z, gx_x, Bb), blk, 0, stream>>>(xf_trans, zf_trans, sim);
    sparsemax_rows<<<dim3((Bb * Nx + 3) / 4), blk, 0, stream>>>(sim, Bb * Nx);

    // embedding (reuse xf_trans buffer)
    emb_gemm<<<dim3(gx_x, C / 64, Bb), blk, 0, stream>>>(zf_g, sim, xf_trans);

    // final conv over concat([embedding, xf_g]) + BN + ReLU
    conv_gemm<1><<<dim3(gx_x, C / 64, Bb), blk, 0, stream>>>(
        xf_trans, xf_g, Wf, bf, f_gamma, f_beta, f_mean, f_var,
        out, Nx, C, 2 * C, C);
}

// Round 2
// 729.766 us; speedup vs baseline: 2.1555x; 2.1555x over previous
//
#include <hip/hip_runtime.h>
#include <math.h>

#define EPS 1e-5f

constexpr int Bb  = 128;
constexpr int C   = 256;
constexpr int Nz  = 169;   // 13*13
constexpr int Nx  = 625;   // 25*25
constexpr int NzP = 192;   // Nz padded to multiple of 32 (zero-filled)

typedef __bf16 bf16x8 __attribute__((ext_vector_type(8)));
typedef float  f32x4  __attribute__((ext_vector_type(4)));

__device__ __forceinline__ unsigned short f2bf(float f) {
    union { float f; unsigned u; } x; x.f = f;
    unsigned r = x.u + 0x7FFFu + ((x.u >> 16) & 1u);   // RNE
    return (unsigned short)(r >> 16);
}

// ---------------------------------------------------------------------------
// fp32 → bf16 elementwise (weights)
// ---------------------------------------------------------------------------
__global__ void cvt_bf16(const float* __restrict__ s, unsigned short* __restrict__ d, int n)
{
    int i = blockIdx.x * 256 + threadIdx.x;
    if (i < n) d[i] = f2bf(s[i]);
}

// ---------------------------------------------------------------------------
// X [b][C][N] f32  →  XT [b][N][C] bf16  (k-major rows for MFMA B operand)
// ---------------------------------------------------------------------------
__global__ __launch_bounds__(256)
void x2t(const float* __restrict__ X, unsigned short* __restrict__ XT, int N)
{
    __shared__ float T[64][65];
    const int b = blockIdx.z, n0 = blockIdx.x * 64, c0 = blockIdx.y * 64;
    const float* Xb = X + ((size_t)b * C + c0) * N;
    #pragma unroll
    for (int i = 0; i < 16; ++i) {
        int e = threadIdx.x + 256 * i;
        int c = e >> 6, n = e & 63;
        T[c][n] = (n0 + n < N) ? Xb[(size_t)c * N + n0 + n] : 0.f;
    }
    __syncthreads();
    #pragma unroll
    for (int i = 0; i < 16; ++i) {
        int e = threadIdx.x + 256 * i;
        int n = e >> 6, c = e & 63;
        if (n0 + n < N)
            XT[((size_t)b * N + n0 + n) * C + c0 + c] = f2bf(T[c][n]);
    }
}

// ---------------------------------------------------------------------------
// MFMA bf16 GEMM:  D[b,o,n] = sum_k A(o,k) * Brow(b,n,k)   (+ epilogue)
//   A : [O][K] bf16 row-major (k contiguous), optionally batched via aStride
//   B : rows k-major; k < K1 from B1 (row stride K1), else B2 (row stride K-K1)
// MODE: 0 = write [b][N][O] bf16 (transposed, for downstream B operand)
//       1 = write [b][O][Nout] bf16, zero-padded for n in [N, Nout)
//       2 = write [b][O][N] f32
// EPI : 0 = none, 1 = bias + BN + ReLU
// Tile 64(o) x 64(n), 4 waves each 32x32, K-chunks of 32.
// ---------------------------------------------------------------------------
template<int MODE, int EPI>
__global__ __launch_bounds__(256)
void mfma_conv(const unsigned short* __restrict__ A, size_t aStride,
               const unsigned short* __restrict__ B1,
               const unsigned short* __restrict__ B2,
               const float* __restrict__ bias, const float* __restrict__ gamma,
               const float* __restrict__ beta, const float* __restrict__ mean,
               const float* __restrict__ var,
               void* __restrict__ Yv, int N, int Nout, int K1, int K, int O)
{
    __shared__ unsigned short As[64][40];   // [o][k], +16B pad
    __shared__ unsigned short Bs[64][40];   // [n][k], +16B pad

    const int b   = blockIdx.z;
    const int n0  = blockIdx.x * 64;
    const int o0  = blockIdx.y * 64;
    const int tid = threadIdx.x;
    const int lane = tid & 63, wid = tid >> 6;
    const int wr = wid >> 1, wc = wid & 1;          // wave sub-tile (32x32)

    const unsigned short* Ab  = A + (size_t)b * aStride;
    const int K2 = K - K1;
    const unsigned short* B1b = B1 + (size_t)b * N * K1;
    const unsigned short* B2b = B2 ? (B2 + (size_t)b * N * K2) : nullptr;

    f32x4 acc[2][2];
    #pragma unroll
    for (int i = 0; i < 2; ++i)
        #pragma unroll
        for (int j = 0; j < 2; ++j)
            #pragma unroll
            for (int e = 0; e < 4; ++e) acc[i][j][e] = 0.f;

    const int srow = tid >> 2, sseg = tid & 3;      // staging: 64 rows x 4x16B
    const int lr = lane & 15, lk = (lane >> 4) * 8;

    for (int kc = 0; kc < K; kc += 32) {
        const int gk = kc + sseg * 8;
        *(int4*)&As[srow][sseg * 8] =
            *(const int4*)&Ab[(size_t)(o0 + srow) * K + gk];

        const int gn = n0 + srow;
        int4 bv = make_int4(0, 0, 0, 0);
        if (gn < N) {
            if (gk < K1) bv = *(const int4*)&B1b[(size_t)gn * K1 + gk];
            else         bv = *(const int4*)&B2b[(size_t)gn * K2 + (gk - K1)];
        }
        *(int4*)&Bs[srow][sseg * 8] = bv;
        __syncthreads();

        bf16x8 a0 = *(const bf16x8*)&As[wr * 32 +      lr][lk];
        bf16x8 a1 = *(const bf16x8*)&As[wr * 32 + 16 + lr][lk];
        bf16x8 b0 = *(const bf16x8*)&Bs[wc * 32 +      lr][lk];
        bf16x8 b1 = *(const bf16x8*)&Bs[wc * 32 + 16 + lr][lk];

        acc[0][0] = __builtin_amdgcn_mfma_f32_16x16x32_bf16(a0, b0, acc[0][0], 0, 0, 0);
        acc[0][1] = __builtin_amdgcn_mfma_f32_16x16x32_bf16(a0, b1, acc[0][1], 0, 0, 0);
        acc[1][0] = __builtin_amdgcn_mfma_f32_16x16x32_bf16(a1, b0, acc[1][0], 0, 0, 0);
        acc[1][1] = __builtin_amdgcn_mfma_f32_16x16x32_bf16(a1, b1, acc[1][1], 0, 0, 0);
        __syncthreads();
    }

    // epilogue — C/D layout: col = lane&15, row = (lane>>4)*4 + reg  [m89]
    const int lg = lane >> 4;
    #pragma unroll
    for (int i = 0; i < 2; ++i) {
        const int ob = o0 + wr * 32 + i * 16 + lg * 4;   // 4 consecutive o's
        float inv[4], sh[4], bi[4];
        if (EPI) {
            #pragma unroll
            for (int r = 0; r < 4; ++r) {
                int o = ob + r;
                float iv = gamma[o] * rsqrtf(var[o] + EPS);
                inv[r] = iv; sh[r] = beta[o] - mean[o] * iv; bi[r] = bias[o];
            }
        }
        #pragma unroll
        for (int j = 0; j < 2; ++j) {
            const int gn = n0 + wc * 32 + j * 16 + lr;
            float v[4];
            #pragma unroll
            for (int r = 0; r < 4; ++r) {
                v[r] = acc[i][j][r];
                if (EPI) v[r] = fmaxf(fmaf(v[r] + bi[r], inv[r], sh[r]), 0.f);
            }
            if (MODE == 0) {
                if (gn < N) {
                    uint2 pk;
                    pk.x = (unsigned)f2bf(v[0]) | ((unsigned)f2bf(v[1]) << 16);
                    pk.y = (unsigned)f2bf(v[2]) | ((unsigned)f2bf(v[3]) << 16);
                    *(uint2*)((unsigned short*)Yv + ((size_t)b * N + gn) * O + ob) = pk;
                }
            } else if (MODE == 1) {
                if (gn < Nout) {
                    #pragma unroll
                    for (int r = 0; r < 4; ++r)
                        ((unsigned short*)Yv)[((size_t)b * O + ob + r) * Nout + gn] =
                            (gn < N) ? f2bf(v[r]) : (unsigned short)0;
                }
            } else {
                if (gn < N) {
                    #pragma unroll
                    for (int r = 0; r < 4; ++r)
                        ((float*)Yv)[((size_t)b * O + ob + r) * N + gn] = v[r];
                }
            }
        }
    }
}

// ---------------------------------------------------------------------------
// fp32 conv1x1 GEMM (precision-sensitive path: Wq, Ws) — unchanged from R1
// ---------------------------------------------------------------------------
template<int DO_BN>
__global__ __launch_bounds__(256)
void conv_gemm(const float* __restrict__ X1, const float* __restrict__ X2,
               const float* __restrict__ W, const float* __restrict__ bias,
               const float* __restrict__ gamma, const float* __restrict__ beta,
               const float* __restrict__ mean, const float* __restrict__ var,
               float* __restrict__ Y, int N, int K1, int K, int O)
{
    __shared__ float Wt[64][17];
    __shared__ float Xs[16][64];

    const int b  = blockIdx.z;
    const int n0 = blockIdx.x * 64;
    const int o0 = blockIdx.y * 64;
    const int tid = threadIdx.x;
    const int tx = tid & 15, ty = tid >> 4;

    const float* X1b = X1 + (size_t)b * K1 * N;
    const float* X2b = X2 ? (X2 + (size_t)b * (K - K1) * N) : nullptr;

    float acc[4][4] = {};

    for (int kc = 0; kc < K; kc += 16) {
        #pragma unroll
        for (int i = 0; i < 4; ++i) {
            int e = tid + 256 * i;
            int o = e >> 4, k = e & 15;
            Wt[o][k] = W[(size_t)(o0 + o) * K + (kc + k)];
        }
        #pragma unroll
        for (int i = 0; i < 4; ++i) {
            int e = tid + 256 * i;
            int k = e >> 6, n = e & 63;
            int gk = kc + k, gn = n0 + n;
            float v = 0.f;
            if (gn < N)
                v = (gk < K1) ? X1b[(size_t)gk * N + gn]
                              : X2b[(size_t)(gk - K1) * N + gn];
            Xs[k][n] = v;
        }
        __syncthreads();
        #pragma unroll
        for (int k = 0; k < 16; ++k) {
            float a[4], bv[4];
            #pragma unroll
            for (int i = 0; i < 4; ++i) a[i] = Wt[ty * 4 + i][k];
            #pragma unroll
            for (int j = 0; j < 4; ++j) bv[j] = Xs[k][tx * 4 + j];
            #pragma unroll
            for (int i = 0; i < 4; ++i)
                #pragma unroll
                for (int j = 0; j < 4; ++j)
                    acc[i][j] = fmaf(a[i], bv[j], acc[i][j]);
        }
        __syncthreads();
    }

    float* Yb = Y + (size_t)b * O * N;
    #pragma unroll
    for (int i = 0; i < 4; ++i) {
        int go = o0 + ty * 4 + i;
        float bi = bias[go];
        float inv = 1.f, sh = 0.f;
        if (DO_BN) {
            inv = gamma[go] * rsqrtf(var[go] + EPS);
            sh  = beta[go] - mean[go] * inv;
        }
        #pragma unroll
        for (int j = 0; j < 4; ++j) {
            int gn = n0 + tx * 4 + j;
            if (gn < N) {
                float v = acc[i][j] + bi;
                if (DO_BN) v = fmaxf(fmaf(v, inv, sh), 0.f);
                Yb[(size_t)go * N + gn] = v;
            }
        }
    }
}

// ---------------------------------------------------------------------------
// similar[b,n,m] = sum_c xf_trans[b,c,n] * zf_trans[b,c,m]  — unchanged
// ---------------------------------------------------------------------------
__global__ __launch_bounds__(256)
void sim_gemm(const float* __restrict__ A, const float* __restrict__ Bz,
              float* __restrict__ S)
{
    __shared__ float At[16][64];
    __shared__ float Bt[16][64];

    const int b  = blockIdx.z;
    const int m0 = blockIdx.x * 64;
    const int n0 = blockIdx.y * 64;
    const int tid = threadIdx.x;
    const int tx = tid & 15, ty = tid >> 4;

    const float* Ab = A  + (size_t)b * C * Nx;
    const float* Zb = Bz + (size_t)b * C * Nz;

    float acc[4][4] = {};

    for (int kc = 0; kc < C; kc += 16) {
        #pragma unroll
        for (int i = 0; i < 4; ++i) {
            int e = tid + 256 * i;
            int k = e >> 6, n = e & 63;
            int gn = n0 + n;
            At[k][n] = (gn < Nx) ? Ab[(size_t)(kc + k) * Nx + gn] : 0.f;
            int gm = m0 + n;
            Bt[k][n] = (gm < Nz) ? Zb[(size_t)(kc + k) * Nz + gm] : 0.f;
        }
        __syncthreads();
        #pragma unroll
        for (int k = 0; k < 16; ++k) {
            float a[4], bv[4];
            #pragma unroll
            for (int i = 0; i < 4; ++i) a[i] = At[k][ty * 4 + i];
            #pragma unroll
            for (int j = 0; j < 4; ++j) bv[j] = Bt[k][tx * 4 + j];
            #pragma unroll
            for (int i = 0; i < 4; ++i)
                #pragma unroll
                for (int j = 0; j < 4; ++j)
                    acc[i][j] = fmaf(a[i], bv[j], acc[i][j]);
        }
        __syncthreads();
    }

    float* Sb = S + (size_t)b * Nx * Nz;
    #pragma unroll
    for (int i = 0; i < 4; ++i) {
        int gn = n0 + ty * 4 + i;
        #pragma unroll
        for (int j = 0; j < 4; ++j) {
            int gm = m0 + tx * 4 + j;
            if (gn < Nx && gm < Nz)
                Sb[(size_t)gn * Nz + gm] = acc[i][j];
        }
    }
}

// ---------------------------------------------------------------------------
// Sparsemax rows of S (len Nz), write bf16 scores [rows][NzP] zero-padded.
// ---------------------------------------------------------------------------
__global__ __launch_bounds__(256)
void sparsemax_rows(const float* __restrict__ S, unsigned short* __restrict__ P,
                    int rows)
{
    const int wid  = threadIdx.x >> 6;
    const int lane = threadIdx.x & 63;
    const int row  = blockIdx.x * 4 + wid;
    if (row >= rows) return;

    const float* x = S + (size_t)row * Nz;
    float v[3];
    #pragma unroll
    for (int t = 0; t < 3; ++t) {
        int m = lane + 64 * t;
        v[t] = (m < Nz) ? x[m] : -1e30f;
    }

    float mx = fmaxf(v[0], fmaxf(v[1], v[2]));
    #pragma unroll
    for (int off = 32; off; off >>= 1) mx = fmaxf(mx, __shfl_xor(mx, off));

    float tau = mx - 1.0f;
    for (int it = 0; it < 64; ++it) {
        float s = 0.f, cnt = 0.f;
        #pragma unroll
        for (int t = 0; t < 3; ++t)
            if (v[t] > tau) { s += v[t]; cnt += 1.f; }
        #pragma unroll
        for (int off = 32; off; off >>= 1) {
            s   += __shfl_xor(s, off);
            cnt += __shfl_xor(cnt, off);
        }
        float nt = (s - 1.0f) / cnt;
        if (!(nt > tau)) break;
        tau = nt;
    }

    unsigned short* pr = P + (size_t)row * NzP;
    #pragma unroll
    for (int t = 0; t < 3; ++t) {
        int m = lane + 64 * t;
        float sv = (m < Nz) ? fmaxf(v[t] - tau, 0.f) : 0.f;
        if (m < NzP) pr[m] = f2bf(sv);
    }
}

// ---------------------------------------------------------------------------
extern "C" void kernel_launch(void* const* d_in, const int* in_sizes, int n_in,
                              void* d_out, int out_size, void* d_ws, size_t ws_size,
                              hipStream_t stream)
{
    const float* zf      = (const float*)d_in[0];
    const float* xf      = (const float*)d_in[1];
    const float* Wq      = (const float*)d_in[2];
    const float* bq      = (const float*)d_in[3];
    const float* Ws_     = (const float*)d_in[4];
    const float* bs      = (const float*)d_in[5];
    const float* Wg      = (const float*)d_in[6];
    const float* bg      = (const float*)d_in[7];
    const float* g_gamma = (const float*)d_in[8];
    const float* g_beta  = (const float*)d_in[9];
    const float* g_mean  = (const float*)d_in[10];
    const float* g_var   = (const float*)d_in[11];
    const float* Wf      = (const float*)d_in[12];
    const float* bf_     = (const float*)d_in[13];
    const float* f_gamma = (const float*)d_in[14];
    const float* f_beta  = (const float*)d_in[15];
    const float* f_mean  = (const float*)d_in[16];
    const float* f_var   = (const float*)d_in[17];
    float* out = (float*)d_out;

    char* ws = (char*)d_ws;
    float* xf_trans        = (float*)(ws);                      // 81,920,000 B
    float* zf_trans        = (float*)(ws + 81920000);           // 22,151,168
    float* sim             = (float*)(ws + 104071168);          // 54,080,000
    unsigned short* xfT    = (unsigned short*)(ws + 158151168); // 40,960,000
    unsigned short* zfT    = (unsigned short*)(ws + 199111168); // 11,075,584
    unsigned short* xf_gT  = (unsigned short*)(ws + 210186752); // 40,960,000
    unsigned short* zf_gP  = (unsigned short*)(ws + 251146752); // 12,582,912
    unsigned short* scoreP = (unsigned short*)(ws + 263729664); // 30,720,000
    unsigned short* Wg_bf  = (unsigned short*)(ws + 294449664); //    131,072
    unsigned short* Wf_bf  = (unsigned short*)(ws + 294580736); //    262,144
    unsigned short* embT   = (unsigned short*)(ws);             // alias xf_trans (dead after sim)

    dim3 blk(256);
    const int gx_x = (Nx + 63) / 64;   // 10
    const int gx_z = (Nz + 63) / 64;   // 3

    // --- bf16 conversions / transposes (for the MFMA path) ---
    cvt_bf16<<<dim3((C * C + 255) / 256), blk, 0, stream>>>(Wg, Wg_bf, C * C);
    cvt_bf16<<<dim3((C * 2 * C + 255) / 256), blk, 0, stream>>>(Wf, Wf_bf, C * 2 * C);
    x2t<<<dim3(gx_x, C / 64, Bb), blk, 0, stream>>>(xf, xfT, Nx);
    x2t<<<dim3(gx_z, C / 64, Bb), blk, 0, stream>>>(zf, zfT, Nz);

    // --- precision-sensitive path (fp32) ---
    conv_gemm<0><<<dim3(gx_x, C / 64, Bb), blk, 0, stream>>>(
        xf, nullptr, Wq, bq, nullptr, nullptr, nullptr, nullptr,
        xf_trans, Nx, C, C, C);
    conv_gemm<0><<<dim3(gx_z, C / 64, Bb), blk, 0, stream>>>(
        zf, nullptr, Ws_, bs, nullptr, nullptr, nullptr, nullptr,
        zf_trans, Nz, C, C, C);
    sim_gemm<<<dim3(gx_z, gx_x, Bb), blk, 0, stream>>>(xf_trans, zf_trans, sim);
    sparsemax_rows<<<dim3((Bb * Nx + 3) / 4), blk, 0, stream>>>(sim, scoreP, Bb * Nx);

    // --- tolerant path (bf16 MFMA) ---
    // xf_g = bn_relu(Wg @ xf)  -> [b][Nx][C] bf16
    mfma_conv<0, 1><<<dim3(gx_x, C / 64, Bb), blk, 0, stream>>>(
        Wg_bf, 0, xfT, nullptr, bg, g_gamma, g_beta, g_mean, g_var,
        xf_gT, Nx, Nx, C, C, C);
    // zf_g = bn_relu(Wg @ zf)  -> [b][C][NzP] bf16 zero-padded
    mfma_conv<1, 1><<<dim3(NzP / 64, C / 64, Bb), blk, 0, stream>>>(
        Wg_bf, 0, zfT, nullptr, bg, g_gamma, g_beta, g_mean, g_var,
        zf_gP, Nz, NzP, C, C, C);
    // embedding = zf_g @ score^T  -> [b][Nx][C] bf16   (A batched)
    mfma_conv<0, 0><<<dim3(gx_x, C / 64, Bb), blk, 0, stream>>>(
        zf_gP, (size_t)C * NzP, scoreP, nullptr,
        nullptr, nullptr, nullptr, nullptr, nullptr,
        embT, Nx, Nx, NzP, NzP, C);
    // out = bn_relu(Wf @ concat(embedding, xf_g))  -> [b][C][Nx] f32
    mfma_conv<2, 1><<<dim3(gx_x, C / 64, Bb), blk, 0, stream>>>(
        Wf_bf, 0, embT, xf_gT, bf_, f_gamma, f_beta, f_mean, f_var,
        out, Nx, Nx, C, 2 * C, C);
}

// Round 3
// 512.178 us; speedup vs baseline: 3.0712x; 1.4248x over previous
//
#include <hip/hip_runtime.h>
#include <math.h>

#define EPS 1e-5f

constexpr int Bb  = 128;
constexpr int C   = 256;
constexpr int Nz  = 169;   // 13*13
constexpr int Nx  = 625;   // 25*25
constexpr int NzP = 192;   // Nz padded to multiple of 32 (zero-filled)

typedef __bf16 bf16x8 __attribute__((ext_vector_type(8)));
typedef float  f32x4  __attribute__((ext_vector_type(4)));

__device__ __forceinline__ unsigned short f2bf(float f) {
    union { float f; unsigned u; } x; x.f = f;
    unsigned r = x.u + 0x7FFFu + ((x.u >> 16) & 1u);   // RNE
    return (unsigned short)(r >> 16);
}
__device__ __forceinline__ float bf2f(unsigned short h) {
    union { unsigned u; float f; } x; x.u = ((unsigned)h) << 16;
    return x.f;
}

// ---------------------------------------------------------------------------
// All weight conversions in one launch.
// Wq, Ws, Wg: C*C elements; Wf: C*2C.
// ---------------------------------------------------------------------------
__global__ void cvt_weights(const float* __restrict__ Wq, const float* __restrict__ Ws,
                            const float* __restrict__ Wg, const float* __restrict__ Wf,
                            unsigned short* __restrict__ qh, unsigned short* __restrict__ ql,
                            unsigned short* __restrict__ sh_, unsigned short* __restrict__ sl,
                            unsigned short* __restrict__ g,  unsigned short* __restrict__ f)
{
    int i = blockIdx.x * 256 + threadIdx.x;
    if (i < C * C) {
        float q = Wq[i]; unsigned short h = f2bf(q);
        qh[i] = h; ql[i] = f2bf(q - bf2f(h));
        float s = Ws[i]; h = f2bf(s);
        sh_[i] = h; sl[i] = f2bf(s - bf2f(h));
        g[i] = f2bf(Wg[i]);
    }
    if (i < C * 2 * C) f[i] = f2bf(Wf[i]);
}

// ---------------------------------------------------------------------------
// X [b][C][N] f32  →  hi/lo bf16 [b][N][C]  (k-major rows for MFMA operands)
// ---------------------------------------------------------------------------
__global__ __launch_bounds__(256)
void x2t_split(const float* __restrict__ X, unsigned short* __restrict__ Hi,
               unsigned short* __restrict__ Lo, int N)
{
    __shared__ float T[64][65];
    const int b = blockIdx.z, n0 = blockIdx.x * 64, c0 = blockIdx.y * 64;
    const float* Xb = X + ((size_t)b * C + c0) * N;
    #pragma unroll
    for (int i = 0; i < 16; ++i) {
        int e = threadIdx.x + 256 * i;
        int c = e >> 6, n = e & 63;
        T[c][n] = (n0 + n < N) ? Xb[(size_t)c * N + n0 + n] : 0.f;
    }
    __syncthreads();
    #pragma unroll
    for (int i = 0; i < 16; ++i) {
        int e = threadIdx.x + 256 * i;
        int n = e >> 6, c = e & 63;
        if (n0 + n < N) {
            float v = T[c][n];
            unsigned short h = f2bf(v);
            size_t idx = ((size_t)b * N + n0 + n) * C + c0 + c;
            Hi[idx] = h;
            Lo[idx] = f2bf(v - bf2f(h));
        }
    }
}

// ---------------------------------------------------------------------------
// Split-bf16 MFMA GEMM (fp32-accurate path):
//   D[b,o,n] = sum_k A(o,k)*B(b,n,k), A = Ah+Al, B = Bh+Bl,
//   product ≈ ah*bh + ah*bl + al*bh  (al*bl dropped, ~2^-18 rel)
// A rows: stride K, bound O (zero-filled beyond). aStride batches A.
// B rows: [b][N][K], bound N.
// MODE 0: write split bf16 [b][N][O] (hi/lo)    EPI 1: add bias
// MODE 1: write f32 [b][O][N]
// ---------------------------------------------------------------------------
template<int MODE, int EPI>
__global__ __launch_bounds__(256)
void mfma_split(const unsigned short* __restrict__ Ahi,
                const unsigned short* __restrict__ Alo, size_t aStride,
                const unsigned short* __restrict__ Bhi,
                const unsigned short* __restrict__ Blo,
                const float* __restrict__ bias,
                unsigned short* __restrict__ Yhi, unsigned short* __restrict__ Ylo,
                float* __restrict__ Yf,
                int N, int K, int O)
{
    __shared__ unsigned short Ah[64][40], Al[64][40], Bh[64][40], Bl[64][40];

    const int b   = blockIdx.z;
    const int n0  = blockIdx.x * 64;
    const int o0  = blockIdx.y * 64;
    const int tid = threadIdx.x;
    const int lane = tid & 63, wid = tid >> 6;
    const int wr = wid >> 1, wc = wid & 1;

    const unsigned short* Ahb = Ahi + (size_t)b * aStride;
    const unsigned short* Alb = Alo + (size_t)b * aStride;
    const unsigned short* Bhb = Bhi + (size_t)b * N * K;
    const unsigned short* Blb = Blo + (size_t)b * N * K;

    f32x4 acc[2][2];
    #pragma unroll
    for (int i = 0; i < 2; ++i)
        #pragma unroll
        for (int j = 0; j < 2; ++j)
            #pragma unroll
            for (int e = 0; e < 4; ++e) acc[i][j][e] = 0.f;

    const int srow = tid >> 2, sseg = tid & 3;
    const int lr = lane & 15, lk = (lane >> 4) * 8;

    for (int kc = 0; kc < K; kc += 32) {
        const int gk = kc + sseg * 8;
        const int go = o0 + srow;
        int4 av = make_int4(0, 0, 0, 0), alv = make_int4(0, 0, 0, 0);
        if (go < O) {
            av  = *(const int4*)&Ahb[(size_t)go * K + gk];
            alv = *(const int4*)&Alb[(size_t)go * K + gk];
        }
        *(int4*)&Ah[srow][sseg * 8] = av;
        *(int4*)&Al[srow][sseg * 8] = alv;

        const int gn = n0 + srow;
        int4 bv = make_int4(0, 0, 0, 0), blv = make_int4(0, 0, 0, 0);
        if (gn < N) {
            bv  = *(const int4*)&Bhb[(size_t)gn * K + gk];
            blv = *(const int4*)&Blb[(size_t)gn * K + gk];
        }
        *(int4*)&Bh[srow][sseg * 8] = bv;
        *(int4*)&Bl[srow][sseg * 8] = blv;
        __syncthreads();

        bf16x8 ah[2], al[2], bh[2], bl[2];
        #pragma unroll
        for (int i = 0; i < 2; ++i) {
            ah[i] = *(const bf16x8*)&Ah[wr * 32 + i * 16 + lr][lk];
            al[i] = *(const bf16x8*)&Al[wr * 32 + i * 16 + lr][lk];
            bh[i] = *(const bf16x8*)&Bh[wc * 32 + i * 16 + lr][lk];
            bl[i] = *(const bf16x8*)&Bl[wc * 32 + i * 16 + lr][lk];
        }
        #pragma unroll
        for (int i = 0; i < 2; ++i)
            #pragma unroll
            for (int j = 0; j < 2; ++j) {
                acc[i][j] = __builtin_amdgcn_mfma_f32_16x16x32_bf16(al[i], bh[j], acc[i][j], 0, 0, 0);
                acc[i][j] = __builtin_amdgcn_mfma_f32_16x16x32_bf16(ah[i], bl[j], acc[i][j], 0, 0, 0);
                acc[i][j] = __builtin_amdgcn_mfma_f32_16x16x32_bf16(ah[i], bh[j], acc[i][j], 0, 0, 0);
            }
        __syncthreads();
    }

    // C/D layout: col = lane&15, row = (lane>>4)*4 + reg
    const int lg = lane >> 4;
    #pragma unroll
    for (int i = 0; i < 2; ++i) {
        const int ob = o0 + wr * 32 + i * 16 + lg * 4;
        float bi[4];
        if (EPI) {
            #pragma unroll
            for (int r = 0; r < 4; ++r) bi[r] = bias[ob + r];
        }
        #pragma unroll
        for (int j = 0; j < 2; ++j) {
            const int gn = n0 + wc * 32 + j * 16 + lr;
            float v[4];
            #pragma unroll
            for (int r = 0; r < 4; ++r) {
                v[r] = acc[i][j][r];
                if (EPI) v[r] += bi[r];
            }
            if (MODE == 0) {
                if (gn < N) {
                    unsigned short h[4], l[4];
                    #pragma unroll
                    for (int r = 0; r < 4; ++r) {
                        h[r] = f2bf(v[r]);
                        l[r] = f2bf(v[r] - bf2f(h[r]));
                    }
                    size_t idx = ((size_t)b * N + gn) * O + ob;
                    uint2 ph, pl;
                    ph.x = (unsigned)h[0] | ((unsigned)h[1] << 16);
                    ph.y = (unsigned)h[2] | ((unsigned)h[3] << 16);
                    pl.x = (unsigned)l[0] | ((unsigned)l[1] << 16);
                    pl.y = (unsigned)l[2] | ((unsigned)l[3] << 16);
                    *(uint2*)&Yhi[idx] = ph;
                    *(uint2*)&Ylo[idx] = pl;
                }
            } else {
                if (gn < N) {
                    #pragma unroll
                    for (int r = 0; r < 4; ++r)
                        if (ob + r < O)
                            Yf[((size_t)b * O + ob + r) * N + gn] = v[r];
                }
            }
        }
    }
}

// ---------------------------------------------------------------------------
// Plain bf16 MFMA GEMM (tolerant path) — unchanged from round 2.
// ---------------------------------------------------------------------------
template<int MODE, int EPI>
__global__ __launch_bounds__(256)
void mfma_conv(const unsigned short* __restrict__ A, size_t aStride,
               const unsigned short* __restrict__ B1,
               const unsigned short* __restrict__ B2,
               const float* __restrict__ bias, const float* __restrict__ gamma,
               const float* __restrict__ beta, const float* __restrict__ mean,
               const float* __restrict__ var,
               void* __restrict__ Yv, int N, int Nout, int K1, int K, int O)
{
    __shared__ unsigned short As[64][40];
    __shared__ unsigned short Bs[64][40];

    const int b   = blockIdx.z;
    const int n0  = blockIdx.x * 64;
    const int o0  = blockIdx.y * 64;
    const int tid = threadIdx.x;
    const int lane = tid & 63, wid = tid >> 6;
    const int wr = wid >> 1, wc = wid & 1;

    const unsigned short* Ab  = A + (size_t)b * aStride;
    const int K2 = K - K1;
    const unsigned short* B1b = B1 + (size_t)b * N * K1;
    const unsigned short* B2b = B2 ? (B2 + (size_t)b * N * K2) : nullptr;

    f32x4 acc[2][2];
    #pragma unroll
    for (int i = 0; i < 2; ++i)
        #pragma unroll
        for (int j = 0; j < 2; ++j)
            #pragma unroll
            for (int e = 0; e < 4; ++e) acc[i][j][e] = 0.f;

    const int srow = tid >> 2, sseg = tid & 3;
    const int lr = lane & 15, lk = (lane >> 4) * 8;

    for (int kc = 0; kc < K; kc += 32) {
        const int gk = kc + sseg * 8;
        *(int4*)&As[srow][sseg * 8] =
            *(const int4*)&Ab[(size_t)(o0 + srow) * K + gk];

        const int gn = n0 + srow;
        int4 bv = make_int4(0, 0, 0, 0);
        if (gn < N) {
            if (gk < K1) bv = *(const int4*)&B1b[(size_t)gn * K1 + gk];
            else         bv = *(const int4*)&B2b[(size_t)gn * K2 + (gk - K1)];
        }
        *(int4*)&Bs[srow][sseg * 8] = bv;
        __syncthreads();

        bf16x8 a0 = *(const bf16x8*)&As[wr * 32 +      lr][lk];
        bf16x8 a1 = *(const bf16x8*)&As[wr * 32 + 16 + lr][lk];
        bf16x8 b0 = *(const bf16x8*)&Bs[wc * 32 +      lr][lk];
        bf16x8 b1 = *(const bf16x8*)&Bs[wc * 32 + 16 + lr][lk];

        acc[0][0] = __builtin_amdgcn_mfma_f32_16x16x32_bf16(a0, b0, acc[0][0], 0, 0, 0);
        acc[0][1] = __builtin_amdgcn_mfma_f32_16x16x32_bf16(a0, b1, acc[0][1], 0, 0, 0);
        acc[1][0] = __builtin_amdgcn_mfma_f32_16x16x32_bf16(a1, b0, acc[1][0], 0, 0, 0);
        acc[1][1] = __builtin_amdgcn_mfma_f32_16x16x32_bf16(a1, b1, acc[1][1], 0, 0, 0);
        __syncthreads();
    }

    const int lg = lane >> 4;
    #pragma unroll
    for (int i = 0; i < 2; ++i) {
        const int ob = o0 + wr * 32 + i * 16 + lg * 4;
        float inv[4], sh[4], bi[4];
        if (EPI) {
            #pragma unroll
            for (int r = 0; r < 4; ++r) {
                int o = ob + r;
                float iv = gamma[o] * rsqrtf(var[o] + EPS);
                inv[r] = iv; sh[r] = beta[o] - mean[o] * iv; bi[r] = bias[o];
            }
        }
        #pragma unroll
        for (int j = 0; j < 2; ++j) {
            const int gn = n0 + wc * 32 + j * 16 + lr;
            float v[4];
            #pragma unroll
            for (int r = 0; r < 4; ++r) {
                v[r] = acc[i][j][r];
                if (EPI) v[r] = fmaxf(fmaf(v[r] + bi[r], inv[r], sh[r]), 0.f);
            }
            if (MODE == 0) {
                if (gn < N) {
                    uint2 pk;
                    pk.x = (unsigned)f2bf(v[0]) | ((unsigned)f2bf(v[1]) << 16);
                    pk.y = (unsigned)f2bf(v[2]) | ((unsigned)f2bf(v[3]) << 16);
                    *(uint2*)((unsigned short*)Yv + ((size_t)b * N + gn) * O + ob) = pk;
                }
            } else if (MODE == 1) {
                if (gn < Nout) {
                    #pragma unroll
                    for (int r = 0; r < 4; ++r)
                        ((unsigned short*)Yv)[((size_t)b * O + ob + r) * Nout + gn] =
                            (gn < N) ? f2bf(v[r]) : (unsigned short)0;
                }
            } else {
                if (gn < N) {
                    #pragma unroll
                    for (int r = 0; r < 4; ++r)
                        ((float*)Yv)[((size_t)b * O + ob + r) * N + gn] = v[r];
                }
            }
        }
    }
}

// ---------------------------------------------------------------------------
// Sparsemax rows of S (len Nz), write bf16 scores [rows][NzP] zero-padded.
// ---------------------------------------------------------------------------
__global__ __launch_bounds__(256)
void sparsemax_rows(const float* __restrict__ S, unsigned short* __restrict__ P,
                    int rows)
{
    const int wid  = threadIdx.x >> 6;
    const int lane = threadIdx.x & 63;
    const int row  = blockIdx.x * 4 + wid;
    if (row >= rows) return;

    const float* x = S + (size_t)row * Nz;
    float v[3];
    #pragma unroll
    for (int t = 0; t < 3; ++t) {
        int m = lane + 64 * t;
        v[t] = (m < Nz) ? x[m] : -1e30f;
    }

    float mx = fmaxf(v[0], fmaxf(v[1], v[2]));
    #pragma unroll
    for (int off = 32; off; off >>= 1) mx = fmaxf(mx, __shfl_xor(mx, off));

    float tau = mx - 1.0f;
    for (int it = 0; it < 64; ++it) {
        float s = 0.f, cnt = 0.f;
        #pragma unroll
        for (int t = 0; t < 3; ++t)
            if (v[t] > tau) { s += v[t]; cnt += 1.f; }
        #pragma unroll
        for (int off = 32; off; off >>= 1) {
            s   += __shfl_xor(s, off);
            cnt += __shfl_xor(cnt, off);
        }
        float nt = (s - 1.0f) / cnt;
        if (!(nt > tau)) break;
        tau = nt;
    }

    unsigned short* pr = P + (size_t)row * NzP;
    #pragma unroll
    for (int t = 0; t < 3; ++t) {
        int m = lane + 64 * t;
        float sv = (m < Nz) ? fmaxf(v[t] - tau, 0.f) : 0.f;
        if (m < NzP) pr[m] = f2bf(sv);
    }
}

// ---------------------------------------------------------------------------
extern "C" void kernel_launch(void* const* d_in, const int* in_sizes, int n_in,
                              void* d_out, int out_size, void* d_ws, size_t ws_size,
                              hipStream_t stream)
{
    const float* zf      = (const float*)d_in[0];
    const float* xf      = (const float*)d_in[1];
    const float* Wq      = (const float*)d_in[2];
    const float* bq      = (const float*)d_in[3];
    const float* Ws_     = (const float*)d_in[4];
    const float* bs      = (const float*)d_in[5];
    const float* Wg      = (const float*)d_in[6];
    const float* bg      = (const float*)d_in[7];
    const float* g_gamma = (const float*)d_in[8];
    const float* g_beta  = (const float*)d_in[9];
    const float* g_mean  = (const float*)d_in[10];
    const float* g_var   = (const float*)d_in[11];
    const float* Wf      = (const float*)d_in[12];
    const float* bf_     = (const float*)d_in[13];
    const float* f_gamma = (const float*)d_in[14];
    const float* f_beta  = (const float*)d_in[15];
    const float* f_mean  = (const float*)d_in[16];
    const float* f_var   = (const float*)d_in[17];
    float* out = (float*)d_out;

    typedef unsigned short u16;
    char* ws = (char*)d_ws;
    u16* xfT_hi = (u16*)(ws);                  // 40,960,000  (reused as embT)
    u16* xfT_lo = (u16*)(ws +  40960000);      // 40,960,000 ┐
    u16* zfT_hi = (u16*)(ws +  81920000);      // 11,075,584 ├ sim f32 aliases here
    u16* zfT_lo = (u16*)(ws +  92995584);      // 11,075,584 ┘
    u16* xq_hi  = (u16*)(ws + 104071168);      // 40,960,000  xf_trans split
    u16* xq_lo  = (u16*)(ws + 145031168);      // 40,960,000
    u16* zq_hi  = (u16*)(ws + 185991168);      // 11,075,584  zf_trans split
    u16* zq_lo  = (u16*)(ws + 197066752);      // 11,075,584
    u16* xf_gT  = (u16*)(ws + 208142336);      // 40,960,000
    u16* zf_gP  = (u16*)(ws + 249102336);      // 12,582,912
    u16* scoreP = (u16*)(ws + 261685248);      // 30,720,000
    u16* Wq_hi  = (u16*)(ws + 292405248);      //    131,072
    u16* Wq_lo  = (u16*)(ws + 292536320);
    u16* Ws_hi  = (u16*)(ws + 292667392);
    u16* Ws_lo  = (u16*)(ws + 292798464);
    u16* Wg_bf  = (u16*)(ws + 292929536);
    u16* Wf_bf  = (u16*)(ws + 293060608);      //    262,144  (end 293,322,752)
    float* sim  = (float*)(ws + 40960000);     // 54,080,000 over dead xfT_lo/zfT_*
    u16* embT   = xfT_hi;                      // over dead xfT_hi

    dim3 blk(256);
    const int gx_x = (Nx + 63) / 64;   // 10
    const int gx_z = (Nz + 63) / 64;   // 3

    cvt_weights<<<dim3((C * 2 * C + 255) / 256), blk, 0, stream>>>(
        Wq, Ws_, Wg, Wf, Wq_hi, Wq_lo, Ws_hi, Ws_lo, Wg_bf, Wf_bf);

    x2t_split<<<dim3(gx_x, C / 64, Bb), blk, 0, stream>>>(xf, xfT_hi, xfT_lo, Nx);
    x2t_split<<<dim3(gx_z, C / 64, Bb), blk, 0, stream>>>(zf, zfT_hi, zfT_lo, Nz);

    // sensitive path: split-bf16 MFMA (≈fp32 accuracy)
    mfma_split<0, 1><<<dim3(gx_x, C / 64, Bb), blk, 0, stream>>>(
        Wq_hi, Wq_lo, 0, xfT_hi, xfT_lo, bq, xq_hi, xq_lo, nullptr, Nx, C, C);
    mfma_split<0, 1><<<dim3(gx_z, C / 64, Bb), blk, 0, stream>>>(
        Ws_hi, Ws_lo, 0, zfT_hi, zfT_lo, bs, zq_hi, zq_lo, nullptr, Nz, C, C);

    // tolerant path: g-branch
    mfma_conv<0, 1><<<dim3(gx_x, C / 64, Bb), blk, 0, stream>>>(
        Wg_bf, 0, xfT_hi, nullptr, bg, g_gamma, g_beta, g_mean, g_var,
        xf_gT, Nx, Nx, C, C, C);
    mfma_conv<1, 1><<<dim3(NzP / 64, C / 64, Bb), blk, 0, stream>>>(
        Wg_bf, 0, zfT_hi, nullptr, bg, g_gamma, g_beta, g_mean, g_var,
        zf_gP, Nz, NzP, C, C, C);

    // similar = xf_trans^T zf_trans  (split ×3 MFMA, fp32 out)
    mfma_split<1, 0><<<dim3(gx_z, gx_x, Bb), blk, 0, stream>>>(
        xq_hi, xq_lo, (size_t)Nx * C, zq_hi, zq_lo, nullptr,
        nullptr, nullptr, sim, Nz, C, Nx);

    sparsemax_rows<<<dim3((Bb * Nx + 3) / 4), blk, 0, stream>>>(sim, scoreP, Bb * Nx);

    // embedding = zf_g @ score^T
    mfma_conv<0, 0><<<dim3(gx_x, C / 64, Bb), blk, 0, stream>>>(
        zf_gP, (size_t)C * NzP, scoreP, nullptr,
        nullptr, nullptr, nullptr, nullptr, nullptr,
        embT, Nx, Nx, NzP, NzP, C);

    // out = bn_relu(Wf @ concat(embedding, xf_g))
    mfma_conv<2, 1><<<dim3(gx_x, C / 64, Bb), blk, 0, stream>>>(
        Wf_bf, 0, embT, xf_gT, bf_, f_gamma, f_beta, f_mean, f_var,
        out, Nx, Nx, C, 2 * C, C);
}

// Round 4
// 395.502 us; speedup vs baseline: 3.9773x; 1.2950x over previous
//
#include <hip/hip_runtime.h>
#include <math.h>

#define EPS 1e-5f

constexpr int Bb  = 128;
constexpr int C   = 256;
constexpr int Nz  = 169;   // 13*13
constexpr int Nx  = 625;   // 25*25
constexpr int NzP = 192;   // Nz padded to multiple of 32/64 (zero-filled)

typedef __bf16 bf16x8 __attribute__((ext_vector_type(8)));
typedef float  f32x4  __attribute__((ext_vector_type(4)));

__device__ __forceinline__ unsigned short f2bf(float f) {
    union { float f; unsigned u; } x; x.f = f;
    unsigned r = x.u + 0x7FFFu + ((x.u >> 16) & 1u);   // RNE
    return (unsigned short)(r >> 16);
}
__device__ __forceinline__ float bf2f(unsigned short h) {
    union { unsigned u; float f; } x; x.u = ((unsigned)h) << 16;
    return x.f;
}

// ---------------------------------------------------------------------------
// Wg, Wf → bf16
// ---------------------------------------------------------------------------
__global__ void cvt_wgf(const float* __restrict__ Wg, const float* __restrict__ Wf,
                        unsigned short* __restrict__ g, unsigned short* __restrict__ f)
{
    int i = blockIdx.x * 256 + threadIdx.x;
    if (i < C * C) g[i] = f2bf(Wg[i]);
    if (i < C * 2 * C) f[i] = f2bf(Wf[i]);
}

// ---------------------------------------------------------------------------
// wv = Wq^T bs, wu = Ws^T bq, c0 = bq.bs   (one block, 256 threads)
// ---------------------------------------------------------------------------
__global__ void prep_small(const float* __restrict__ Wq, const float* __restrict__ Ws,
                           const float* __restrict__ bq, const float* __restrict__ bs,
                           float* __restrict__ wv, float* __restrict__ wu,
                           float* __restrict__ c0)
{
    const int tid = threadIdx.x;
    float a = 0.f, b = 0.f;
    for (int o = 0; o < C; ++o) {
        a += Wq[o * C + tid] * bs[o];
        b += Ws[o * C + tid] * bq[o];
    }
    wv[tid] = a;
    wu[tid] = b;
    if (tid == 0) {
        float c = 0.f;
        for (int o = 0; o < C; ++o) c += bq[o] * bs[o];
        c0[0] = c;
    }
}

// ---------------------------------------------------------------------------
// M = Wq^T Ws  (fp32 compute, split bf16 hi/lo output).  grid (4,4)
// M[i,j] = sum_o Wq[o,i] * Ws[o,j]
// ---------------------------------------------------------------------------
__global__ __launch_bounds__(256)
void m_gemm(const float* __restrict__ Wq, const float* __restrict__ Ws,
            unsigned short* __restrict__ Mhi, unsigned short* __restrict__ Mlo)
{
    __shared__ float Qs[16][65], Ss[16][65];
    const int j0 = blockIdx.x * 64, i0 = blockIdx.y * 64;
    const int tid = threadIdx.x, tx = tid & 15, ty = tid >> 4;
    float acc[4][4] = {};

    for (int kc = 0; kc < C; kc += 16) {
        #pragma unroll
        for (int i = 0; i < 4; ++i) {
            int e = tid + 256 * i;
            int k = e >> 6, col = e & 63;
            Qs[k][col] = Wq[(size_t)(kc + k) * C + i0 + col];
            Ss[k][col] = Ws[(size_t)(kc + k) * C + j0 + col];
        }
        __syncthreads();
        #pragma unroll
        for (int k = 0; k < 16; ++k) {
            float a[4], bv[4];
            #pragma unroll
            for (int i = 0; i < 4; ++i) a[i] = Qs[k][ty * 4 + i];
            #pragma unroll
            for (int j = 0; j < 4; ++j) bv[j] = Ss[k][tx * 4 + j];
            #pragma unroll
            for (int i = 0; i < 4; ++i)
                #pragma unroll
                for (int j = 0; j < 4; ++j)
                    acc[i][j] = fmaf(a[i], bv[j], acc[i][j]);
        }
        __syncthreads();
    }
    #pragma unroll
    for (int i = 0; i < 4; ++i)
        #pragma unroll
        for (int j = 0; j < 4; ++j) {
            float v = acc[i][j];
            unsigned short h = f2bf(v);
            size_t idx = (size_t)(i0 + ty * 4 + i) * C + j0 + tx * 4 + j;
            Mhi[idx] = h;
            Mlo[idx] = f2bf(v - bf2f(h));
        }
}

// ---------------------------------------------------------------------------
// u[b,m] = wu . zf[b,:,m] + c0   for m < Nz, 0 beyond.  grid (Bb), block 256
// ---------------------------------------------------------------------------
__global__ void bias_u(const float* __restrict__ zf, const float* __restrict__ wu,
                       const float* __restrict__ c0, float* __restrict__ U)
{
    const int b = blockIdx.x, m = threadIdx.x;
    if (m >= NzP) return;
    float s = 0.f;
    if (m < Nz) {
        s = c0[0];
        const float* zb = zf + (size_t)b * C * Nz + m;
        for (int c = 0; c < C; ++c) s += wu[c] * zb[(size_t)c * Nz];
    }
    U[(size_t)b * NzP + m] = s;
}

// ---------------------------------------------------------------------------
// X [b][C][N] f32  →  hi/lo bf16 [b][N][C]  (k-major rows for MFMA operands)
// ---------------------------------------------------------------------------
__global__ __launch_bounds__(256)
void x2t_split(const float* __restrict__ X, unsigned short* __restrict__ Hi,
               unsigned short* __restrict__ Lo, int N)
{
    __shared__ float T[64][65];
    const int b = blockIdx.z, n0 = blockIdx.x * 64, c0 = blockIdx.y * 64;
    const float* Xb = X + ((size_t)b * C + c0) * N;
    #pragma unroll
    for (int i = 0; i < 16; ++i) {
        int e = threadIdx.x + 256 * i;
        int c = e >> 6, n = e & 63;
        T[c][n] = (n0 + n < N) ? Xb[(size_t)c * N + n0 + n] : 0.f;
    }
    __syncthreads();
    #pragma unroll
    for (int i = 0; i < 16; ++i) {
        int e = threadIdx.x + 256 * i;
        int n = e >> 6, c = e & 63;
        if (n0 + n < N) {
            float v = T[c][n];
            unsigned short h = f2bf(v);
            size_t idx = ((size_t)b * N + n0 + n) * C + c0 + c;
            Hi[idx] = h;
            Lo[idx] = f2bf(v - bf2f(h));
        }
    }
}

// ---------------------------------------------------------------------------
// Split-bf16 MFMA GEMM (sensitive path), here used for zq' = M zf + wv.
//   D[b,o,n] = sum_k A(o,k)*B(b,n,k); A=Ah+Al (aStride batches, 0 = shared)
// Writes split bf16 [b][Nout][O]; rows n in [N,Nout) zero-filled.
// ---------------------------------------------------------------------------
__global__ __launch_bounds__(256)
void mfma_split(const unsigned short* __restrict__ Ahi,
                const unsigned short* __restrict__ Alo, size_t aStride,
                const unsigned short* __restrict__ Bhi,
                const unsigned short* __restrict__ Blo,
                const float* __restrict__ bias,
                unsigned short* __restrict__ Yhi, unsigned short* __restrict__ Ylo,
                int N, int Nout, int K, int O)
{
    __shared__ unsigned short Ah[64][40], Al[64][40], Bh[64][40], Bl[64][40];

    const int b   = blockIdx.z;
    const int n0  = blockIdx.x * 64;
    const int o0  = blockIdx.y * 64;
    const int tid = threadIdx.x;
    const int lane = tid & 63, wid = tid >> 6;
    const int wr = wid >> 1, wc = wid & 1;

    const unsigned short* Ahb = Ahi + (size_t)b * aStride;
    const unsigned short* Alb = Alo + (size_t)b * aStride;
    const unsigned short* Bhb = Bhi + (size_t)b * N * K;
    const unsigned short* Blb = Blo + (size_t)b * N * K;

    f32x4 acc[2][2];
    #pragma unroll
    for (int i = 0; i < 2; ++i)
        #pragma unroll
        for (int j = 0; j < 2; ++j)
            #pragma unroll
            for (int e = 0; e < 4; ++e) acc[i][j][e] = 0.f;

    const int srow = tid >> 2, sseg = tid & 3;
    const int lr = lane & 15, lk = (lane >> 4) * 8;

    for (int kc = 0; kc < K; kc += 32) {
        const int gk = kc + sseg * 8;
        *(int4*)&Ah[srow][sseg * 8] = *(const int4*)&Ahb[(size_t)(o0 + srow) * K + gk];
        *(int4*)&Al[srow][sseg * 8] = *(const int4*)&Alb[(size_t)(o0 + srow) * K + gk];

        const int gn = n0 + srow;
        int4 bv = make_int4(0, 0, 0, 0), blv = make_int4(0, 0, 0, 0);
        if (gn < N) {
            bv  = *(const int4*)&Bhb[(size_t)gn * K + gk];
            blv = *(const int4*)&Blb[(size_t)gn * K + gk];
        }
        *(int4*)&Bh[srow][sseg * 8] = bv;
        *(int4*)&Bl[srow][sseg * 8] = blv;
        __syncthreads();

        bf16x8 ah[2], al[2], bh[2], bl[2];
        #pragma unroll
        for (int i = 0; i < 2; ++i) {
            ah[i] = *(const bf16x8*)&Ah[wr * 32 + i * 16 + lr][lk];
            al[i] = *(const bf16x8*)&Al[wr * 32 + i * 16 + lr][lk];
            bh[i] = *(const bf16x8*)&Bh[wc * 32 + i * 16 + lr][lk];
            bl[i] = *(const bf16x8*)&Bl[wc * 32 + i * 16 + lr][lk];
        }
        #pragma unroll
        for (int i = 0; i < 2; ++i)
            #pragma unroll
            for (int j = 0; j < 2; ++j) {
                acc[i][j] = __builtin_amdgcn_mfma_f32_16x16x32_bf16(al[i], bh[j], acc[i][j], 0, 0, 0);
                acc[i][j] = __builtin_amdgcn_mfma_f32_16x16x32_bf16(ah[i], bl[j], acc[i][j], 0, 0, 0);
                acc[i][j] = __builtin_amdgcn_mfma_f32_16x16x32_bf16(ah[i], bh[j], acc[i][j], 0, 0, 0);
            }
        __syncthreads();
    }

    const int lg = lane >> 4;
    #pragma unroll
    for (int i = 0; i < 2; ++i) {
        const int ob = o0 + wr * 32 + i * 16 + lg * 4;
        float bi[4];
        #pragma unroll
        for (int r = 0; r < 4; ++r) bi[r] = bias[ob + r];
        #pragma unroll
        for (int j = 0; j < 2; ++j) {
            const int gn = n0 + wc * 32 + j * 16 + lr;
            if (gn < Nout) {
                uint2 ph = make_uint2(0, 0), pl = make_uint2(0, 0);
                if (gn < N) {
                    unsigned short h[4], l[4];
                    #pragma unroll
                    for (int r = 0; r < 4; ++r) {
                        float v = acc[i][j][r] + bi[r];
                        h[r] = f2bf(v);
                        l[r] = f2bf(v - bf2f(h[r]));
                    }
                    ph.x = (unsigned)h[0] | ((unsigned)h[1] << 16);
                    ph.y = (unsigned)h[2] | ((unsigned)h[3] << 16);
                    pl.x = (unsigned)l[0] | ((unsigned)l[1] << 16);
                    pl.y = (unsigned)l[2] | ((unsigned)l[3] << 16);
                }
                size_t idx = ((size_t)b * Nout + gn) * O + ob;
                *(uint2*)&Yhi[idx] = ph;
                *(uint2*)&Ylo[idx] = pl;
            }
        }
    }
}

// ---------------------------------------------------------------------------
// Plain bf16 MFMA GEMM (tolerant path): g-convs and zg2.
// D[b,o,n] = sum_k A(o,k (lda aLd)) * B1(b,n,k)   (+ bias/BN/ReLU)
// MODE 0: write [b][Nout][O] bf16 (rows [N,Nout) zeroed)
// MODE 1: write [b][O][Nout] bf16
// EPI  1: bias + BN + ReLU
// ---------------------------------------------------------------------------
template<int MODE, int EPI>
__global__ __launch_bounds__(256)
void mfma_conv(const unsigned short* __restrict__ A, int aLd, size_t aStride,
               const unsigned short* __restrict__ B1,
               const float* __restrict__ bias, const float* __restrict__ gamma,
               const float* __restrict__ beta, const float* __restrict__ mean,
               const float* __restrict__ var,
               unsigned short* __restrict__ Y, int N, int Nout, int K, int O)
{
    __shared__ unsigned short As[64][40];
    __shared__ unsigned short Bs[64][40];

    const int b   = blockIdx.z;
    const int n0  = blockIdx.x * 64;
    const int o0  = blockIdx.y * 64;
    const int tid = threadIdx.x;
    const int lane = tid & 63, wid = tid >> 6;
    const int wr = wid >> 1, wc = wid & 1;

    const unsigned short* Ab  = A + (size_t)b * aStride;
    const unsigned short* B1b = B1 + (size_t)b * N * K;

    f32x4 acc[2][2];
    #pragma unroll
    for (int i = 0; i < 2; ++i)
        #pragma unroll
        for (int j = 0; j < 2; ++j)
            #pragma unroll
            for (int e = 0; e < 4; ++e) acc[i][j][e] = 0.f;

    const int srow = tid >> 2, sseg = tid & 3;
    const int lr = lane & 15, lk = (lane >> 4) * 8;

    for (int kc = 0; kc < K; kc += 32) {
        const int gk = kc + sseg * 8;
        *(int4*)&As[srow][sseg * 8] = *(const int4*)&Ab[(size_t)(o0 + srow) * aLd + gk];

        const int gn = n0 + srow;
        int4 bv = make_int4(0, 0, 0, 0);
        if (gn < N) bv = *(const int4*)&B1b[(size_t)gn * K + gk];
        *(int4*)&Bs[srow][sseg * 8] = bv;
        __syncthreads();

        bf16x8 a0 = *(const bf16x8*)&As[wr * 32 +      lr][lk];
        bf16x8 a1 = *(const bf16x8*)&As[wr * 32 + 16 + lr][lk];
        bf16x8 b0 = *(const bf16x8*)&Bs[wc * 32 +      lr][lk];
        bf16x8 b1 = *(const bf16x8*)&Bs[wc * 32 + 16 + lr][lk];

        acc[0][0] = __builtin_amdgcn_mfma_f32_16x16x32_bf16(a0, b0, acc[0][0], 0, 0, 0);
        acc[0][1] = __builtin_amdgcn_mfma_f32_16x16x32_bf16(a0, b1, acc[0][1], 0, 0, 0);
        acc[1][0] = __builtin_amdgcn_mfma_f32_16x16x32_bf16(a1, b0, acc[1][0], 0, 0, 0);
        acc[1][1] = __builtin_amdgcn_mfma_f32_16x16x32_bf16(a1, b1, acc[1][1], 0, 0, 0);
        __syncthreads();
    }

    const int lg = lane >> 4;
    #pragma unroll
    for (int i = 0; i < 2; ++i) {
        const int ob = o0 + wr * 32 + i * 16 + lg * 4;
        float inv[4], sh[4], bi[4];
        if (EPI) {
            #pragma unroll
            for (int r = 0; r < 4; ++r) {
                int o = ob + r;
                float iv = gamma[o] * rsqrtf(var[o] + EPS);
                inv[r] = iv; sh[r] = beta[o] - mean[o] * iv; bi[r] = bias[o];
            }
        }
        #pragma unroll
        for (int j = 0; j < 2; ++j) {
            const int gn = n0 + wc * 32 + j * 16 + lr;
            float v[4];
            #pragma unroll
            for (int r = 0; r < 4; ++r) {
                v[r] = acc[i][j][r];
                if (EPI) v[r] = fmaxf(fmaf(v[r] + bi[r], inv[r], sh[r]), 0.f);
            }
            if (MODE == 0) {
                if (gn < Nout) {
                    uint2 pk = make_uint2(0, 0);
                    if (gn < N) {
                        pk.x = (unsigned)f2bf(v[0]) | ((unsigned)f2bf(v[1]) << 16);
                        pk.y = (unsigned)f2bf(v[2]) | ((unsigned)f2bf(v[3]) << 16);
                    }
                    *(uint2*)&Y[((size_t)b * Nout + gn) * O + ob] = pk;
                }
            } else {
                if (gn < Nout) {
                    #pragma unroll
                    for (int r = 0; r < 4; ++r)
                        Y[((size_t)b * O + ob + r) * Nout + gn] =
                            (gn < N) ? f2bf(v[r]) : (unsigned short)0;
                }
            }
        }
    }
}

// ---------------------------------------------------------------------------
// Fused sim + sparsemax:
//   sim[n,m] = xf_n . zq'_m (split x3 MFMA) + u[m];  sparsemax over m (169);
//   write bf16 scores [b][Nx][NzP].
// Block: 64 n-rows x 192 m (full row). Wave w owns 16 n-rows.
// ---------------------------------------------------------------------------
__global__ __launch_bounds__(256)
void sim_sparsemax(const unsigned short* __restrict__ Ahi,   // xfT hi [b][Nx][C]
                   const unsigned short* __restrict__ Alo,
                   const unsigned short* __restrict__ Bhi,   // zqT hi [b][NzP][C]
                   const unsigned short* __restrict__ Blo,
                   const float* __restrict__ U,              // [b][NzP]
                   unsigned short* __restrict__ P)           // [b][Nx][NzP]
{
    __shared__ unsigned short Ah[64][40], Al[64][40];
    __shared__ unsigned short Bh[192][40], Bl[192][40];
    __shared__ float Us[192];

    const int b  = blockIdx.z, n0 = blockIdx.x * 64;
    const int tid = threadIdx.x, lane = tid & 63, w = tid >> 6;
    const int lr = lane & 15, lg = lane >> 4, lk = lg * 8;

    const unsigned short* Ahb = Ahi + (size_t)b * Nx * C;
    const unsigned short* Alb = Alo + (size_t)b * Nx * C;
    const unsigned short* Bhb = Bhi + (size_t)b * NzP * C;
    const unsigned short* Blb = Blo + (size_t)b * NzP * C;

    if (tid < 192) Us[tid] = U[(size_t)b * NzP + tid];

    f32x4 acc[12];
    #pragma unroll
    for (int j = 0; j < 12; ++j)
        #pragma unroll
        for (int e = 0; e < 4; ++e) acc[j][e] = 0.f;

    const int arow = tid >> 2, aseg = tid & 3;

    for (int kc = 0; kc < C; kc += 32) {
        // stage A (64 rows x 32 k, hi+lo)
        {
            const int gk = kc + aseg * 8;
            const int gn = n0 + arow;
            int4 av = make_int4(0, 0, 0, 0), alv = make_int4(0, 0, 0, 0);
            if (gn < Nx) {
                av  = *(const int4*)&Ahb[(size_t)gn * C + gk];
                alv = *(const int4*)&Alb[(size_t)gn * C + gk];
            }
            *(int4*)&Ah[arow][aseg * 8] = av;
            *(int4*)&Al[arow][aseg * 8] = alv;
        }
        // stage B (192 rows x 32 k, hi+lo) — 3 slots per thread
        #pragma unroll
        for (int i = 0; i < 3; ++i) {
            const int slot = tid + 256 * i;
            const int brow = slot >> 2, bseg = slot & 3;
            const int gk = kc + bseg * 8;
            *(int4*)&Bh[brow][bseg * 8] = *(const int4*)&Bhb[(size_t)brow * C + gk];
            *(int4*)&Bl[brow][bseg * 8] = *(const int4*)&Blb[(size_t)brow * C + gk];
        }
        __syncthreads();

        bf16x8 a0h = *(const bf16x8*)&Ah[w * 16 + lr][lk];
        bf16x8 a0l = *(const bf16x8*)&Al[w * 16 + lr][lk];
        #pragma unroll
        for (int j = 0; j < 12; ++j) {
            bf16x8 bh = *(const bf16x8*)&Bh[j * 16 + lr][lk];
            bf16x8 bl = *(const bf16x8*)&Bl[j * 16 + lr][lk];
            acc[j] = __builtin_amdgcn_mfma_f32_16x16x32_bf16(a0l, bh, acc[j], 0, 0, 0);
            acc[j] = __builtin_amdgcn_mfma_f32_16x16x32_bf16(a0h, bl, acc[j], 0, 0, 0);
            acc[j] = __builtin_amdgcn_mfma_f32_16x16x32_bf16(a0h, bh, acc[j], 0, 0, 0);
        }
        __syncthreads();
    }

    // add u[m]; mask padded m. acc[j][q]: n = n0+16w+4lg+q, m = 16j+lr.
    #pragma unroll
    for (int j = 0; j < 12; ++j) {
        const int m = j * 16 + lr;
        const float uv = Us[m];
        const bool bad = (m >= Nz);
        #pragma unroll
        for (int q = 0; q < 4; ++q)
            acc[j][q] = bad ? -1e30f : (acc[j][q] + uv);
    }

    // row max (over 12 regs, then 16 lanes sharing lg)
    f32x4 mx = acc[0];
    #pragma unroll
    for (int j = 1; j < 12; ++j)
        #pragma unroll
        for (int q = 0; q < 4; ++q) mx[q] = fmaxf(mx[q], acc[j][q]);
    #pragma unroll
    for (int off = 1; off < 16; off <<= 1)
        #pragma unroll
        for (int q = 0; q < 4; ++q) mx[q] = fmaxf(mx[q], __shfl_xor(mx[q], off));

    // Newton on tau: sum(max(x - tau, 0)) = 1
    f32x4 tau;
    #pragma unroll
    for (int q = 0; q < 4; ++q) tau[q] = mx[q] - 1.0f;

    for (int it = 0; it < 16; ++it) {
        f32x4 s, cnt;
        #pragma unroll
        for (int q = 0; q < 4; ++q) { s[q] = 0.f; cnt[q] = 0.f; }
        #pragma unroll
        for (int j = 0; j < 12; ++j)
            #pragma unroll
            for (int q = 0; q < 4; ++q)
                if (acc[j][q] > tau[q]) { s[q] += acc[j][q]; cnt[q] += 1.f; }
        #pragma unroll
        for (int off = 1; off < 16; off <<= 1)
            #pragma unroll
            for (int q = 0; q < 4; ++q) {
                s[q]   += __shfl_xor(s[q], off);
                cnt[q] += __shfl_xor(cnt[q], off);
            }
        bool adv = false;
        #pragma unroll
        for (int q = 0; q < 4; ++q) {
            float nt = (s[q] - 1.0f) / cnt[q];
            if (nt > tau[q]) { tau[q] = nt; adv = true; }
        }
        if (!__any(adv ? 1 : 0)) break;
    }

    // write scores
    unsigned short* Pb = P + (size_t)b * Nx * NzP;
    #pragma unroll
    for (int q = 0; q < 4; ++q) {
        const int n = n0 + w * 16 + 4 * lg + q;
        if (n < Nx) {
            #pragma unroll
            for (int j = 0; j < 12; ++j) {
                const int m = j * 16 + lr;
                float sv = (m < Nz) ? fmaxf(acc[j][q] - tau[q], 0.f) : 0.f;
                Pb[(size_t)n * NzP + m] = f2bf(sv);
            }
        }
    }
}

// ---------------------------------------------------------------------------
// Fused final: out[b,o,n] = bn_relu( sum_m zg2[b,o,m]*score[b,n,m]
//                                  + sum_k Wf2[o,k]*xf_g[b,n,k] + bf )
// Two K-phases: K1=NzP (batched A=zg2), K2=C (shared A=Wf2, lda 512).
// ---------------------------------------------------------------------------
__global__ __launch_bounds__(256)
void final_conv(const unsigned short* __restrict__ Zg2,   // [b][C][NzP]
                const unsigned short* __restrict__ Sc,    // [b][Nx][NzP]
                const unsigned short* __restrict__ Wf2,   // [C][512] base+256
                const unsigned short* __restrict__ Xg,    // [b][Nx][C]
                const float* __restrict__ bias, const float* __restrict__ gamma,
                const float* __restrict__ beta, const float* __restrict__ mean,
                const float* __restrict__ var,
                float* __restrict__ out)
{
    __shared__ unsigned short As[64][40];
    __shared__ unsigned short Bs[64][40];

    const int b   = blockIdx.z;
    const int n0  = blockIdx.x * 64;
    const int o0  = blockIdx.y * 64;
    const int tid = threadIdx.x;
    const int lane = tid & 63, wid = tid >> 6;
    const int wr = wid >> 1, wc = wid & 1;

    const unsigned short* Azg = Zg2 + (size_t)b * C * NzP;
    const unsigned short* Bsc = Sc  + (size_t)b * Nx * NzP;
    const unsigned short* Bxg = Xg  + (size_t)b * Nx * C;

    f32x4 acc[2][2];
    #pragma unroll
    for (int i = 0; i < 2; ++i)
        #pragma unroll
        for (int j = 0; j < 2; ++j)
            #pragma unroll
            for (int e = 0; e < 4; ++e) acc[i][j][e] = 0.f;

    const int srow = tid >> 2, sseg = tid & 3;
    const int lr = lane & 15, lk = (lane >> 4) * 8;

    for (int kc = 0; kc < NzP + C; kc += 32) {
        const int gn = n0 + srow;
        int4 av, bv = make_int4(0, 0, 0, 0);
        if (kc < NzP) {
            const int gk = kc + sseg * 8;
            av = *(const int4*)&Azg[(size_t)(o0 + srow) * NzP + gk];
            if (gn < Nx) bv = *(const int4*)&Bsc[(size_t)gn * NzP + gk];
        } else {
            const int gk = kc - NzP + sseg * 8;
            av = *(const int4*)&Wf2[(size_t)(o0 + srow) * 512 + gk];
            if (gn < Nx) bv = *(const int4*)&Bxg[(size_t)gn * C + gk];
        }
        *(int4*)&As[srow][sseg * 8] = av;
        *(int4*)&Bs[srow][sseg * 8] = bv;
        __syncthreads();

        bf16x8 a0 = *(const bf16x8*)&As[wr * 32 +      lr][lk];
        bf16x8 a1 = *(const bf16x8*)&As[wr * 32 + 16 + lr][lk];
        bf16x8 b0 = *(const bf16x8*)&Bs[wc * 32 +      lr][lk];
        bf16x8 b1 = *(const bf16x8*)&Bs[wc * 32 + 16 + lr][lk];

        acc[0][0] = __builtin_amdgcn_mfma_f32_16x16x32_bf16(a0, b0, acc[0][0], 0, 0, 0);
        acc[0][1] = __builtin_amdgcn_mfma_f32_16x16x32_bf16(a0, b1, acc[0][1], 0, 0, 0);
        acc[1][0] = __builtin_amdgcn_mfma_f32_16x16x32_bf16(a1, b0, acc[1][0], 0, 0, 0);
        acc[1][1] = __builtin_amdgcn_mfma_f32_16x16x32_bf16(a1, b1, acc[1][1], 0, 0, 0);
        __syncthreads();
    }

    const int lg = lane >> 4;
    #pragma unroll
    for (int i = 0; i < 2; ++i) {
        const int ob = o0 + wr * 32 + i * 16 + lg * 4;
        float inv[4], sh[4], bi[4];
        #pragma unroll
        for (int r = 0; r < 4; ++r) {
            int o = ob + r;
            float iv = gamma[o] * rsqrtf(var[o] + EPS);
            inv[r] = iv; sh[r] = beta[o] - mean[o] * iv; bi[r] = bias[o];
        }
        #pragma unroll
        for (int j = 0; j < 2; ++j) {
            const int gn = n0 + wc * 32 + j * 16 + lr;
            if (gn < Nx) {
                #pragma unroll
                for (int r = 0; r < 4; ++r) {
                    float v = fmaxf(fmaf(acc[i][j][r] + bi[r], inv[r], sh[r]), 0.f);
                    out[((size_t)b * C + ob + r) * Nx + gn] = v;
                }
            }
        }
    }
}

// ---------------------------------------------------------------------------
extern "C" void kernel_launch(void* const* d_in, const int* in_sizes, int n_in,
                              void* d_out, int out_size, void* d_ws, size_t ws_size,
                              hipStream_t stream)
{
    const float* zf      = (const float*)d_in[0];
    const float* xf      = (const float*)d_in[1];
    const float* Wq      = (const float*)d_in[2];
    const float* bq      = (const float*)d_in[3];
    const float* Ws_     = (const float*)d_in[4];
    const float* bs      = (const float*)d_in[5];
    const float* Wg      = (const float*)d_in[6];
    const float* bg      = (const float*)d_in[7];
    const float* g_gamma = (const float*)d_in[8];
    const float* g_beta  = (const float*)d_in[9];
    const float* g_mean  = (const float*)d_in[10];
    const float* g_var   = (const float*)d_in[11];
    const float* Wf      = (const float*)d_in[12];
    const float* bf_     = (const float*)d_in[13];
    const float* f_gamma = (const float*)d_in[14];
    const float* f_beta  = (const float*)d_in[15];
    const float* f_mean  = (const float*)d_in[16];
    const float* f_var   = (const float*)d_in[17];
    float* out = (float*)d_out;

    typedef unsigned short u16;
    char* ws = (char*)d_ws;
    u16*   xfT_hi = (u16*)(ws);                   //  40,960,000
    u16*   xfT_lo = (u16*)(ws +  40960000);       //  40,960,000
    u16*   zfT_hi = (u16*)(ws +  81920000);       //  11,075,584
    u16*   zfT_lo = (u16*)(ws +  92995584);       //  11,075,584
    u16*   zqT_hi = (u16*)(ws + 104071168);       //  12,582,912
    u16*   zqT_lo = (u16*)(ws + 116654080);       //  12,582,912
    u16*   xf_gT  = (u16*)(ws + 129236992);       //  40,960,000
    u16*   zf_gT  = (u16*)(ws + 170196992);       //  12,582,912
    u16*   zg2    = (u16*)(ws + 182779904);       //  12,582,912
    u16*   scoreP = (u16*)(ws + 195362816);       //  30,720,000
    float* U      = (float*)(ws + 226082816);     //      98,304
    u16*   Mhi    = (u16*)(ws + 226181120);       //     131,072
    u16*   Mlo    = (u16*)(ws + 226312192);       //     131,072
    u16*   Wg_bf  = (u16*)(ws + 226443264);       //     131,072
    u16*   Wf_bf  = (u16*)(ws + 226574336);       //     262,144
    float* wv     = (float*)(ws + 226836480);     //       1,024
    float* wu     = (float*)(ws + 226837504);     //       1,024
    float* c0     = (float*)(ws + 226838528);     //         256

    dim3 blk(256);
    const int gx_x = (Nx + 63) / 64;   // 10
    const int gx_z = NzP / 64;         // 3

    // small precomputes
    cvt_wgf<<<dim3((C * 2 * C + 255) / 256), blk, 0, stream>>>(Wg, Wf, Wg_bf, Wf_bf);
    prep_small<<<dim3(1), blk, 0, stream>>>(Wq, Ws_, bq, bs, wv, wu, c0);
    m_gemm<<<dim3(4, 4), blk, 0, stream>>>(Wq, Ws_, Mhi, Mlo);
    bias_u<<<dim3(Bb), blk, 0, stream>>>(zf, wu, c0, U);

    // input transposes/splits
    x2t_split<<<dim3(gx_x, C / 64, Bb), blk, 0, stream>>>(xf, xfT_hi, xfT_lo, Nx);
    x2t_split<<<dim3((Nz + 63) / 64, C / 64, Bb), blk, 0, stream>>>(zf, zfT_hi, zfT_lo, Nz);

    // zq' = M zf + wv  (split, z-side)
    mfma_split<<<dim3(gx_z, C / 64, Bb), blk, 0, stream>>>(
        Mhi, Mlo, 0, zfT_hi, zfT_lo, wv, zqT_hi, zqT_lo, Nz, NzP, C, C);

    // g-branch (tolerant)
    mfma_conv<0, 1><<<dim3(gx_x, C / 64, Bb), blk, 0, stream>>>(
        Wg_bf, C, 0, xfT_hi, bg, g_gamma, g_beta, g_mean, g_var,
        xf_gT, Nx, Nx, C, C);
    mfma_conv<0, 1><<<dim3(gx_z, C / 64, Bb), blk, 0, stream>>>(
        Wg_bf, C, 0, zfT_hi, bg, g_gamma, g_beta, g_mean, g_var,
        zf_gT, Nz, NzP, C, C);

    // zg2 = Wf1 . zf_g   -> [b][C][NzP] bf16
    mfma_conv<1, 0><<<dim3(gx_z, C / 64, Bb), blk, 0, stream>>>(
        Wf_bf, 2 * C, 0, zf_gT, nullptr, nullptr, nullptr, nullptr, nullptr,
        zg2, NzP, NzP, C, C);

    // fused similar + sparsemax -> scoreP
    sim_sparsemax<<<dim3(gx_x, 1, Bb), blk, 0, stream>>>(
        xfT_hi, xfT_lo, zqT_hi, zqT_lo, U, scoreP);

    // fused final conv
    final_conv<<<dim3(gx_x, C / 64, Bb), blk, 0, stream>>>(
        zg2, scoreP, Wf_bf + C, xf_gT, bf_, f_gamma, f_beta, f_mean, f_var, out);
}

// Round 5
// 365.032 us; speedup vs baseline: 4.3093x; 1.0835x over previous
//
#include <hip/hip_runtime.h>
#include <math.h>

#define EPS 1e-5f

constexpr int Bb  = 128;
constexpr int C   = 256;
constexpr int Nz  = 169;   // 13*13
constexpr int Nx  = 625;   // 25*25
constexpr int NzP = 192;   // Nz padded to multiple of 32/64 (zero-filled)

typedef __bf16 bf16x8 __attribute__((ext_vector_type(8)));
typedef float  f32x4  __attribute__((ext_vector_type(4)));

__device__ __forceinline__ unsigned short f2bf(float f) {
    union { float f; unsigned u; } x; x.f = f;
    unsigned r = x.u + 0x7FFFu + ((x.u >> 16) & 1u);   // RNE
    return (unsigned short)(r >> 16);
}
__device__ __forceinline__ float bf2f(unsigned short h) {
    union { unsigned u; float f; } x; x.u = ((unsigned)h) << 16;
    return x.f;
}

// ---------------------------------------------------------------------------
// Wg, Wf → bf16
// ---------------------------------------------------------------------------
__global__ void cvt_wgf(const float* __restrict__ Wg, const float* __restrict__ Wf,
                        unsigned short* __restrict__ g, unsigned short* __restrict__ f)
{
    int i = blockIdx.x * 256 + threadIdx.x;
    if (i < C * C) g[i] = f2bf(Wg[i]);
    if (i < C * 2 * C) f[i] = f2bf(Wf[i]);
}

// ---------------------------------------------------------------------------
// wv = Wq^T bs, wu = Ws^T bq, c0 = bq.bs   (one block, 256 threads)
// ---------------------------------------------------------------------------
__global__ void prep_small(const float* __restrict__ Wq, const float* __restrict__ Ws,
                           const float* __restrict__ bq, const float* __restrict__ bs,
                           float* __restrict__ wv, float* __restrict__ wu,
                           float* __restrict__ c0)
{
    const int tid = threadIdx.x;
    float a = 0.f, b = 0.f;
    for (int o = 0; o < C; ++o) {
        a += Wq[o * C + tid] * bs[o];
        b += Ws[o * C + tid] * bq[o];
    }
    wv[tid] = a;
    wu[tid] = b;
    if (tid == 0) {
        float c = 0.f;
        for (int o = 0; o < C; ++o) c += bq[o] * bs[o];
        c0[0] = c;
    }
}

// ---------------------------------------------------------------------------
// M = Wq^T Ws  (fp32 compute, split bf16 hi/lo output).  grid (4,4)
// ---------------------------------------------------------------------------
__global__ __launch_bounds__(256)
void m_gemm(const float* __restrict__ Wq, const float* __restrict__ Ws,
            unsigned short* __restrict__ Mhi, unsigned short* __restrict__ Mlo)
{
    __shared__ float Qs[16][65], Ss[16][65];
    const int j0 = blockIdx.x * 64, i0 = blockIdx.y * 64;
    const int tid = threadIdx.x, tx = tid & 15, ty = tid >> 4;
    float acc[4][4] = {};

    for (int kc = 0; kc < C; kc += 16) {
        #pragma unroll
        for (int i = 0; i < 4; ++i) {
            int e = tid + 256 * i;
            int k = e >> 6, col = e & 63;
            Qs[k][col] = Wq[(size_t)(kc + k) * C + i0 + col];
            Ss[k][col] = Ws[(size_t)(kc + k) * C + j0 + col];
        }
        __syncthreads();
        #pragma unroll
        for (int k = 0; k < 16; ++k) {
            float a[4], bv[4];
            #pragma unroll
            for (int i = 0; i < 4; ++i) a[i] = Qs[k][ty * 4 + i];
            #pragma unroll
            for (int j = 0; j < 4; ++j) bv[j] = Ss[k][tx * 4 + j];
            #pragma unroll
            for (int i = 0; i < 4; ++i)
                #pragma unroll
                for (int j = 0; j < 4; ++j)
                    acc[i][j] = fmaf(a[i], bv[j], acc[i][j]);
        }
        __syncthreads();
    }
    #pragma unroll
    for (int i = 0; i < 4; ++i)
        #pragma unroll
        for (int j = 0; j < 4; ++j) {
            float v = acc[i][j];
            unsigned short h = f2bf(v);
            size_t idx = (size_t)(i0 + ty * 4 + i) * C + j0 + tx * 4 + j;
            Mhi[idx] = h;
            Mlo[idx] = f2bf(v - bf2f(h));
        }
}

// ---------------------------------------------------------------------------
// u[b,m] = wu . zf[b,:,m] + c0   for m < Nz, 0 beyond.  grid (Bb), block 256
// 4-way ILP unroll.
// ---------------------------------------------------------------------------
__global__ void bias_u(const float* __restrict__ zf, const float* __restrict__ wu,
                       const float* __restrict__ c0, float* __restrict__ U)
{
    const int b = blockIdx.x, m = threadIdx.x;
    if (m >= NzP) return;
    float s = 0.f;
    if (m < Nz) {
        const float* zb = zf + (size_t)b * C * Nz + m;
        float s0 = 0.f, s1 = 0.f, s2 = 0.f, s3 = 0.f;
        for (int c = 0; c < C; c += 4) {
            s0 += wu[c]     * zb[(size_t)c * Nz];
            s1 += wu[c + 1] * zb[(size_t)(c + 1) * Nz];
            s2 += wu[c + 2] * zb[(size_t)(c + 2) * Nz];
            s3 += wu[c + 3] * zb[(size_t)(c + 3) * Nz];
        }
        s = (s0 + s1) + (s2 + s3) + c0[0];
    }
    U[(size_t)b * NzP + m] = s;
}

// ---------------------------------------------------------------------------
// X [b][C][N] f32  →  hi/lo bf16 [b][N][C]  (k-major rows for MFMA operands)
// ---------------------------------------------------------------------------
__global__ __launch_bounds__(256)
void x2t_split(const float* __restrict__ X, unsigned short* __restrict__ Hi,
               unsigned short* __restrict__ Lo, int N)
{
    __shared__ float T[64][65];
    const int b = blockIdx.z, n0 = blockIdx.x * 64, c0 = blockIdx.y * 64;
    const float* Xb = X + ((size_t)b * C + c0) * N;
    #pragma unroll
    for (int i = 0; i < 16; ++i) {
        int e = threadIdx.x + 256 * i;
        int c = e >> 6, n = e & 63;
        T[c][n] = (n0 + n < N) ? Xb[(size_t)c * N + n0 + n] : 0.f;
    }
    __syncthreads();
    #pragma unroll
    for (int i = 0; i < 16; ++i) {
        int e = threadIdx.x + 256 * i;
        int n = e >> 6, c = e & 63;
        if (n0 + n < N) {
            float v = T[c][n];
            unsigned short h = f2bf(v);
            size_t idx = ((size_t)b * N + n0 + n) * C + c0 + c;
            Hi[idx] = h;
            Lo[idx] = f2bf(v - bf2f(h));
        }
    }
}

// ---------------------------------------------------------------------------
// Split-bf16 MFMA GEMM — z-side zq' = M zf + wv.
// Writes split bf16 [b][Nout][O]; rows n in [N,Nout) zero-filled.
// ---------------------------------------------------------------------------
__global__ __launch_bounds__(256)
void mfma_split(const unsigned short* __restrict__ Ahi,
                const unsigned short* __restrict__ Alo, size_t aStride,
                const unsigned short* __restrict__ Bhi,
                const unsigned short* __restrict__ Blo,
                const float* __restrict__ bias,
                unsigned short* __restrict__ Yhi, unsigned short* __restrict__ Ylo,
                int N, int Nout, int K, int O)
{
    __shared__ unsigned short Ah[64][40], Al[64][40], Bh[64][40], Bl[64][40];

    const int b   = blockIdx.z;
    const int n0  = blockIdx.x * 64;
    const int o0  = blockIdx.y * 64;
    const int tid = threadIdx.x;
    const int lane = tid & 63, wid = tid >> 6;
    const int wr = wid >> 1, wc = wid & 1;

    const unsigned short* Ahb = Ahi + (size_t)b * aStride;
    const unsigned short* Alb = Alo + (size_t)b * aStride;
    const unsigned short* Bhb = Bhi + (size_t)b * N * K;
    const unsigned short* Blb = Blo + (size_t)b * N * K;

    f32x4 acc[2][2];
    #pragma unroll
    for (int i = 0; i < 2; ++i)
        #pragma unroll
        for (int j = 0; j < 2; ++j)
            #pragma unroll
            for (int e = 0; e < 4; ++e) acc[i][j][e] = 0.f;

    const int srow = tid >> 2, sseg = tid & 3;
    const int lr = lane & 15, lk = (lane >> 4) * 8;

    for (int kc = 0; kc < K; kc += 32) {
        const int gk = kc + sseg * 8;
        *(int4*)&Ah[srow][sseg * 8] = *(const int4*)&Ahb[(size_t)(o0 + srow) * K + gk];
        *(int4*)&Al[srow][sseg * 8] = *(const int4*)&Alb[(size_t)(o0 + srow) * K + gk];

        const int gn = n0 + srow;
        int4 bv = make_int4(0, 0, 0, 0), blv = make_int4(0, 0, 0, 0);
        if (gn < N) {
            bv  = *(const int4*)&Bhb[(size_t)gn * K + gk];
            blv = *(const int4*)&Blb[(size_t)gn * K + gk];
        }
        *(int4*)&Bh[srow][sseg * 8] = bv;
        *(int4*)&Bl[srow][sseg * 8] = blv;
        __syncthreads();

        bf16x8 ah[2], al[2], bh[2], bl[2];
        #pragma unroll
        for (int i = 0; i < 2; ++i) {
            ah[i] = *(const bf16x8*)&Ah[wr * 32 + i * 16 + lr][lk];
            al[i] = *(const bf16x8*)&Al[wr * 32 + i * 16 + lr][lk];
            bh[i] = *(const bf16x8*)&Bh[wc * 32 + i * 16 + lr][lk];
            bl[i] = *(const bf16x8*)&Bl[wc * 32 + i * 16 + lr][lk];
        }
        #pragma unroll
        for (int i = 0; i < 2; ++i)
            #pragma unroll
            for (int j = 0; j < 2; ++j) {
                acc[i][j] = __builtin_amdgcn_mfma_f32_16x16x32_bf16(al[i], bh[j], acc[i][j], 0, 0, 0);
                acc[i][j] = __builtin_amdgcn_mfma_f32_16x16x32_bf16(ah[i], bl[j], acc[i][j], 0, 0, 0);
                acc[i][j] = __builtin_amdgcn_mfma_f32_16x16x32_bf16(ah[i], bh[j], acc[i][j], 0, 0, 0);
            }
        __syncthreads();
    }

    const int lg = lane >> 4;
    #pragma unroll
    for (int i = 0; i < 2; ++i) {
        const int ob = o0 + wr * 32 + i * 16 + lg * 4;
        float bi[4];
        #pragma unroll
        for (int r = 0; r < 4; ++r) bi[r] = bias[ob + r];
        #pragma unroll
        for (int j = 0; j < 2; ++j) {
            const int gn = n0 + wc * 32 + j * 16 + lr;
            if (gn < Nout) {
                uint2 ph = make_uint2(0, 0), pl = make_uint2(0, 0);
                if (gn < N) {
                    unsigned short h[4], l[4];
                    #pragma unroll
                    for (int r = 0; r < 4; ++r) {
                        float v = acc[i][j][r] + bi[r];
                        h[r] = f2bf(v);
                        l[r] = f2bf(v - bf2f(h[r]));
                    }
                    ph.x = (unsigned)h[0] | ((unsigned)h[1] << 16);
                    ph.y = (unsigned)h[2] | ((unsigned)h[3] << 16);
                    pl.x = (unsigned)l[0] | ((unsigned)l[1] << 16);
                    pl.y = (unsigned)l[2] | ((unsigned)l[3] << 16);
                }
                size_t idx = ((size_t)b * Nout + gn) * O + ob;
                *(uint2*)&Yhi[idx] = ph;
                *(uint2*)&Ylo[idx] = pl;
            }
        }
    }
}

// ---------------------------------------------------------------------------
// Plain bf16 MFMA GEMM (z-side small: zf_g conv, zg2).
// MODE 0: write [b][Nout][O] bf16 (rows [N,Nout) zeroed)
// MODE 1: write [b][O][Nout] bf16
// ---------------------------------------------------------------------------
template<int MODE, int EPI>
__global__ __launch_bounds__(256)
void mfma_conv(const unsigned short* __restrict__ A, int aLd, size_t aStride,
               const unsigned short* __restrict__ B1,
               const float* __restrict__ bias, const float* __restrict__ gamma,
               const float* __restrict__ beta, const float* __restrict__ mean,
               const float* __restrict__ var,
               unsigned short* __restrict__ Y, int N, int Nout, int K, int O)
{
    __shared__ unsigned short As[64][40];
    __shared__ unsigned short Bs[64][40];

    const int b   = blockIdx.z;
    const int n0  = blockIdx.x * 64;
    const int o0  = blockIdx.y * 64;
    const int tid = threadIdx.x;
    const int lane = tid & 63, wid = tid >> 6;
    const int wr = wid >> 1, wc = wid & 1;

    const unsigned short* Ab  = A + (size_t)b * aStride;
    const unsigned short* B1b = B1 + (size_t)b * N * K;

    f32x4 acc[2][2];
    #pragma unroll
    for (int i = 0; i < 2; ++i)
        #pragma unroll
        for (int j = 0; j < 2; ++j)
            #pragma unroll
            for (int e = 0; e < 4; ++e) acc[i][j][e] = 0.f;

    const int srow = tid >> 2, sseg = tid & 3;
    const int lr = lane & 15, lk = (lane >> 4) * 8;

    for (int kc = 0; kc < K; kc += 32) {
        const int gk = kc + sseg * 8;
        *(int4*)&As[srow][sseg * 8] = *(const int4*)&Ab[(size_t)(o0 + srow) * aLd + gk];

        const int gn = n0 + srow;
        int4 bv = make_int4(0, 0, 0, 0);
        if (gn < N) bv = *(const int4*)&B1b[(size_t)gn * K + gk];
        *(int4*)&Bs[srow][sseg * 8] = bv;
        __syncthreads();

        bf16x8 a0 = *(const bf16x8*)&As[wr * 32 +      lr][lk];
        bf16x8 a1 = *(const bf16x8*)&As[wr * 32 + 16 + lr][lk];
        bf16x8 b0 = *(const bf16x8*)&Bs[wc * 32 +      lr][lk];
        bf16x8 b1 = *(const bf16x8*)&Bs[wc * 32 + 16 + lr][lk];

        acc[0][0] = __builtin_amdgcn_mfma_f32_16x16x32_bf16(a0, b0, acc[0][0], 0, 0, 0);
        acc[0][1] = __builtin_amdgcn_mfma_f32_16x16x32_bf16(a0, b1, acc[0][1], 0, 0, 0);
        acc[1][0] = __builtin_amdgcn_mfma_f32_16x16x32_bf16(a1, b0, acc[1][0], 0, 0, 0);
        acc[1][1] = __builtin_amdgcn_mfma_f32_16x16x32_bf16(a1, b1, acc[1][1], 0, 0, 0);
        __syncthreads();
    }

    const int lg = lane >> 4;
    #pragma unroll
    for (int i = 0; i < 2; ++i) {
        const int ob = o0 + wr * 32 + i * 16 + lg * 4;
        float inv[4], sh[4], bi[4];
        if (EPI) {
            #pragma unroll
            for (int r = 0; r < 4; ++r) {
                int o = ob + r;
                float iv = gamma[o] * rsqrtf(var[o] + EPS);
                inv[r] = iv; sh[r] = beta[o] - mean[o] * iv; bi[r] = bias[o];
            }
        }
        #pragma unroll
        for (int j = 0; j < 2; ++j) {
            const int gn = n0 + wc * 32 + j * 16 + lr;
            float v[4];
            #pragma unroll
            for (int r = 0; r < 4; ++r) {
                v[r] = acc[i][j][r];
                if (EPI) v[r] = fmaxf(fmaf(v[r] + bi[r], inv[r], sh[r]), 0.f);
            }
            if (MODE == 0) {
                if (gn < Nout) {
                    uint2 pk = make_uint2(0, 0);
                    if (gn < N) {
                        pk.x = (unsigned)f2bf(v[0]) | ((unsigned)f2bf(v[1]) << 16);
                        pk.y = (unsigned)f2bf(v[2]) | ((unsigned)f2bf(v[3]) << 16);
                    }
                    *(uint2*)&Y[((size_t)b * Nout + gn) * O + ob] = pk;
                }
            } else {
                if (gn < Nout) {
                    #pragma unroll
                    for (int r = 0; r < 4; ++r)
                        Y[((size_t)b * O + ob + r) * Nout + gn] =
                            (gn < N) ? f2bf(v[r]) : (unsigned short)0;
                }
            }
        }
    }
}

// ---------------------------------------------------------------------------
// Big-tile conv: full O=256 x 64 n per block, B read exactly once.
// Two K phases: [0,K1) -> A1 (lda1, batched via aStride1) x B1 (row stride K1)
//               [K1,K1+K2) -> A2 (lda2, shared) x B2 (row stride K2)
// 4 waves; wave w owns o in [64w, 64w+64); acc[4][4] f32x4.
// Epilogue: bias + BN + ReLU.
// OUT_MODE 0: bf16 [b][N][256]   OUT_MODE 1: f32 [b][256][N]
// ---------------------------------------------------------------------------
template<int OUT_MODE>
__global__ __launch_bounds__(256)
void conv_big(const unsigned short* __restrict__ A1, int lda1, size_t aStride1,
              const unsigned short* __restrict__ B1, int K1,
              const unsigned short* __restrict__ A2, int lda2,
              const unsigned short* __restrict__ B2, int K2,
              const float* __restrict__ bias, const float* __restrict__ gamma,
              const float* __restrict__ beta, const float* __restrict__ mean,
              const float* __restrict__ var,
              void* __restrict__ Yv, int N)
{
    __shared__ unsigned short As[256][40];
    __shared__ unsigned short Bs[64][40];

    const int b   = blockIdx.z;
    const int n0  = blockIdx.x * 64;
    const int tid = threadIdx.x;
    const int lane = tid & 63, w = tid >> 6;
    const int lr = lane & 15, lg = lane >> 4, lk = lg * 8;

    const unsigned short* A1b = A1 + (size_t)b * aStride1;
    const unsigned short* B1b = B1 + (size_t)b * N * K1;
    const unsigned short* B2b = B2 ? (B2 + (size_t)b * N * K2) : nullptr;

    f32x4 acc[4][4];
    #pragma unroll
    for (int i = 0; i < 4; ++i)
        #pragma unroll
        for (int j = 0; j < 4; ++j)
            #pragma unroll
            for (int e = 0; e < 4; ++e) acc[i][j][e] = 0.f;

    const int brow = tid >> 2, bseg = tid & 3;

    for (int kc = 0; kc < K1 + K2; kc += 32) {
        const bool p1 = (kc < K1);
        // stage A: 256 rows x 32 k  (4 int4 per thread)
        #pragma unroll
        for (int s = 0; s < 4; ++s) {
            int e = tid + 256 * s;
            int row = e >> 2, seg = e & 3;
            int4 av;
            if (p1) av = *(const int4*)&A1b[(size_t)row * lda1 + kc + seg * 8];
            else    av = *(const int4*)&A2 [(size_t)row * lda2 + (kc - K1) + seg * 8];
            *(int4*)&As[row][seg * 8] = av;
        }
        // stage B: 64 rows x 32 k (1 int4 per thread)
        {
            const int gn = n0 + brow;
            int4 bv = make_int4(0, 0, 0, 0);
            if (gn < N) {
                if (p1) bv = *(const int4*)&B1b[(size_t)gn * K1 + kc + bseg * 8];
                else    bv = *(const int4*)&B2b[(size_t)gn * K2 + (kc - K1) + bseg * 8];
            }
            *(int4*)&Bs[brow][bseg * 8] = bv;
        }
        __syncthreads();

        bf16x8 a[4], bfr[4];
        #pragma unroll
        for (int i = 0; i < 4; ++i) a[i]   = *(const bf16x8*)&As[w * 64 + i * 16 + lr][lk];
        #pragma unroll
        for (int j = 0; j < 4; ++j) bfr[j] = *(const bf16x8*)&Bs[j * 16 + lr][lk];
        #pragma unroll
        for (int i = 0; i < 4; ++i)
            #pragma unroll
            for (int j = 0; j < 4; ++j)
                acc[i][j] = __builtin_amdgcn_mfma_f32_16x16x32_bf16(a[i], bfr[j], acc[i][j], 0, 0, 0);
        __syncthreads();
    }

    // epilogue: o = 64w + 16i + 4lg + r, n = n0 + 16j + lr
    #pragma unroll
    for (int i = 0; i < 4; ++i) {
        const int ob = w * 64 + i * 16 + lg * 4;
        float inv[4], sh[4], bi[4];
        #pragma unroll
        for (int r = 0; r < 4; ++r) {
            int o = ob + r;
            float iv = gamma[o] * rsqrtf(var[o] + EPS);
            inv[r] = iv; sh[r] = beta[o] - mean[o] * iv; bi[r] = bias[o];
        }
        #pragma unroll
        for (int j = 0; j < 4; ++j) {
            const int gn = n0 + j * 16 + lr;
            if (gn < N) {
                float v[4];
                #pragma unroll
                for (int r = 0; r < 4; ++r)
                    v[r] = fmaxf(fmaf(acc[i][j][r] + bi[r], inv[r], sh[r]), 0.f);
                if (OUT_MODE == 0) {
                    uint2 pk;
                    pk.x = (unsigned)f2bf(v[0]) | ((unsigned)f2bf(v[1]) << 16);
                    pk.y = (unsigned)f2bf(v[2]) | ((unsigned)f2bf(v[3]) << 16);
                    *(uint2*)((unsigned short*)Yv + ((size_t)b * N + gn) * 256 + ob) = pk;
                } else {
                    #pragma unroll
                    for (int r = 0; r < 4; ++r)
                        ((float*)Yv)[((size_t)b * 256 + ob + r) * N + gn] = v[r];
                }
            }
        }
    }
}

// ---------------------------------------------------------------------------
// Fused sim + sparsemax (unchanged from round 4).
// ---------------------------------------------------------------------------
__global__ __launch_bounds__(256)
void sim_sparsemax(const unsigned short* __restrict__ Ahi,
                   const unsigned short* __restrict__ Alo,
                   const unsigned short* __restrict__ Bhi,
                   const unsigned short* __restrict__ Blo,
                   const float* __restrict__ U,
                   unsigned short* __restrict__ P)
{
    __shared__ unsigned short Ah[64][40], Al[64][40];
    __shared__ unsigned short Bh[192][40], Bl[192][40];
    __shared__ float Us[192];

    const int b  = blockIdx.z, n0 = blockIdx.x * 64;
    const int tid = threadIdx.x, lane = tid & 63, w = tid >> 6;
    const int lr = lane & 15, lg = lane >> 4, lk = lg * 8;

    const unsigned short* Ahb = Ahi + (size_t)b * Nx * C;
    const unsigned short* Alb = Alo + (size_t)b * Nx * C;
    const unsigned short* Bhb = Bhi + (size_t)b * NzP * C;
    const unsigned short* Blb = Blo + (size_t)b * NzP * C;

    if (tid < 192) Us[tid] = U[(size_t)b * NzP + tid];

    f32x4 acc[12];
    #pragma unroll
    for (int j = 0; j < 12; ++j)
        #pragma unroll
        for (int e = 0; e < 4; ++e) acc[j][e] = 0.f;

    const int arow = tid >> 2, aseg = tid & 3;

    for (int kc = 0; kc < C; kc += 32) {
        {
            const int gk = kc + aseg * 8;
            const int gn = n0 + arow;
            int4 av = make_int4(0, 0, 0, 0), alv = make_int4(0, 0, 0, 0);
            if (gn < Nx) {
                av  = *(const int4*)&Ahb[(size_t)gn * C + gk];
                alv = *(const int4*)&Alb[(size_t)gn * C + gk];
            }
            *(int4*)&Ah[arow][aseg * 8] = av;
            *(int4*)&Al[arow][aseg * 8] = alv;
        }
        #pragma unroll
        for (int i = 0; i < 3; ++i) {
            const int slot = tid + 256 * i;
            const int brow = slot >> 2, bseg = slot & 3;
            const int gk = kc + bseg * 8;
            *(int4*)&Bh[brow][bseg * 8] = *(const int4*)&Bhb[(size_t)brow * C + gk];
            *(int4*)&Bl[brow][bseg * 8] = *(const int4*)&Blb[(size_t)brow * C + gk];
        }
        __syncthreads();

        bf16x8 a0h = *(const bf16x8*)&Ah[w * 16 + lr][lk];
        bf16x8 a0l = *(const bf16x8*)&Al[w * 16 + lr][lk];
        #pragma unroll
        for (int j = 0; j < 12; ++j) {
            bf16x8 bh = *(const bf16x8*)&Bh[j * 16 + lr][lk];
            bf16x8 bl = *(const bf16x8*)&Bl[j * 16 + lr][lk];
            acc[j] = __builtin_amdgcn_mfma_f32_16x16x32_bf16(a0l, bh, acc[j], 0, 0, 0);
            acc[j] = __builtin_amdgcn_mfma_f32_16x16x32_bf16(a0h, bl, acc[j], 0, 0, 0);
            acc[j] = __builtin_amdgcn_mfma_f32_16x16x32_bf16(a0h, bh, acc[j], 0, 0, 0);
        }
        __syncthreads();
    }

    #pragma unroll
    for (int j = 0; j < 12; ++j) {
        const int m = j * 16 + lr;
        const float uv = Us[m];
        const bool bad = (m >= Nz);
        #pragma unroll
        for (int q = 0; q < 4; ++q)
            acc[j][q] = bad ? -1e30f : (acc[j][q] + uv);
    }

    f32x4 mx = acc[0];
    #pragma unroll
    for (int j = 1; j < 12; ++j)
        #pragma unroll
        for (int q = 0; q < 4; ++q) mx[q] = fmaxf(mx[q], acc[j][q]);
    #pragma unroll
    for (int off = 1; off < 16; off <<= 1)
        #pragma unroll
        for (int q = 0; q < 4; ++q) mx[q] = fmaxf(mx[q], __shfl_xor(mx[q], off));

    f32x4 tau;
    #pragma unroll
    for (int q = 0; q < 4; ++q) tau[q] = mx[q] - 1.0f;

    for (int it = 0; it < 16; ++it) {
        f32x4 s, cnt;
        #pragma unroll
        for (int q = 0; q < 4; ++q) { s[q] = 0.f; cnt[q] = 0.f; }
        #pragma unroll
        for (int j = 0; j < 12; ++j)
            #pragma unroll
            for (int q = 0; q < 4; ++q)
                if (acc[j][q] > tau[q]) { s[q] += acc[j][q]; cnt[q] += 1.f; }
        #pragma unroll
        for (int off = 1; off < 16; off <<= 1)
            #pragma unroll
            for (int q = 0; q < 4; ++q) {
                s[q]   += __shfl_xor(s[q], off);
                cnt[q] += __shfl_xor(cnt[q], off);
            }
        bool adv = false;
        #pragma unroll
        for (int q = 0; q < 4; ++q) {
            float nt = (s[q] - 1.0f) / cnt[q];
            if (nt > tau[q]) { tau[q] = nt; adv = true; }
        }
        if (!__any(adv ? 1 : 0)) break;
    }

    unsigned short* Pb = P + (size_t)b * Nx * NzP;
    #pragma unroll
    for (int q = 0; q < 4; ++q) {
        const int n = n0 + w * 16 + 4 * lg + q;
        if (n < Nx) {
            #pragma unroll
            for (int j = 0; j < 12; ++j) {
                const int m = j * 16 + lr;
                float sv = (m < Nz) ? fmaxf(acc[j][q] - tau[q], 0.f) : 0.f;
                Pb[(size_t)n * NzP + m] = f2bf(sv);
            }
        }
    }
}

// ---------------------------------------------------------------------------
extern "C" void kernel_launch(void* const* d_in, const int* in_sizes, int n_in,
                              void* d_out, int out_size, void* d_ws, size_t ws_size,
                              hipStream_t stream)
{
    const float* zf      = (const float*)d_in[0];
    const float* xf      = (const float*)d_in[1];
    const float* Wq      = (const float*)d_in[2];
    const float* bq      = (const float*)d_in[3];
    const float* Ws_     = (const float*)d_in[4];
    const float* bs      = (const float*)d_in[5];
    const float* Wg      = (const float*)d_in[6];
    const float* bg      = (const float*)d_in[7];
    const float* g_gamma = (const float*)d_in[8];
    const float* g_beta  = (const float*)d_in[9];
    const float* g_mean  = (const float*)d_in[10];
    const float* g_var   = (const float*)d_in[11];
    const float* Wf      = (const float*)d_in[12];
    const float* bf_     = (const float*)d_in[13];
    const float* f_gamma = (const float*)d_in[14];
    const float* f_beta  = (const float*)d_in[15];
    const float* f_mean  = (const float*)d_in[16];
    const float* f_var   = (const float*)d_in[17];
    float* out = (float*)d_out;

    typedef unsigned short u16;
    char* ws = (char*)d_ws;
    u16*   xfT_hi = (u16*)(ws);                   //  40,960,000
    u16*   xfT_lo = (u16*)(ws +  40960000);       //  40,960,000
    u16*   zfT_hi = (u16*)(ws +  81920000);       //  11,075,584
    u16*   zfT_lo = (u16*)(ws +  92995584);       //  11,075,584
    u16*   zqT_hi = (u16*)(ws + 104071168);       //  12,582,912
    u16*   zqT_lo = (u16*)(ws + 116654080);       //  12,582,912
    u16*   xf_gT  = (u16*)(ws + 129236992);       //  40,960,000
    u16*   zf_gT  = (u16*)(ws + 170196992);       //  12,582,912
    u16*   zg2    = (u16*)(ws + 182779904);       //  12,582,912
    u16*   scoreP = (u16*)(ws + 195362816);       //  30,720,000
    float* U      = (float*)(ws + 226082816);     //      98,304
    u16*   Mhi    = (u16*)(ws + 226181120);       //     131,072
    u16*   Mlo    = (u16*)(ws + 226312192);       //     131,072
    u16*   Wg_bf  = (u16*)(ws + 226443264);       //     131,072
    u16*   Wf_bf  = (u16*)(ws + 226574336);       //     262,144
    float* wv     = (float*)(ws + 226836480);     //       1,024
    float* wu     = (float*)(ws + 226837504);     //       1,024
    float* c0     = (float*)(ws + 226838528);     //         256

    dim3 blk(256);
    const int gx_x = (Nx + 63) / 64;   // 10
    const int gx_z = NzP / 64;         // 3

    // small precomputes
    cvt_wgf<<<dim3((C * 2 * C + 255) / 256), blk, 0, stream>>>(Wg, Wf, Wg_bf, Wf_bf);
    prep_small<<<dim3(1), blk, 0, stream>>>(Wq, Ws_, bq, bs, wv, wu, c0);
    m_gemm<<<dim3(4, 4), blk, 0, stream>>>(Wq, Ws_, Mhi, Mlo);
    bias_u<<<dim3(Bb), blk, 0, stream>>>(zf, wu, c0, U);

    // input transposes/splits
    x2t_split<<<dim3(gx_x, C / 64, Bb), blk, 0, stream>>>(xf, xfT_hi, xfT_lo, Nx);
    x2t_split<<<dim3((Nz + 63) / 64, C / 64, Bb), blk, 0, stream>>>(zf, zfT_hi, zfT_lo, Nz);

    // zq' = M zf + wv  (split, z-side)
    mfma_split<<<dim3(gx_z, C / 64, Bb), blk, 0, stream>>>(
        Mhi, Mlo, 0, zfT_hi, zfT_lo, wv, zqT_hi, zqT_lo, Nz, NzP, C, C);

    // g-branch
    // xf_g: big tile (B read once) -> [b][Nx][256] bf16
    conv_big<0><<<dim3(gx_x, 1, Bb), blk, 0, stream>>>(
        Wg_bf, C, 0, xfT_hi, C, nullptr, 0, nullptr, 0,
        bg, g_gamma, g_beta, g_mean, g_var, xf_gT, Nx);
    // zf_g (z-side, small)
    mfma_conv<0, 1><<<dim3(gx_z, C / 64, Bb), blk, 0, stream>>>(
        Wg_bf, C, 0, zfT_hi, bg, g_gamma, g_beta, g_mean, g_var,
        zf_gT, Nz, NzP, C, C);

    // zg2 = Wf1 . zf_g   -> [b][C][NzP] bf16
    mfma_conv<1, 0><<<dim3(gx_z, C / 64, Bb), blk, 0, stream>>>(
        Wf_bf, 2 * C, 0, zf_gT, nullptr, nullptr, nullptr, nullptr, nullptr,
        zg2, NzP, NzP, C, C);

    // fused similar + sparsemax -> scoreP
    sim_sparsemax<<<dim3(gx_x, 1, Bb), blk, 0, stream>>>(
        xfT_hi, xfT_lo, zqT_hi, zqT_lo, U, scoreP);

    // fused final conv: phase1 zg2 x score (K=192), phase2 Wf2 x xf_g (K=256)
    conv_big<1><<<dim3(gx_x, 1, Bb), blk, 0, stream>>>(
        zg2, NzP, (size_t)C * NzP, scoreP, NzP,
        Wf_bf + C, 2 * C, xf_gT, C,
        bf_, f_gamma, f_beta, f_mean, f_var, out, Nx);
}

// Round 6
// 296.746 us; speedup vs baseline: 5.3009x; 1.2301x over previous
//
#include <hip/hip_runtime.h>
#include <math.h>

#define EPS 1e-5f

constexpr int Bb  = 128;
constexpr int C   = 256;
constexpr int Nz  = 169;   // 13*13
constexpr int Nx  = 625;   // 25*25
constexpr int NzP = 192;   // Nz padded to multiple of 32/64 (zero-filled)

typedef __bf16 bf16x8 __attribute__((ext_vector_type(8)));
typedef float  f32x4  __attribute__((ext_vector_type(4)));

__device__ __forceinline__ unsigned short f2bf(float f) {
    union { float f; unsigned u; } x; x.f = f;
    unsigned r = x.u + 0x7FFFu + ((x.u >> 16) & 1u);   // RNE
    return (unsigned short)(r >> 16);
}
__device__ __forceinline__ float bf2f(unsigned short h) {
    union { unsigned u; float f; } x; x.u = ((unsigned)h) << 16;
    return x.f;
}

// ---------------------------------------------------------------------------
// Wg, Wf → bf16
// ---------------------------------------------------------------------------
__global__ void cvt_wgf(const float* __restrict__ Wg, const float* __restrict__ Wf,
                        unsigned short* __restrict__ g, unsigned short* __restrict__ f)
{
    int i = blockIdx.x * 256 + threadIdx.x;
    if (i < C * C) g[i] = f2bf(Wg[i]);
    if (i < C * 2 * C) f[i] = f2bf(Wf[i]);
}

// ---------------------------------------------------------------------------
// wv = Wq^T bs, wu = Ws^T bq, c0 = bq.bs   (one block, 256 threads)
// ---------------------------------------------------------------------------
__global__ void prep_small(const float* __restrict__ Wq, const float* __restrict__ Ws,
                           const float* __restrict__ bq, const float* __restrict__ bs,
                           float* __restrict__ wv, float* __restrict__ wu,
                           float* __restrict__ c0)
{
    const int tid = threadIdx.x;
    float a = 0.f, b = 0.f;
    for (int o = 0; o < C; ++o) {
        a += Wq[o * C + tid] * bs[o];
        b += Ws[o * C + tid] * bq[o];
    }
    wv[tid] = a;
    wu[tid] = b;
    if (tid == 0) {
        float c = 0.f;
        for (int o = 0; o < C; ++o) c += bq[o] * bs[o];
        c0[0] = c;
    }
}

// ---------------------------------------------------------------------------
// M = Wq^T Ws  (fp32 compute, split bf16 hi/lo output).  grid (4,4)
// ---------------------------------------------------------------------------
__global__ __launch_bounds__(256)
void m_gemm(const float* __restrict__ Wq, const float* __restrict__ Ws,
            unsigned short* __restrict__ Mhi, unsigned short* __restrict__ Mlo)
{
    __shared__ float Qs[16][65], Ss[16][65];
    const int j0 = blockIdx.x * 64, i0 = blockIdx.y * 64;
    const int tid = threadIdx.x, tx = tid & 15, ty = tid >> 4;
    float acc[4][4] = {};

    for (int kc = 0; kc < C; kc += 16) {
        #pragma unroll
        for (int i = 0; i < 4; ++i) {
            int e = tid + 256 * i;
            int k = e >> 6, col = e & 63;
            Qs[k][col] = Wq[(size_t)(kc + k) * C + i0 + col];
            Ss[k][col] = Ws[(size_t)(kc + k) * C + j0 + col];
        }
        __syncthreads();
        #pragma unroll
        for (int k = 0; k < 16; ++k) {
            float a[4], bv[4];
            #pragma unroll
            for (int i = 0; i < 4; ++i) a[i] = Qs[k][ty * 4 + i];
            #pragma unroll
            for (int j = 0; j < 4; ++j) bv[j] = Ss[k][tx * 4 + j];
            #pragma unroll
            for (int i = 0; i < 4; ++i)
                #pragma unroll
                for (int j = 0; j < 4; ++j)
                    acc[i][j] = fmaf(a[i], bv[j], acc[i][j]);
        }
        __syncthreads();
    }
    #pragma unroll
    for (int i = 0; i < 4; ++i)
        #pragma unroll
        for (int j = 0; j < 4; ++j) {
            float v = acc[i][j];
            unsigned short h = f2bf(v);
            size_t idx = (size_t)(i0 + ty * 4 + i) * C + j0 + tx * 4 + j;
            Mhi[idx] = h;
            Mlo[idx] = f2bf(v - bf2f(h));
        }
}

// ---------------------------------------------------------------------------
// u[b,m] = wu . zf[b,:,m] + c0   for m < Nz, 0 beyond.  grid (Bb), block 256
// ---------------------------------------------------------------------------
__global__ void bias_u(const float* __restrict__ zf, const float* __restrict__ wu,
                       const float* __restrict__ c0, float* __restrict__ U)
{
    const int b = blockIdx.x, m = threadIdx.x;
    if (m >= NzP) return;
    float s = 0.f;
    if (m < Nz) {
        const float* zb = zf + (size_t)b * C * Nz + m;
        float s0 = 0.f, s1 = 0.f, s2 = 0.f, s3 = 0.f;
        for (int c = 0; c < C; c += 4) {
            s0 += wu[c]     * zb[(size_t)c * Nz];
            s1 += wu[c + 1] * zb[(size_t)(c + 1) * Nz];
            s2 += wu[c + 2] * zb[(size_t)(c + 2) * Nz];
            s3 += wu[c + 3] * zb[(size_t)(c + 3) * Nz];
        }
        s = (s0 + s1) + (s2 + s3) + c0[0];
    }
    U[(size_t)b * NzP + m] = s;
}

// ---------------------------------------------------------------------------
// zf [b][C][Nz] f32  →  hi/lo bf16 [b][Nz][C]  (z-side only)
// ---------------------------------------------------------------------------
__global__ __launch_bounds__(256)
void x2t_split(const float* __restrict__ X, unsigned short* __restrict__ Hi,
               unsigned short* __restrict__ Lo, int N)
{
    __shared__ float T[64][65];
    const int b = blockIdx.z, n0 = blockIdx.x * 64, c0 = blockIdx.y * 64;
    const float* Xb = X + ((size_t)b * C + c0) * N;
    #pragma unroll
    for (int i = 0; i < 16; ++i) {
        int e = threadIdx.x + 256 * i;
        int c = e >> 6, n = e & 63;
        T[c][n] = (n0 + n < N) ? Xb[(size_t)c * N + n0 + n] : 0.f;
    }
    __syncthreads();
    #pragma unroll
    for (int i = 0; i < 16; ++i) {
        int e = threadIdx.x + 256 * i;
        int n = e >> 6, c = e & 63;
        if (n0 + n < N) {
            float v = T[c][n];
            unsigned short h = f2bf(v);
            size_t idx = ((size_t)b * N + n0 + n) * C + c0 + c;
            Hi[idx] = h;
            Lo[idx] = f2bf(v - bf2f(h));
        }
    }
}

// ---------------------------------------------------------------------------
// Split-bf16 MFMA GEMM — z-side zq' = M zf + wv.
// Writes split bf16 [b][Nout][O]; rows n in [N,Nout) zero-filled.
// ---------------------------------------------------------------------------
__global__ __launch_bounds__(256)
void mfma_split(const unsigned short* __restrict__ Ahi,
                const unsigned short* __restrict__ Alo, size_t aStride,
                const unsigned short* __restrict__ Bhi,
                const unsigned short* __restrict__ Blo,
                const float* __restrict__ bias,
                unsigned short* __restrict__ Yhi, unsigned short* __restrict__ Ylo,
                int N, int Nout, int K, int O)
{
    __shared__ unsigned short Ah[64][40], Al[64][40], Bh[64][40], Bl[64][40];

    const int b   = blockIdx.z;
    const int n0  = blockIdx.x * 64;
    const int o0  = blockIdx.y * 64;
    const int tid = threadIdx.x;
    const int lane = tid & 63, wid = tid >> 6;
    const int wr = wid >> 1, wc = wid & 1;

    const unsigned short* Ahb = Ahi + (size_t)b * aStride;
    const unsigned short* Alb = Alo + (size_t)b * aStride;
    const unsigned short* Bhb = Bhi + (size_t)b * N * K;
    const unsigned short* Blb = Blo + (size_t)b * N * K;

    f32x4 acc[2][2];
    #pragma unroll
    for (int i = 0; i < 2; ++i)
        #pragma unroll
        for (int j = 0; j < 2; ++j)
            #pragma unroll
            for (int e = 0; e < 4; ++e) acc[i][j][e] = 0.f;

    const int srow = tid >> 2, sseg = tid & 3;
    const int lr = lane & 15, lk = (lane >> 4) * 8;

    for (int kc = 0; kc < K; kc += 32) {
        const int gk = kc + sseg * 8;
        *(int4*)&Ah[srow][sseg * 8] = *(const int4*)&Ahb[(size_t)(o0 + srow) * K + gk];
        *(int4*)&Al[srow][sseg * 8] = *(const int4*)&Alb[(size_t)(o0 + srow) * K + gk];

        const int gn = n0 + srow;
        int4 bv = make_int4(0, 0, 0, 0), blv = make_int4(0, 0, 0, 0);
        if (gn < N) {
            bv  = *(const int4*)&Bhb[(size_t)gn * K + gk];
            blv = *(const int4*)&Blb[(size_t)gn * K + gk];
        }
        *(int4*)&Bh[srow][sseg * 8] = bv;
        *(int4*)&Bl[srow][sseg * 8] = blv;
        __syncthreads();

        bf16x8 ah[2], al[2], bh[2], bl[2];
        #pragma unroll
        for (int i = 0; i < 2; ++i) {
            ah[i] = *(const bf16x8*)&Ah[wr * 32 + i * 16 + lr][lk];
            al[i] = *(const bf16x8*)&Al[wr * 32 + i * 16 + lr][lk];
            bh[i] = *(const bf16x8*)&Bh[wc * 32 + i * 16 + lr][lk];
            bl[i] = *(const bf16x8*)&Bl[wc * 32 + i * 16 + lr][lk];
        }
        #pragma unroll
        for (int i = 0; i < 2; ++i)
            #pragma unroll
            for (int j = 0; j < 2; ++j) {
                acc[i][j] = __builtin_amdgcn_mfma_f32_16x16x32_bf16(al[i], bh[j], acc[i][j], 0, 0, 0);
                acc[i][j] = __builtin_amdgcn_mfma_f32_16x16x32_bf16(ah[i], bl[j], acc[i][j], 0, 0, 0);
                acc[i][j] = __builtin_amdgcn_mfma_f32_16x16x32_bf16(ah[i], bh[j], acc[i][j], 0, 0, 0);
            }
        __syncthreads();
    }

    const int lg = lane >> 4;
    #pragma unroll
    for (int i = 0; i < 2; ++i) {
        const int ob = o0 + wr * 32 + i * 16 + lg * 4;
        float bi[4];
        #pragma unroll
        for (int r = 0; r < 4; ++r) bi[r] = bias[ob + r];
        #pragma unroll
        for (int j = 0; j < 2; ++j) {
            const int gn = n0 + wc * 32 + j * 16 + lr;
            if (gn < Nout) {
                uint2 ph = make_uint2(0, 0), pl = make_uint2(0, 0);
                if (gn < N) {
                    unsigned short h[4], l[4];
                    #pragma unroll
                    for (int r = 0; r < 4; ++r) {
                        float v = acc[i][j][r] + bi[r];
                        h[r] = f2bf(v);
                        l[r] = f2bf(v - bf2f(h[r]));
                    }
                    ph.x = (unsigned)h[0] | ((unsigned)h[1] << 16);
                    ph.y = (unsigned)h[2] | ((unsigned)h[3] << 16);
                    pl.x = (unsigned)l[0] | ((unsigned)l[1] << 16);
                    pl.y = (unsigned)l[2] | ((unsigned)l[3] << 16);
                }
                size_t idx = ((size_t)b * Nout + gn) * O + ob;
                *(uint2*)&Yhi[idx] = ph;
                *(uint2*)&Ylo[idx] = pl;
            }
        }
    }
}

// ---------------------------------------------------------------------------
// Plain bf16 MFMA GEMM (z-side small: zf_g conv, zg2).
// MODE 0: write [b][Nout][O] bf16 (rows [N,Nout) zeroed)
// MODE 1: write [b][O][Nout] bf16
// ---------------------------------------------------------------------------
template<int MODE, int EPI>
__global__ __launch_bounds__(256)
void mfma_conv(const unsigned short* __restrict__ A, int aLd, size_t aStride,
               const unsigned short* __restrict__ B1,
               const float* __restrict__ bias, const float* __restrict__ gamma,
               const float* __restrict__ beta, const float* __restrict__ mean,
               const float* __restrict__ var,
               unsigned short* __restrict__ Y, int N, int Nout, int K, int O)
{
    __shared__ unsigned short As[64][40];
    __shared__ unsigned short Bs[64][40];

    const int b   = blockIdx.z;
    const int n0  = blockIdx.x * 64;
    const int o0  = blockIdx.y * 64;
    const int tid = threadIdx.x;
    const int lane = tid & 63, wid = tid >> 6;
    const int wr = wid >> 1, wc = wid & 1;

    const unsigned short* Ab  = A + (size_t)b * aStride;
    const unsigned short* B1b = B1 + (size_t)b * N * K;

    f32x4 acc[2][2];
    #pragma unroll
    for (int i = 0; i < 2; ++i)
        #pragma unroll
        for (int j = 0; j < 2; ++j)
            #pragma unroll
            for (int e = 0; e < 4; ++e) acc[i][j][e] = 0.f;

    const int srow = tid >> 2, sseg = tid & 3;
    const int lr = lane & 15, lk = (lane >> 4) * 8;

    for (int kc = 0; kc < K; kc += 32) {
        const int gk = kc + sseg * 8;
        *(int4*)&As[srow][sseg * 8] = *(const int4*)&Ab[(size_t)(o0 + srow) * aLd + gk];

        const int gn = n0 + srow;
        int4 bv = make_int4(0, 0, 0, 0);
        if (gn < N) bv = *(const int4*)&B1b[(size_t)gn * K + gk];
        *(int4*)&Bs[srow][sseg * 8] = bv;
        __syncthreads();

        bf16x8 a0 = *(const bf16x8*)&As[wr * 32 +      lr][lk];
        bf16x8 a1 = *(const bf16x8*)&As[wr * 32 + 16 + lr][lk];
        bf16x8 b0 = *(const bf16x8*)&Bs[wc * 32 +      lr][lk];
        bf16x8 b1 = *(const bf16x8*)&Bs[wc * 32 + 16 + lr][lk];

        acc[0][0] = __builtin_amdgcn_mfma_f32_16x16x32_bf16(a0, b0, acc[0][0], 0, 0, 0);
        acc[0][1] = __builtin_amdgcn_mfma_f32_16x16x32_bf16(a0, b1, acc[0][1], 0, 0, 0);
        acc[1][0] = __builtin_amdgcn_mfma_f32_16x16x32_bf16(a1, b0, acc[1][0], 0, 0, 0);
        acc[1][1] = __builtin_amdgcn_mfma_f32_16x16x32_bf16(a1, b1, acc[1][1], 0, 0, 0);
        __syncthreads();
    }

    const int lg = lane >> 4;
    #pragma unroll
    for (int i = 0; i < 2; ++i) {
        const int ob = o0 + wr * 32 + i * 16 + lg * 4;
        float inv[4], sh[4], bi[4];
        if (EPI) {
            #pragma unroll
            for (int r = 0; r < 4; ++r) {
                int o = ob + r;
                float iv = gamma[o] * rsqrtf(var[o] + EPS);
                inv[r] = iv; sh[r] = beta[o] - mean[o] * iv; bi[r] = bias[o];
            }
        }
        #pragma unroll
        for (int j = 0; j < 2; ++j) {
            const int gn = n0 + wc * 32 + j * 16 + lr;
            float v[4];
            #pragma unroll
            for (int r = 0; r < 4; ++r) {
                v[r] = acc[i][j][r];
                if (EPI) v[r] = fmaxf(fmaf(v[r] + bi[r], inv[r], sh[r]), 0.f);
            }
            if (MODE == 0) {
                if (gn < Nout) {
                    uint2 pk = make_uint2(0, 0);
                    if (gn < N) {
                        pk.x = (unsigned)f2bf(v[0]) | ((unsigned)f2bf(v[1]) << 16);
                        pk.y = (unsigned)f2bf(v[2]) | ((unsigned)f2bf(v[3]) << 16);
                    }
                    *(uint2*)&Y[((size_t)b * Nout + gn) * O + ob] = pk;
                }
            } else {
                if (gn < Nout) {
                    #pragma unroll
                    for (int r = 0; r < 4; ++r)
                        Y[((size_t)b * O + ob + r) * Nout + gn] =
                            (gn < N) ? f2bf(v[r]) : (unsigned short)0;
                }
            }
        }
    }
}

// ---------------------------------------------------------------------------
// Fused sim + sparsemax; A staged DIRECTLY from xf f32 (on-the-fly hi/lo).
// ---------------------------------------------------------------------------
__global__ __launch_bounds__(256)
void sim_sparsemax(const float* __restrict__ Xf,
                   const unsigned short* __restrict__ Bhi,
                   const unsigned short* __restrict__ Blo,
                   const float* __restrict__ U,
                   unsigned short* __restrict__ P)
{
    __shared__ unsigned short Ah[64][40], Al[64][40];
    __shared__ unsigned short Bh[192][40], Bl[192][40];
    __shared__ float Us[192];

    const int b  = blockIdx.z, n0 = blockIdx.x * 64;
    const int tid = threadIdx.x, lane = tid & 63, w = tid >> 6;
    const int lr = lane & 15, lg = lane >> 4, lk = lg * 8;

    const unsigned short* Bhb = Bhi + (size_t)b * NzP * C;
    const unsigned short* Blb = Blo + (size_t)b * NzP * C;

    if (tid < 192) Us[tid] = U[(size_t)b * NzP + tid];

    f32x4 acc[12];
    #pragma unroll
    for (int j = 0; j < 12; ++j)
        #pragma unroll
        for (int e = 0; e < 4; ++e) acc[j][e] = 0.f;

    const int arow = tid >> 2, aseg = tid & 3;

    for (int kc = 0; kc < C; kc += 32) {
        // stage A directly from xf f32 (strided rows), split hi/lo
        {
            const int gn = min(n0 + arow, Nx - 1);
            const float* src = Xf + ((size_t)b * C + kc + aseg * 8) * Nx + gn;
            unsigned short h[8], l[8];
            #pragma unroll
            for (int e = 0; e < 8; ++e) {
                float v = src[(size_t)e * Nx];
                h[e] = f2bf(v);
                l[e] = f2bf(v - bf2f(h[e]));
            }
            uint4 ph, pl;
            ph.x = (unsigned)h[0] | ((unsigned)h[1] << 16);
            ph.y = (unsigned)h[2] | ((unsigned)h[3] << 16);
            ph.z = (unsigned)h[4] | ((unsigned)h[5] << 16);
            ph.w = (unsigned)h[6] | ((unsigned)h[7] << 16);
            pl.x = (unsigned)l[0] | ((unsigned)l[1] << 16);
            pl.y = (unsigned)l[2] | ((unsigned)l[3] << 16);
            pl.z = (unsigned)l[4] | ((unsigned)l[5] << 16);
            pl.w = (unsigned)l[6] | ((unsigned)l[7] << 16);
            *(uint4*)&Ah[arow][aseg * 8] = ph;
            *(uint4*)&Al[arow][aseg * 8] = pl;
        }
        // stage B (192 rows x 32 k, hi+lo) — 3 slots per thread
        #pragma unroll
        for (int i = 0; i < 3; ++i) {
            const int slot = tid + 256 * i;
            const int brow = slot >> 2, bseg = slot & 3;
            const int gk = kc + bseg * 8;
            *(int4*)&Bh[brow][bseg * 8] = *(const int4*)&Bhb[(size_t)brow * C + gk];
            *(int4*)&Bl[brow][bseg * 8] = *(const int4*)&Blb[(size_t)brow * C + gk];
        }
        __syncthreads();

        bf16x8 a0h = *(const bf16x8*)&Ah[w * 16 + lr][lk];
        bf16x8 a0l = *(const bf16x8*)&Al[w * 16 + lr][lk];
        #pragma unroll
        for (int j = 0; j < 12; ++j) {
            bf16x8 bh = *(const bf16x8*)&Bh[j * 16 + lr][lk];
            bf16x8 bl = *(const bf16x8*)&Bl[j * 16 + lr][lk];
            acc[j] = __builtin_amdgcn_mfma_f32_16x16x32_bf16(a0l, bh, acc[j], 0, 0, 0);
            acc[j] = __builtin_amdgcn_mfma_f32_16x16x32_bf16(a0h, bl, acc[j], 0, 0, 0);
            acc[j] = __builtin_amdgcn_mfma_f32_16x16x32_bf16(a0h, bh, acc[j], 0, 0, 0);
        }
        __syncthreads();
    }

    #pragma unroll
    for (int j = 0; j < 12; ++j) {
        const int m = j * 16 + lr;
        const float uv = Us[m];
        const bool bad = (m >= Nz);
        #pragma unroll
        for (int q = 0; q < 4; ++q)
            acc[j][q] = bad ? -1e30f : (acc[j][q] + uv);
    }

    f32x4 mx = acc[0];
    #pragma unroll
    for (int j = 1; j < 12; ++j)
        #pragma unroll
        for (int q = 0; q < 4; ++q) mx[q] = fmaxf(mx[q], acc[j][q]);
    #pragma unroll
    for (int off = 1; off < 16; off <<= 1)
        #pragma unroll
        for (int q = 0; q < 4; ++q) mx[q] = fmaxf(mx[q], __shfl_xor(mx[q], off));

    f32x4 tau;
    #pragma unroll
    for (int q = 0; q < 4; ++q) tau[q] = mx[q] - 1.0f;

    for (int it = 0; it < 16; ++it) {
        f32x4 s, cnt;
        #pragma unroll
        for (int q = 0; q < 4; ++q) { s[q] = 0.f; cnt[q] = 0.f; }
        #pragma unroll
        for (int j = 0; j < 12; ++j)
            #pragma unroll
            for (int q = 0; q < 4; ++q)
                if (acc[j][q] > tau[q]) { s[q] += acc[j][q]; cnt[q] += 1.f; }
        #pragma unroll
        for (int off = 1; off < 16; off <<= 1)
            #pragma unroll
            for (int q = 0; q < 4; ++q) {
                s[q]   += __shfl_xor(s[q], off);
                cnt[q] += __shfl_xor(cnt[q], off);
            }
        bool adv = false;
        #pragma unroll
        for (int q = 0; q < 4; ++q) {
            float nt = (s[q] - 1.0f) / cnt[q];
            if (nt > tau[q]) { tau[q] = nt; adv = true; }
        }
        if (!__any(adv ? 1 : 0)) break;
    }

    unsigned short* Pb = P + (size_t)b * Nx * NzP;
    #pragma unroll
    for (int q = 0; q < 4; ++q) {
        const int n = n0 + w * 16 + 4 * lg + q;
        if (n < Nx) {
            #pragma unroll
            for (int j = 0; j < 12; ++j) {
                const int m = j * 16 + lr;
                float sv = (m < Nz) ? fmaxf(acc[j][q] - tau[q], 0.f) : 0.f;
                Pb[(size_t)n * NzP + m] = f2bf(sv);
            }
        }
    }
}

// ---------------------------------------------------------------------------
// Fused g-conv + final conv, per (b, 64-n tile):
//  G : XG[n][o] = bn_relu(Wg . xf + bg)    (xf staged direct from f32)
//  P1: acc  = zg2 . score                  (K = 192)
//  P2: acc += Wf2 . XG                     (K = 256, B from LDS, no HBM)
//  out = bn_relu(acc + bf)                 f32 [b][256][Nx]
// ---------------------------------------------------------------------------
__global__ __launch_bounds__(256)
void final_fused(const float* __restrict__ Xf,
                 const unsigned short* __restrict__ Wg,    // [256][256] bf16
                 const unsigned short* __restrict__ Zg2,   // [b][256][192] bf16
                 const unsigned short* __restrict__ Sc,    // [b][625][192] bf16
                 const unsigned short* __restrict__ Wf2,   // [256][512] base+256
                 const float* __restrict__ bg, const float* __restrict__ g_gamma,
                 const float* __restrict__ g_beta, const float* __restrict__ g_mean,
                 const float* __restrict__ g_var,
                 const float* __restrict__ bf, const float* __restrict__ f_gamma,
                 const float* __restrict__ f_beta, const float* __restrict__ f_mean,
                 const float* __restrict__ f_var,
                 float* __restrict__ out)
{
    __shared__ unsigned short As[256][40];   // A staging (Wg / zg2 / Wf2)
    __shared__ unsigned short Bs[64][40];    // B staging (xf-G / score-P1)
    __shared__ unsigned short XG[64][264];   // xf_g^T tile (row 528 B, 16-aligned)

    const int b   = blockIdx.z;
    const int n0  = blockIdx.x * 64;
    const int tid = threadIdx.x;
    const int lane = tid & 63, w = tid >> 6;
    const int lr = lane & 15, lg = lane >> 4, lk = lg * 8;
    const int brow = tid >> 2, bseg = tid & 3;

    const unsigned short* Zg2b = Zg2 + (size_t)b * C * NzP;
    const unsigned short* Scb  = Sc  + (size_t)b * Nx * NzP;

    f32x4 acc[4][4];
    #pragma unroll
    for (int i = 0; i < 4; ++i)
        #pragma unroll
        for (int j = 0; j < 4; ++j)
            #pragma unroll
            for (int e = 0; e < 4; ++e) acc[i][j][e] = 0.f;

    // ---------------- phase G ----------------
    for (int kc = 0; kc < C; kc += 32) {
        #pragma unroll
        for (int s = 0; s < 4; ++s) {
            int e = tid + 256 * s;
            int row = e >> 2, seg = e & 3;
            *(int4*)&As[row][seg * 8] = *(const int4*)&Wg[(size_t)row * C + kc + seg * 8];
        }
        {
            const int gn = min(n0 + brow, Nx - 1);
            const float* src = Xf + ((size_t)b * C + kc + bseg * 8) * Nx + gn;
            unsigned short h[8];
            #pragma unroll
            for (int e = 0; e < 8; ++e) h[e] = f2bf(src[(size_t)e * Nx]);
            uint4 ph;
            ph.x = (unsigned)h[0] | ((unsigned)h[1] << 16);
            ph.y = (unsigned)h[2] | ((unsigned)h[3] << 16);
            ph.z = (unsigned)h[4] | ((unsigned)h[5] << 16);
            ph.w = (unsigned)h[6] | ((unsigned)h[7] << 16);
            *(uint4*)&Bs[brow][bseg * 8] = ph;
        }
        __syncthreads();

        bf16x8 a[4], bfr[4];
        #pragma unroll
        for (int i = 0; i < 4; ++i) a[i]   = *(const bf16x8*)&As[w * 64 + i * 16 + lr][lk];
        #pragma unroll
        for (int j = 0; j < 4; ++j) bfr[j] = *(const bf16x8*)&Bs[j * 16 + lr][lk];
        #pragma unroll
        for (int i = 0; i < 4; ++i)
            #pragma unroll
            for (int j = 0; j < 4; ++j)
                acc[i][j] = __builtin_amdgcn_mfma_f32_16x16x32_bf16(a[i], bfr[j], acc[i][j], 0, 0, 0);
        __syncthreads();
    }

    // G epilogue: bn_relu -> XG[n][o] (transposed, bf16)
    #pragma unroll
    for (int i = 0; i < 4; ++i) {
        const int ob = w * 64 + i * 16 + lg * 4;
        float inv[4], sh[4], bi[4];
        #pragma unroll
        for (int r = 0; r < 4; ++r) {
            int o = ob + r;
            float iv = g_gamma[o] * rsqrtf(g_var[o] + EPS);
            inv[r] = iv; sh[r] = g_beta[o] - g_mean[o] * iv; bi[r] = bg[o];
        }
        #pragma unroll
        for (int j = 0; j < 4; ++j) {
            unsigned short h[4];
            #pragma unroll
            for (int r = 0; r < 4; ++r)
                h[r] = f2bf(fmaxf(fmaf(acc[i][j][r] + bi[r], inv[r], sh[r]), 0.f));
            uint2 pk;
            pk.x = (unsigned)h[0] | ((unsigned)h[1] << 16);
            pk.y = (unsigned)h[2] | ((unsigned)h[3] << 16);
            *(uint2*)&XG[j * 16 + lr][ob] = pk;
        }
    }
    #pragma unroll
    for (int i = 0; i < 4; ++i)
        #pragma unroll
        for (int j = 0; j < 4; ++j)
            #pragma unroll
            for (int e = 0; e < 4; ++e) acc[i][j][e] = 0.f;
    __syncthreads();

    // ---------------- phase P1: zg2 x score (K=192) ----------------
    for (int kc = 0; kc < NzP; kc += 32) {
        #pragma unroll
        for (int s = 0; s < 4; ++s) {
            int e = tid + 256 * s;
            int row = e >> 2, seg = e & 3;
            *(int4*)&As[row][seg * 8] = *(const int4*)&Zg2b[(size_t)row * NzP + kc + seg * 8];
        }
        {
            const int gn = min(n0 + brow, Nx - 1);
            *(int4*)&Bs[brow][bseg * 8] = *(const int4*)&Scb[(size_t)gn * NzP + kc + bseg * 8];
        }
        __syncthreads();

        bf16x8 a[4], bfr[4];
        #pragma unroll
        for (int i = 0; i < 4; ++i) a[i]   = *(const bf16x8*)&As[w * 64 + i * 16 + lr][lk];
        #pragma unroll
        for (int j = 0; j < 4; ++j) bfr[j] = *(const bf16x8*)&Bs[j * 16 + lr][lk];
        #pragma unroll
        for (int i = 0; i < 4; ++i)
            #pragma unroll
            for (int j = 0; j < 4; ++j)
                acc[i][j] = __builtin_amdgcn_mfma_f32_16x16x32_bf16(a[i], bfr[j], acc[i][j], 0, 0, 0);
        __syncthreads();
    }

    // ---------------- phase P2: Wf2 x XG (K=256, B from LDS) ----------------
    for (int kc = 0; kc < C; kc += 32) {
        #pragma unroll
        for (int s = 0; s < 4; ++s) {
            int e = tid + 256 * s;
            int row = e >> 2, seg = e & 3;
            *(int4*)&As[row][seg * 8] = *(const int4*)&Wf2[(size_t)row * 512 + kc + seg * 8];
        }
        __syncthreads();

        bf16x8 a[4], bfr[4];
        #pragma unroll
        for (int i = 0; i < 4; ++i) a[i]   = *(const bf16x8*)&As[w * 64 + i * 16 + lr][lk];
        #pragma unroll
        for (int j = 0; j < 4; ++j) bfr[j] = *(const bf16x8*)&XG[j * 16 + lr][kc + lk];
        #pragma unroll
        for (int i = 0; i < 4; ++i)
            #pragma unroll
            for (int j = 0; j < 4; ++j)
                acc[i][j] = __builtin_amdgcn_mfma_f32_16x16x32_bf16(a[i], bfr[j], acc[i][j], 0, 0, 0);
        __syncthreads();
    }

    // final epilogue: bn_relu(f) -> out f32 [b][256][Nx]
    #pragma unroll
    for (int i = 0; i < 4; ++i) {
        const int ob = w * 64 + i * 16 + lg * 4;
        float inv[4], sh[4], bi[4];
        #pragma unroll
        for (int r = 0; r < 4; ++r) {
            int o = ob + r;
            float iv = f_gamma[o] * rsqrtf(f_var[o] + EPS);
            inv[r] = iv; sh[r] = f_beta[o] - f_mean[o] * iv; bi[r] = bf[o];
        }
        #pragma unroll
        for (int j = 0; j < 4; ++j) {
            const int gn = n0 + j * 16 + lr;
            if (gn < Nx) {
                #pragma unroll
                for (int r = 0; r < 4; ++r) {
                    float v = fmaxf(fmaf(acc[i][j][r] + bi[r], inv[r], sh[r]), 0.f);
                    out[((size_t)b * C + ob + r) * Nx + gn] = v;
                }
            }
        }
    }
}

// ---------------------------------------------------------------------------
extern "C" void kernel_launch(void* const* d_in, const int* in_sizes, int n_in,
                              void* d_out, int out_size, void* d_ws, size_t ws_size,
                              hipStream_t stream)
{
    const float* zf      = (const float*)d_in[0];
    const float* xf      = (const float*)d_in[1];
    const float* Wq      = (const float*)d_in[2];
    const float* bq      = (const float*)d_in[3];
    const float* Ws_     = (const float*)d_in[4];
    const float* bs      = (const float*)d_in[5];
    const float* Wg      = (const float*)d_in[6];
    const float* bg      = (const float*)d_in[7];
    const float* g_gamma = (const float*)d_in[8];
    const float* g_beta  = (const float*)d_in[9];
    const float* g_mean  = (const float*)d_in[10];
    const float* g_var   = (const float*)d_in[11];
    const float* Wf      = (const float*)d_in[12];
    const float* bf_     = (const float*)d_in[13];
    const float* f_gamma = (const float*)d_in[14];
    const float* f_beta  = (const float*)d_in[15];
    const float* f_mean  = (const float*)d_in[16];
    const float* f_var   = (const float*)d_in[17];
    float* out = (float*)d_out;

    typedef unsigned short u16;
    char* ws = (char*)d_ws;
    u16*   zfT_hi = (u16*)(ws);                   //  11,075,584
    u16*   zfT_lo = (u16*)(ws +  11075584);       //  11,075,584
    u16*   zqT_hi = (u16*)(ws +  22151168);       //  12,582,912
    u16*   zqT_lo = (u16*)(ws +  34734080);       //  12,582,912
    u16*   zf_gT  = (u16*)(ws +  47316992);       //  12,582,912
    u16*   zg2    = (u16*)(ws +  59899904);       //  12,582,912
    u16*   scoreP = (u16*)(ws +  72482816);       //  30,720,000
    float* U      = (float*)(ws + 103202816);     //      98,304
    u16*   Mhi    = (u16*)(ws + 103301120);       //     131,072
    u16*   Mlo    = (u16*)(ws + 103432192);       //     131,072
    u16*   Wg_bf  = (u16*)(ws + 103563264);       //     131,072
    u16*   Wf_bf  = (u16*)(ws + 103694336);       //     262,144
    float* wv     = (float*)(ws + 103956480);     //       1,024
    float* wu     = (float*)(ws + 103957504);     //       1,024
    float* c0     = (float*)(ws + 103958528);     //         256

    dim3 blk(256);
    const int gx_x = (Nx + 63) / 64;   // 10
    const int gx_z = NzP / 64;         // 3

    // small precomputes
    cvt_wgf<<<dim3((C * 2 * C + 255) / 256), blk, 0, stream>>>(Wg, Wf, Wg_bf, Wf_bf);
    prep_small<<<dim3(1), blk, 0, stream>>>(Wq, Ws_, bq, bs, wv, wu, c0);
    m_gemm<<<dim3(4, 4), blk, 0, stream>>>(Wq, Ws_, Mhi, Mlo);
    bias_u<<<dim3(Bb), blk, 0, stream>>>(zf, wu, c0, U);

    // z-side transpose/split
    x2t_split<<<dim3((Nz + 63) / 64, C / 64, Bb), blk, 0, stream>>>(zf, zfT_hi, zfT_lo, Nz);

    // zq' = M zf + wv  (split)
    mfma_split<<<dim3(gx_z, C / 64, Bb), blk, 0, stream>>>(
        Mhi, Mlo, 0, zfT_hi, zfT_lo, wv, zqT_hi, zqT_lo, Nz, NzP, C, C);

    // zf_g = bn_relu(Wg . zf)
    mfma_conv<0, 1><<<dim3(gx_z, C / 64, Bb), blk, 0, stream>>>(
        Wg_bf, C, 0, zfT_hi, bg, g_gamma, g_beta, g_mean, g_var,
        zf_gT, Nz, NzP, C, C);

    // zg2 = Wf1 . zf_g   -> [b][C][NzP] bf16
    mfma_conv<1, 0><<<dim3(gx_z, C / 64, Bb), blk, 0, stream>>>(
        Wf_bf, 2 * C, 0, zf_gT, nullptr, nullptr, nullptr, nullptr, nullptr,
        zg2, NzP, NzP, C, C);

    // fused similar + sparsemax -> scoreP  (A staged direct from xf)
    sim_sparsemax<<<dim3(gx_x, 1, Bb), blk, 0, stream>>>(
        xf, zqT_hi, zqT_lo, U, scoreP);

    // fused g-conv + final conv
    final_fused<<<dim3(gx_x, 1, Bb), blk, 0, stream>>>(
        xf, Wg_bf, zg2, scoreP, Wf_bf + C,
        bg, g_gamma, g_beta, g_mean, g_var,
        bf_, f_gamma, f_beta, f_mean, f_var, out);
}

// Round 7
// 262.874 us; speedup vs baseline: 5.9839x; 1.1289x over previous
//
#include <hip/hip_runtime.h>
#include <math.h>

#define EPS 1e-5f

constexpr int Bb  = 128;
constexpr int C   = 256;
constexpr int Nz  = 169;   // 13*13
constexpr int Nx  = 625;   // 25*25
constexpr int NzP = 192;   // Nz padded (zero-filled)

typedef __bf16 bf16x8 __attribute__((ext_vector_type(8)));
typedef float  f32x4  __attribute__((ext_vector_type(4)));

__device__ __forceinline__ unsigned short f2bf(float f) {
    union { float f; unsigned u; } x; x.f = f;
    unsigned r = x.u + 0x7FFFu + ((x.u >> 16) & 1u);   // RNE
    return (unsigned short)(r >> 16);
}
__device__ __forceinline__ float bf2f(unsigned short h) {
    union { unsigned u; float f; } x; x.u = ((unsigned)h) << 16;
    return x.f;
}

// ---------------------------------------------------------------------------
// Wg, Wf → bf16
// ---------------------------------------------------------------------------
__global__ void cvt_wgf(const float* __restrict__ Wg, const float* __restrict__ Wf,
                        unsigned short* __restrict__ g, unsigned short* __restrict__ f)
{
    int i = blockIdx.x * 256 + threadIdx.x;
    if (i < C * C) g[i] = f2bf(Wg[i]);
    if (i < C * 2 * C) f[i] = f2bf(Wf[i]);
}

// ---------------------------------------------------------------------------
// wv = Wq^T bs, wu = Ws^T bq, c0 = bq.bs
// ---------------------------------------------------------------------------
__global__ void prep_small(const float* __restrict__ Wq, const float* __restrict__ Ws,
                           const float* __restrict__ bq, const float* __restrict__ bs,
                           float* __restrict__ wv, float* __restrict__ wu,
                           float* __restrict__ c0)
{
    const int tid = threadIdx.x;
    float a = 0.f, b = 0.f;
    for (int o = 0; o < C; ++o) {
        a += Wq[o * C + tid] * bs[o];
        b += Ws[o * C + tid] * bq[o];
    }
    wv[tid] = a;
    wu[tid] = b;
    if (tid == 0) {
        float c = 0.f;
        for (int o = 0; o < C; ++o) c += bq[o] * bs[o];
        c0[0] = c;
    }
}

// ---------------------------------------------------------------------------
// M = Wq^T Ws  (fp32 compute, split bf16 hi/lo output).  grid (4,4)
// ---------------------------------------------------------------------------
__global__ __launch_bounds__(256)
void m_gemm(const float* __restrict__ Wq, const float* __restrict__ Ws,
            unsigned short* __restrict__ Mhi, unsigned short* __restrict__ Mlo)
{
    __shared__ float Qs[16][65], Ss[16][65];
    const int j0 = blockIdx.x * 64, i0 = blockIdx.y * 64;
    const int tid = threadIdx.x, tx = tid & 15, ty = tid >> 4;
    float acc[4][4] = {};

    for (int kc = 0; kc < C; kc += 16) {
        #pragma unroll
        for (int i = 0; i < 4; ++i) {
            int e = tid + 256 * i;
            int k = e >> 6, col = e & 63;
            Qs[k][col] = Wq[(size_t)(kc + k) * C + i0 + col];
            Ss[k][col] = Ws[(size_t)(kc + k) * C + j0 + col];
        }
        __syncthreads();
        #pragma unroll
        for (int k = 0; k < 16; ++k) {
            float a[4], bv[4];
            #pragma unroll
            for (int i = 0; i < 4; ++i) a[i] = Qs[k][ty * 4 + i];
            #pragma unroll
            for (int j = 0; j < 4; ++j) bv[j] = Ss[k][tx * 4 + j];
            #pragma unroll
            for (int i = 0; i < 4; ++i)
                #pragma unroll
                for (int j = 0; j < 4; ++j)
                    acc[i][j] = fmaf(a[i], bv[j], acc[i][j]);
        }
        __syncthreads();
    }
    #pragma unroll
    for (int i = 0; i < 4; ++i)
        #pragma unroll
        for (int j = 0; j < 4; ++j) {
            float v = acc[i][j];
            unsigned short h = f2bf(v);
            size_t idx = (size_t)(i0 + ty * 4 + i) * C + j0 + tx * 4 + j;
            Mhi[idx] = h;
            Mlo[idx] = f2bf(v - bf2f(h));
        }
}

// ---------------------------------------------------------------------------
// u[b,m] = wu . zf[b,:,m] + c0
// ---------------------------------------------------------------------------
__global__ void bias_u(const float* __restrict__ zf, const float* __restrict__ wu,
                       const float* __restrict__ c0, float* __restrict__ U)
{
    const int b = blockIdx.x, m = threadIdx.x;
    if (m >= NzP) return;
    float s = 0.f;
    if (m < Nz) {
        const float* zb = zf + (size_t)b * C * Nz + m;
        float s0 = 0.f, s1 = 0.f, s2 = 0.f, s3 = 0.f;
        for (int c = 0; c < C; c += 4) {
            s0 += wu[c]     * zb[(size_t)c * Nz];
            s1 += wu[c + 1] * zb[(size_t)(c + 1) * Nz];
            s2 += wu[c + 2] * zb[(size_t)(c + 2) * Nz];
            s3 += wu[c + 3] * zb[(size_t)(c + 3) * Nz];
        }
        s = (s0 + s1) + (s2 + s3) + c0[0];
    }
    U[(size_t)b * NzP + m] = s;
}

// ---------------------------------------------------------------------------
// zf [b][C][Nz] f32  →  hi/lo bf16 [b][Nz][C]
// ---------------------------------------------------------------------------
__global__ __launch_bounds__(256)
void x2t_split(const float* __restrict__ X, unsigned short* __restrict__ Hi,
               unsigned short* __restrict__ Lo, int N)
{
    __shared__ float T[64][65];
    const int b = blockIdx.z, n0 = blockIdx.x * 64, c0 = blockIdx.y * 64;
    const float* Xb = X + ((size_t)b * C + c0) * N;
    #pragma unroll
    for (int i = 0; i < 16; ++i) {
        int e = threadIdx.x + 256 * i;
        int c = e >> 6, n = e & 63;
        T[c][n] = (n0 + n < N) ? Xb[(size_t)c * N + n0 + n] : 0.f;
    }
    __syncthreads();
    #pragma unroll
    for (int i = 0; i < 16; ++i) {
        int e = threadIdx.x + 256 * i;
        int n = e >> 6, c = e & 63;
        if (n0 + n < N) {
            float v = T[c][n];
            unsigned short h = f2bf(v);
            size_t idx = ((size_t)b * N + n0 + n) * C + c0 + c;
            Hi[idx] = h;
            Lo[idx] = f2bf(v - bf2f(h));
        }
    }
}

// ---------------------------------------------------------------------------
// Split-bf16 MFMA GEMM — z-side zq' = M zf + wv.
// ---------------------------------------------------------------------------
__global__ __launch_bounds__(256)
void mfma_split(const unsigned short* __restrict__ Ahi,
                const unsigned short* __restrict__ Alo, size_t aStride,
                const unsigned short* __restrict__ Bhi,
                const unsigned short* __restrict__ Blo,
                const float* __restrict__ bias,
                unsigned short* __restrict__ Yhi, unsigned short* __restrict__ Ylo,
                int N, int Nout, int K, int O)
{
    __shared__ unsigned short Ah[64][40], Al[64][40], Bh[64][40], Bl[64][40];

    const int b   = blockIdx.z;
    const int n0  = blockIdx.x * 64;
    const int o0  = blockIdx.y * 64;
    const int tid = threadIdx.x;
    const int lane = tid & 63, wid = tid >> 6;
    const int wr = wid >> 1, wc = wid & 1;

    const unsigned short* Ahb = Ahi + (size_t)b * aStride;
    const unsigned short* Alb = Alo + (size_t)b * aStride;
    const unsigned short* Bhb = Bhi + (size_t)b * N * K;
    const unsigned short* Blb = Blo + (size_t)b * N * K;

    f32x4 acc[2][2];
    #pragma unroll
    for (int i = 0; i < 2; ++i)
        #pragma unroll
        for (int j = 0; j < 2; ++j)
            #pragma unroll
            for (int e = 0; e < 4; ++e) acc[i][j][e] = 0.f;

    const int srow = tid >> 2, sseg = tid & 3;
    const int lr = lane & 15, lk = (lane >> 4) * 8;

    for (int kc = 0; kc < K; kc += 32) {
        const int gk = kc + sseg * 8;
        *(int4*)&Ah[srow][sseg * 8] = *(const int4*)&Ahb[(size_t)(o0 + srow) * K + gk];
        *(int4*)&Al[srow][sseg * 8] = *(const int4*)&Alb[(size_t)(o0 + srow) * K + gk];

        const int gn = n0 + srow;
        int4 bv = make_int4(0, 0, 0, 0), blv = make_int4(0, 0, 0, 0);
        if (gn < N) {
            bv  = *(const int4*)&Bhb[(size_t)gn * K + gk];
            blv = *(const int4*)&Blb[(size_t)gn * K + gk];
        }
        *(int4*)&Bh[srow][sseg * 8] = bv;
        *(int4*)&Bl[srow][sseg * 8] = blv;
        __syncthreads();

        bf16x8 ah[2], al[2], bh[2], bl[2];
        #pragma unroll
        for (int i = 0; i < 2; ++i) {
            ah[i] = *(const bf16x8*)&Ah[wr * 32 + i * 16 + lr][lk];
            al[i] = *(const bf16x8*)&Al[wr * 32 + i * 16 + lr][lk];
            bh[i] = *(const bf16x8*)&Bh[wc * 32 + i * 16 + lr][lk];
            bl[i] = *(const bf16x8*)&Bl[wc * 32 + i * 16 + lr][lk];
        }
        #pragma unroll
        for (int i = 0; i < 2; ++i)
            #pragma unroll
            for (int j = 0; j < 2; ++j) {
                acc[i][j] = __builtin_amdgcn_mfma_f32_16x16x32_bf16(al[i], bh[j], acc[i][j], 0, 0, 0);
                acc[i][j] = __builtin_amdgcn_mfma_f32_16x16x32_bf16(ah[i], bl[j], acc[i][j], 0, 0, 0);
                acc[i][j] = __builtin_amdgcn_mfma_f32_16x16x32_bf16(ah[i], bh[j], acc[i][j], 0, 0, 0);
            }
        __syncthreads();
    }

    const int lg = lane >> 4;
    #pragma unroll
    for (int i = 0; i < 2; ++i) {
        const int ob = o0 + wr * 32 + i * 16 + lg * 4;
        float bi[4];
        #pragma unroll
        for (int r = 0; r < 4; ++r) bi[r] = bias[ob + r];
        #pragma unroll
        for (int j = 0; j < 2; ++j) {
            const int gn = n0 + wc * 32 + j * 16 + lr;
            if (gn < Nout) {
                uint2 ph = make_uint2(0, 0), pl = make_uint2(0, 0);
                if (gn < N) {
                    unsigned short h[4], l[4];
                    #pragma unroll
                    for (int r = 0; r < 4; ++r) {
                        float v = acc[i][j][r] + bi[r];
                        h[r] = f2bf(v);
                        l[r] = f2bf(v - bf2f(h[r]));
                    }
                    ph.x = (unsigned)h[0] | ((unsigned)h[1] << 16);
                    ph.y = (unsigned)h[2] | ((unsigned)h[3] << 16);
                    pl.x = (unsigned)l[0] | ((unsigned)l[1] << 16);
                    pl.y = (unsigned)l[2] | ((unsigned)l[3] << 16);
                }
                size_t idx = ((size_t)b * Nout + gn) * O + ob;
                *(uint2*)&Yhi[idx] = ph;
                *(uint2*)&Ylo[idx] = pl;
            }
        }
    }
}

// ---------------------------------------------------------------------------
// Plain bf16 MFMA GEMM (z-side small: zf_g conv, zg2).
// ---------------------------------------------------------------------------
template<int MODE, int EPI>
__global__ __launch_bounds__(256)
void mfma_conv(const unsigned short* __restrict__ A, int aLd, size_t aStride,
               const unsigned short* __restrict__ B1,
               const float* __restrict__ bias, const float* __restrict__ gamma,
               const float* __restrict__ beta, const float* __restrict__ mean,
               const float* __restrict__ var,
               unsigned short* __restrict__ Y, int N, int Nout, int K, int O)
{
    __shared__ unsigned short As[64][40];
    __shared__ unsigned short Bs[64][40];

    const int b   = blockIdx.z;
    const int n0  = blockIdx.x * 64;
    const int o0  = blockIdx.y * 64;
    const int tid = threadIdx.x;
    const int lane = tid & 63, wid = tid >> 6;
    const int wr = wid >> 1, wc = wid & 1;

    const unsigned short* Ab  = A + (size_t)b * aStride;
    const unsigned short* B1b = B1 + (size_t)b * N * K;

    f32x4 acc[2][2];
    #pragma unroll
    for (int i = 0; i < 2; ++i)
        #pragma unroll
        for (int j = 0; j < 2; ++j)
            #pragma unroll
            for (int e = 0; e < 4; ++e) acc[i][j][e] = 0.f;

    const int srow = tid >> 2, sseg = tid & 3;
    const int lr = lane & 15, lk = (lane >> 4) * 8;

    for (int kc = 0; kc < K; kc += 32) {
        const int gk = kc + sseg * 8;
        *(int4*)&As[srow][sseg * 8] = *(const int4*)&Ab[(size_t)(o0 + srow) * aLd + gk];

        const int gn = n0 + srow;
        int4 bv = make_int4(0, 0, 0, 0);
        if (gn < N) bv = *(const int4*)&B1b[(size_t)gn * K + gk];
        *(int4*)&Bs[srow][sseg * 8] = bv;
        __syncthreads();

        bf16x8 a0 = *(const bf16x8*)&As[wr * 32 +      lr][lk];
        bf16x8 a1 = *(const bf16x8*)&As[wr * 32 + 16 + lr][lk];
        bf16x8 b0 = *(const bf16x8*)&Bs[wc * 32 +      lr][lk];
        bf16x8 b1 = *(const bf16x8*)&Bs[wc * 32 + 16 + lr][lk];

        acc[0][0] = __builtin_amdgcn_mfma_f32_16x16x32_bf16(a0, b0, acc[0][0], 0, 0, 0);
        acc[0][1] = __builtin_amdgcn_mfma_f32_16x16x32_bf16(a0, b1, acc[0][1], 0, 0, 0);
        acc[1][0] = __builtin_amdgcn_mfma_f32_16x16x32_bf16(a1, b0, acc[1][0], 0, 0, 0);
        acc[1][1] = __builtin_amdgcn_mfma_f32_16x16x32_bf16(a1, b1, acc[1][1], 0, 0, 0);
        __syncthreads();
    }

    const int lg = lane >> 4;
    #pragma unroll
    for (int i = 0; i < 2; ++i) {
        const int ob = o0 + wr * 32 + i * 16 + lg * 4;
        float inv[4], sh[4], bi[4];
        if (EPI) {
            #pragma unroll
            for (int r = 0; r < 4; ++r) {
                int o = ob + r;
                float iv = gamma[o] * rsqrtf(var[o] + EPS);
                inv[r] = iv; sh[r] = beta[o] - mean[o] * iv; bi[r] = bias[o];
            }
        }
        #pragma unroll
        for (int j = 0; j < 2; ++j) {
            const int gn = n0 + wc * 32 + j * 16 + lr;
            float v[4];
            #pragma unroll
            for (int r = 0; r < 4; ++r) {
                v[r] = acc[i][j][r];
                if (EPI) v[r] = fmaxf(fmaf(v[r] + bi[r], inv[r], sh[r]), 0.f);
            }
            if (MODE == 0) {
                if (gn < Nout) {
                    uint2 pk = make_uint2(0, 0);
                    if (gn < N) {
                        pk.x = (unsigned)f2bf(v[0]) | ((unsigned)f2bf(v[1]) << 16);
                        pk.y = (unsigned)f2bf(v[2]) | ((unsigned)f2bf(v[3]) << 16);
                    }
                    *(uint2*)&Y[((size_t)b * Nout + gn) * O + ob] = pk;
                }
            } else {
                if (gn < Nout) {
                    #pragma unroll
                    for (int r = 0; r < 4; ++r)
                        Y[((size_t)b * O + ob + r) * Nout + gn] =
                            (gn < N) ? f2bf(v[r]) : (unsigned short)0;
                }
            }
        }
    }
}

// ---------------------------------------------------------------------------
// X-side megakernel, per (b, 64-n tile):
//  sim : S = xf^T zq' + u   (split x3 MFMA, K=256)
//  sparsemax over m (169) -> scores bf16 in LDS
//  G   : XG = bn_relu(Wg . xf)   kept transposed in LDS
//  P1  : acc  = zg2 . score      (K=192, score from LDS)
//  P2  : acc += Wf2 . XG         (K=256, XG from LDS)
//  out = bn_relu(acc + bf)       f32 [b][256][Nx]
// LDS overlaid to 79,872 B (2 blocks/CU). XCD-swizzled block id.
// ---------------------------------------------------------------------------
__global__ __launch_bounds__(256)
void mega_x(const float* __restrict__ Xf,
            const unsigned short* __restrict__ Zqh,   // [b][192][256]
            const unsigned short* __restrict__ Zql,
            const unsigned short* __restrict__ Wg,    // [256][256]
            const unsigned short* __restrict__ Zg2,   // [b][256][192]
            const unsigned short* __restrict__ Wf2,   // [256][512] base+256
            const float* __restrict__ U,              // [b][192]
            const float* __restrict__ bg, const float* __restrict__ g_gamma,
            const float* __restrict__ g_beta, const float* __restrict__ g_mean,
            const float* __restrict__ g_var,
            const float* __restrict__ bf, const float* __restrict__ f_gamma,
            const float* __restrict__ f_beta, const float* __restrict__ f_mean,
            const float* __restrict__ f_var,
            float* __restrict__ out)
{
    __shared__ __attribute__((aligned(16))) char pool[79872];
    __shared__ float Us[192];

    // region S [0, 25600): sim XFh/XFl/Bzh; later Ssc[64][200]
    unsigned short* XFh = (unsigned short*)(pool);            // [64][40]
    unsigned short* XFl = (unsigned short*)(pool + 5120);     // [64][40]
    unsigned short* Bzh = (unsigned short*)(pool + 10240);    // [192][40]
    unsigned short* Ssc = (unsigned short*)(pool);            // [64][200]
    // region A [25600, 46080): sim Bzl; later As[256][40]
    unsigned short* Bzl = (unsigned short*)(pool + 25600);    // [192][40]
    unsigned short* As  = (unsigned short*)(pool + 25600);    // [256][40]
    // region X [46080, 79872): G-phase XFg[64][40]; later XG[64][264]
    unsigned short* XFg = (unsigned short*)(pool + 46080);    // [64][40]
    unsigned short* XG  = (unsigned short*)(pool + 46080);    // [64][264]

    // XCD-aware swizzle: 1280 blocks, 1280 % 8 == 0 -> bijective
    const int g0  = blockIdx.z * gridDim.x + blockIdx.x;
    const int rid = (g0 & 7) * 160 + (g0 >> 3);
    const int b   = rid / 10;
    const int n0  = (rid % 10) * 64;

    const int tid = threadIdx.x;
    const int lane = tid & 63, w = tid >> 6;
    const int lr = lane & 15, lg = lane >> 4, lk = lg * 8;
    const int brow = tid >> 2, bseg = tid & 3;

    const unsigned short* Zqhb = Zqh + (size_t)b * NzP * C;
    const unsigned short* Zqlb = Zql + (size_t)b * NzP * C;
    const unsigned short* Zg2b = Zg2 + (size_t)b * C * NzP;

    if (tid < 192) Us[tid] = U[(size_t)b * NzP + tid];

    // ================= sim phase =================
    f32x4 sacc[12];
    #pragma unroll
    for (int j = 0; j < 12; ++j)
        #pragma unroll
        for (int e = 0; e < 4; ++e) sacc[j][e] = 0.f;

    for (int kc = 0; kc < C; kc += 32) {
        // stage xf tile from f32, split hi/lo
        {
            const int gn = min(n0 + brow, Nx - 1);
            const float* src = Xf + ((size_t)b * C + kc + bseg * 8) * Nx + gn;
            unsigned short h[8], l[8];
            #pragma unroll
            for (int e = 0; e < 8; ++e) {
                float v = src[(size_t)e * Nx];
                h[e] = f2bf(v);
                l[e] = f2bf(v - bf2f(h[e]));
            }
            uint4 ph, pl;
            ph.x = (unsigned)h[0] | ((unsigned)h[1] << 16);
            ph.y = (unsigned)h[2] | ((unsigned)h[3] << 16);
            ph.z = (unsigned)h[4] | ((unsigned)h[5] << 16);
            ph.w = (unsigned)h[6] | ((unsigned)h[7] << 16);
            pl.x = (unsigned)l[0] | ((unsigned)l[1] << 16);
            pl.y = (unsigned)l[2] | ((unsigned)l[3] << 16);
            pl.z = (unsigned)l[4] | ((unsigned)l[5] << 16);
            pl.w = (unsigned)l[6] | ((unsigned)l[7] << 16);
            *(uint4*)&XFh[brow * 40 + bseg * 8] = ph;
            *(uint4*)&XFl[brow * 40 + bseg * 8] = pl;
        }
        // stage zq' hi/lo (192 rows x 32 k) — 3 slots/thread
        #pragma unroll
        for (int i = 0; i < 3; ++i) {
            const int slot = tid + 256 * i;
            const int r = slot >> 2, s = slot & 3;
            const int gk = kc + s * 8;
            *(int4*)&Bzh[r * 40 + s * 8] = *(const int4*)&Zqhb[(size_t)r * C + gk];
            *(int4*)&Bzl[r * 40 + s * 8] = *(const int4*)&Zqlb[(size_t)r * C + gk];
        }
        __syncthreads();

        bf16x8 a0h = *(const bf16x8*)&XFh[(w * 16 + lr) * 40 + lk];
        bf16x8 a0l = *(const bf16x8*)&XFl[(w * 16 + lr) * 40 + lk];
        #pragma unroll
        for (int j = 0; j < 12; ++j) {
            bf16x8 bh = *(const bf16x8*)&Bzh[(j * 16 + lr) * 40 + lk];
            bf16x8 bl = *(const bf16x8*)&Bzl[(j * 16 + lr) * 40 + lk];
            sacc[j] = __builtin_amdgcn_mfma_f32_16x16x32_bf16(a0l, bh, sacc[j], 0, 0, 0);
            sacc[j] = __builtin_amdgcn_mfma_f32_16x16x32_bf16(a0h, bl, sacc[j], 0, 0, 0);
            sacc[j] = __builtin_amdgcn_mfma_f32_16x16x32_bf16(a0h, bh, sacc[j], 0, 0, 0);
        }
        __syncthreads();
    }

    // add u[m], mask padded m
    #pragma unroll
    for (int j = 0; j < 12; ++j) {
        const int m = j * 16 + lr;
        const float uv = Us[m];
        const bool bad = (m >= Nz);
        #pragma unroll
        for (int q = 0; q < 4; ++q)
            sacc[j][q] = bad ? -1e30f : (sacc[j][q] + uv);
    }

    // row max over 12 regs + 16 lanes (m dimension)
    f32x4 mx = sacc[0];
    #pragma unroll
    for (int j = 1; j < 12; ++j)
        #pragma unroll
        for (int q = 0; q < 4; ++q) mx[q] = fmaxf(mx[q], sacc[j][q]);
    #pragma unroll
    for (int off = 1; off < 16; off <<= 1)
        #pragma unroll
        for (int q = 0; q < 4; ++q) mx[q] = fmaxf(mx[q], __shfl_xor(mx[q], off));

    // Newton on tau
    f32x4 tau;
    #pragma unroll
    for (int q = 0; q < 4; ++q) tau[q] = mx[q] - 1.0f;

    for (int it = 0; it < 16; ++it) {
        f32x4 s, cnt;
        #pragma unroll
        for (int q = 0; q < 4; ++q) { s[q] = 0.f; cnt[q] = 0.f; }
        #pragma unroll
        for (int j = 0; j < 12; ++j)
            #pragma unroll
            for (int q = 0; q < 4; ++q)
                if (sacc[j][q] > tau[q]) { s[q] += sacc[j][q]; cnt[q] += 1.f; }
        #pragma unroll
        for (int off = 1; off < 16; off <<= 1)
            #pragma unroll
            for (int q = 0; q < 4; ++q) {
                s[q]   += __shfl_xor(s[q], off);
                cnt[q] += __shfl_xor(cnt[q], off);
            }
        bool adv = false;
        #pragma unroll
        for (int q = 0; q < 4; ++q) {
            float nt = (s[q] - 1.0f) / cnt[q];
            if (nt > tau[q]) { tau[q] = nt; adv = true; }
        }
        if (!__any(adv ? 1 : 0)) break;
    }

    // scores -> Ssc LDS (overwrites sim staging; safe after last sync)
    #pragma unroll
    for (int q = 0; q < 4; ++q) {
        const int n = w * 16 + 4 * lg + q;
        #pragma unroll
        for (int j = 0; j < 12; ++j) {
            const int m = j * 16 + lr;
            float sv = (m < Nz) ? fmaxf(sacc[j][q] - tau[q], 0.f) : 0.f;
            Ssc[n * 200 + m] = f2bf(sv);
        }
    }

    // ================= G phase =================
    f32x4 acc[4][4];
    #pragma unroll
    for (int i = 0; i < 4; ++i)
        #pragma unroll
        for (int j = 0; j < 4; ++j)
            #pragma unroll
            for (int e = 0; e < 4; ++e) acc[i][j][e] = 0.f;

    for (int kc = 0; kc < C; kc += 32) {
        #pragma unroll
        for (int s = 0; s < 4; ++s) {
            int e = tid + 256 * s;
            int row = e >> 2, seg = e & 3;
            *(int4*)&As[row * 40 + seg * 8] = *(const int4*)&Wg[(size_t)row * C + kc + seg * 8];
        }
        {
            const int gn = min(n0 + brow, Nx - 1);
            const float* src = Xf + ((size_t)b * C + kc + bseg * 8) * Nx + gn;
            unsigned short h[8];
            #pragma unroll
            for (int e = 0; e < 8; ++e) h[e] = f2bf(src[(size_t)e * Nx]);
            uint4 ph;
            ph.x = (unsigned)h[0] | ((unsigned)h[1] << 16);
            ph.y = (unsigned)h[2] | ((unsigned)h[3] << 16);
            ph.z = (unsigned)h[4] | ((unsigned)h[5] << 16);
            ph.w = (unsigned)h[6] | ((unsigned)h[7] << 16);
            *(uint4*)&XFg[brow * 40 + bseg * 8] = ph;
        }
        __syncthreads();

        bf16x8 a[4], bfr[4];
        #pragma unroll
        for (int i = 0; i < 4; ++i) a[i]   = *(const bf16x8*)&As[(w * 64 + i * 16 + lr) * 40 + lk];
        #pragma unroll
        for (int j = 0; j < 4; ++j) bfr[j] = *(const bf16x8*)&XFg[(j * 16 + lr) * 40 + lk];
        #pragma unroll
        for (int i = 0; i < 4; ++i)
            #pragma unroll
            for (int j = 0; j < 4; ++j)
                acc[i][j] = __builtin_amdgcn_mfma_f32_16x16x32_bf16(a[i], bfr[j], acc[i][j], 0, 0, 0);
        __syncthreads();
    }

    // G epilogue: bn_relu -> XG[n][o] bf16 (overwrites XFg; safe after sync)
    #pragma unroll
    for (int i = 0; i < 4; ++i) {
        const int ob = w * 64 + i * 16 + lg * 4;
        float inv[4], sh[4], bi[4];
        #pragma unroll
        for (int r = 0; r < 4; ++r) {
            int o = ob + r;
            float iv = g_gamma[o] * rsqrtf(g_var[o] + EPS);
            inv[r] = iv; sh[r] = g_beta[o] - g_mean[o] * iv; bi[r] = bg[o];
        }
        #pragma unroll
        for (int j = 0; j < 4; ++j) {
            unsigned short h[4];
            #pragma unroll
            for (int r = 0; r < 4; ++r)
                h[r] = f2bf(fmaxf(fmaf(acc[i][j][r] + bi[r], inv[r], sh[r]), 0.f));
            uint2 pk;
            pk.x = (unsigned)h[0] | ((unsigned)h[1] << 16);
            pk.y = (unsigned)h[2] | ((unsigned)h[3] << 16);
            *(uint2*)&XG[(j * 16 + lr) * 264 + ob] = pk;
        }
    }
    #pragma unroll
    for (int i = 0; i < 4; ++i)
        #pragma unroll
        for (int j = 0; j < 4; ++j)
            #pragma unroll
            for (int e = 0; e < 4; ++e) acc[i][j][e] = 0.f;
    __syncthreads();

    // ================= P1: zg2 x score (K=192, B from LDS) =================
    for (int kc = 0; kc < NzP; kc += 32) {
        #pragma unroll
        for (int s = 0; s < 4; ++s) {
            int e = tid + 256 * s;
            int row = e >> 2, seg = e & 3;
            *(int4*)&As[row * 40 + seg * 8] = *(const int4*)&Zg2b[(size_t)row * NzP + kc + seg * 8];
        }
        __syncthreads();

        bf16x8 a[4], bfr[4];
        #pragma unroll
        for (int i = 0; i < 4; ++i) a[i]   = *(const bf16x8*)&As[(w * 64 + i * 16 + lr) * 40 + lk];
        #pragma unroll
        for (int j = 0; j < 4; ++j) bfr[j] = *(const bf16x8*)&Ssc[(j * 16 + lr) * 200 + kc + lk];
        #pragma unroll
        for (int i = 0; i < 4; ++i)
            #pragma unroll
            for (int j = 0; j < 4; ++j)
                acc[i][j] = __builtin_amdgcn_mfma_f32_16x16x32_bf16(a[i], bfr[j], acc[i][j], 0, 0, 0);
        __syncthreads();
    }

    // ================= P2: Wf2 x XG (K=256, B from LDS) =================
    for (int kc = 0; kc < C; kc += 32) {
        #pragma unroll
        for (int s = 0; s < 4; ++s) {
            int e = tid + 256 * s;
            int row = e >> 2, seg = e & 3;
            *(int4*)&As[row * 40 + seg * 8] = *(const int4*)&Wf2[(size_t)row * 512 + kc + seg * 8];
        }
        __syncthreads();

        bf16x8 a[4], bfr[4];
        #pragma unroll
        for (int i = 0; i < 4; ++i) a[i]   = *(const bf16x8*)&As[(w * 64 + i * 16 + lr) * 40 + lk];
        #pragma unroll
        for (int j = 0; j < 4; ++j) bfr[j] = *(const bf16x8*)&XG[(j * 16 + lr) * 264 + kc + lk];
        #pragma unroll
        for (int i = 0; i < 4; ++i)
            #pragma unroll
            for (int j = 0; j < 4; ++j)
                acc[i][j] = __builtin_amdgcn_mfma_f32_16x16x32_bf16(a[i], bfr[j], acc[i][j], 0, 0, 0);
        __syncthreads();
    }

    // final epilogue: bn_relu(f) -> out f32 [b][256][Nx]
    #pragma unroll
    for (int i = 0; i < 4; ++i) {
        const int ob = w * 64 + i * 16 + lg * 4;
        float inv[4], sh[4], bi[4];
        #pragma unroll
        for (int r = 0; r < 4; ++r) {
            int o = ob + r;
            float iv = f_gamma[o] * rsqrtf(f_var[o] + EPS);
            inv[r] = iv; sh[r] = f_beta[o] - f_mean[o] * iv; bi[r] = bf[o];
        }
        #pragma unroll
        for (int j = 0; j < 4; ++j) {
            const int gn = n0 + j * 16 + lr;
            if (gn < Nx) {
                #pragma unroll
                for (int r = 0; r < 4; ++r) {
                    float v = fmaxf(fmaf(acc[i][j][r] + bi[r], inv[r], sh[r]), 0.f);
                    out[((size_t)b * C + ob + r) * Nx + gn] = v;
                }
            }
        }
    }
}

// ---------------------------------------------------------------------------
extern "C" void kernel_launch(void* const* d_in, const int* in_sizes, int n_in,
                              void* d_out, int out_size, void* d_ws, size_t ws_size,
                              hipStream_t stream)
{
    const float* zf      = (const float*)d_in[0];
    const float* xf      = (const float*)d_in[1];
    const float* Wq      = (const float*)d_in[2];
    const float* bq      = (const float*)d_in[3];
    const float* Ws_     = (const float*)d_in[4];
    const float* bs      = (const float*)d_in[5];
    const float* Wg      = (const float*)d_in[6];
    const float* bg      = (const float*)d_in[7];
    const float* g_gamma = (const float*)d_in[8];
    const float* g_beta  = (const float*)d_in[9];
    const float* g_mean  = (const float*)d_in[10];
    const float* g_var   = (const float*)d_in[11];
    const float* Wf      = (const float*)d_in[12];
    const float* bf_     = (const float*)d_in[13];
    const float* f_gamma = (const float*)d_in[14];
    const float* f_beta  = (const float*)d_in[15];
    const float* f_mean  = (const float*)d_in[16];
    const float* f_var   = (const float*)d_in[17];
    float* out = (float*)d_out;

    typedef unsigned short u16;
    char* ws = (char*)d_ws;
    u16*   zfT_hi = (u16*)(ws);                   //  11,075,584
    u16*   zfT_lo = (u16*)(ws +  11075584);       //  11,075,584
    u16*   zqT_hi = (u16*)(ws +  22151168);       //  12,582,912
    u16*   zqT_lo = (u16*)(ws +  34734080);       //  12,582,912
    u16*   zf_gT  = (u16*)(ws +  47316992);       //  12,582,912
    u16*   zg2    = (u16*)(ws +  59899904);       //  12,582,912
    float* U      = (float*)(ws +  72482816);     //      98,304
    u16*   Mhi    = (u16*)(ws +  72581120);       //     131,072
    u16*   Mlo    = (u16*)(ws +  72712192);       //     131,072
    u16*   Wg_bf  = (u16*)(ws +  72843264);       //     131,072
    u16*   Wf_bf  = (u16*)(ws +  72974336);       //     262,144
    float* wv     = (float*)(ws +  73236480);     //       1,024
    float* wu     = (float*)(ws +  73237504);     //       1,024
    float* c0     = (float*)(ws +  73238528);     //         256

    dim3 blk(256);
    const int gx_x = (Nx + 63) / 64;   // 10
    const int gx_z = NzP / 64;         // 3

    // small precomputes
    cvt_wgf<<<dim3((C * 2 * C + 255) / 256), blk, 0, stream>>>(Wg, Wf, Wg_bf, Wf_bf);
    prep_small<<<dim3(1), blk, 0, stream>>>(Wq, Ws_, bq, bs, wv, wu, c0);
    m_gemm<<<dim3(4, 4), blk, 0, stream>>>(Wq, Ws_, Mhi, Mlo);
    bias_u<<<dim3(Bb), blk, 0, stream>>>(zf, wu, c0, U);

    // z-side transpose/split
    x2t_split<<<dim3((Nz + 63) / 64, C / 64, Bb), blk, 0, stream>>>(zf, zfT_hi, zfT_lo, Nz);

    // zq' = M zf + wv  (split)
    mfma_split<<<dim3(gx_z, C / 64, Bb), blk, 0, stream>>>(
        Mhi, Mlo, 0, zfT_hi, zfT_lo, wv, zqT_hi, zqT_lo, Nz, NzP, C, C);

    // zf_g = bn_relu(Wg . zf)
    mfma_conv<0, 1><<<dim3(gx_z, C / 64, Bb), blk, 0, stream>>>(
        Wg_bf, C, 0, zfT_hi, bg, g_gamma, g_beta, g_mean, g_var,
        zf_gT, Nz, NzP, C, C);

    // zg2 = Wf1 . zf_g   -> [b][C][NzP] bf16
    mfma_conv<1, 0><<<dim3(gx_z, C / 64, Bb), blk, 0, stream>>>(
        Wf_bf, 2 * C, 0, zf_gT, nullptr, nullptr, nullptr, nullptr, nullptr,
        zg2, NzP, NzP, C, C);

    // x-side megakernel: sim + sparsemax + g-conv + final conv
    mega_x<<<dim3(gx_x, 1, Bb), blk, 0, stream>>>(
        xf, zqT_hi, zqT_lo, Wg_bf, zg2, Wf_bf + C, U,
        bg, g_gamma, g_beta, g_mean, g_var,
        bf_, f_gamma, f_beta, f_mean, f_var, out);
}

// Round 8
// 251.392 us; speedup vs baseline: 6.2572x; 1.0457x over previous
//
#include <hip/hip_runtime.h>
#include <math.h>

#define EPS 1e-5f

constexpr int Bb  = 128;
constexpr int C   = 256;
constexpr int Nz  = 169;   // 13*13
constexpr int Nx  = 625;   // 25*25
constexpr int NzP = 192;   // Nz padded (zero-filled)

typedef __bf16 bf16x8 __attribute__((ext_vector_type(8)));
typedef float  f32x4  __attribute__((ext_vector_type(4)));

__device__ __forceinline__ unsigned short f2bf(float f) {
    union { float f; unsigned u; } x; x.f = f;
    unsigned r = x.u + 0x7FFFu + ((x.u >> 16) & 1u);   // RNE
    return (unsigned short)(r >> 16);
}
__device__ __forceinline__ float bf2f(unsigned short h) {
    union { unsigned u; float f; } x; x.u = ((unsigned)h) << 16;
    return x.f;
}

// ---------------------------------------------------------------------------
// Wg, Wf → bf16
// ---------------------------------------------------------------------------
__global__ void cvt_wgf(const float* __restrict__ Wg, const float* __restrict__ Wf,
                        unsigned short* __restrict__ g, unsigned short* __restrict__ f)
{
    int i = blockIdx.x * 256 + threadIdx.x;
    if (i < C * C) g[i] = f2bf(Wg[i]);
    if (i < C * 2 * C) f[i] = f2bf(Wf[i]);
}

// ---------------------------------------------------------------------------
// wv = Wq^T bs, wu = Ws^T bq, c0 = bq.bs
// ---------------------------------------------------------------------------
__global__ void prep_small(const float* __restrict__ Wq, const float* __restrict__ Ws,
                           const float* __restrict__ bq, const float* __restrict__ bs,
                           float* __restrict__ wv, float* __restrict__ wu,
                           float* __restrict__ c0)
{
    const int tid = threadIdx.x;
    float a = 0.f, b = 0.f;
    for (int o = 0; o < C; ++o) {
        a += Wq[o * C + tid] * bs[o];
        b += Ws[o * C + tid] * bq[o];
    }
    wv[tid] = a;
    wu[tid] = b;
    if (tid == 0) {
        float c = 0.f;
        for (int o = 0; o < C; ++o) c += bq[o] * bs[o];
        c0[0] = c;
    }
}

// ---------------------------------------------------------------------------
// M = Wq^T Ws  (fp32 compute, split bf16 hi/lo output).  grid (4,4)
// ---------------------------------------------------------------------------
__global__ __launch_bounds__(256)
void m_gemm(const float* __restrict__ Wq, const float* __restrict__ Ws,
            unsigned short* __restrict__ Mhi, unsigned short* __restrict__ Mlo)
{
    __shared__ float Qs[16][65], Ss[16][65];
    const int j0 = blockIdx.x * 64, i0 = blockIdx.y * 64;
    const int tid = threadIdx.x, tx = tid & 15, ty = tid >> 4;
    float acc[4][4] = {};

    for (int kc = 0; kc < C; kc += 16) {
        #pragma unroll
        for (int i = 0; i < 4; ++i) {
            int e = tid + 256 * i;
            int k = e >> 6, col = e & 63;
            Qs[k][col] = Wq[(size_t)(kc + k) * C + i0 + col];
            Ss[k][col] = Ws[(size_t)(kc + k) * C + j0 + col];
        }
        __syncthreads();
        #pragma unroll
        for (int k = 0; k < 16; ++k) {
            float a[4], bv[4];
            #pragma unroll
            for (int i = 0; i < 4; ++i) a[i] = Qs[k][ty * 4 + i];
            #pragma unroll
            for (int j = 0; j < 4; ++j) bv[j] = Ss[k][tx * 4 + j];
            #pragma unroll
            for (int i = 0; i < 4; ++i)
                #pragma unroll
                for (int j = 0; j < 4; ++j)
                    acc[i][j] = fmaf(a[i], bv[j], acc[i][j]);
        }
        __syncthreads();
    }
    #pragma unroll
    for (int i = 0; i < 4; ++i)
        #pragma unroll
        for (int j = 0; j < 4; ++j) {
            float v = acc[i][j];
            unsigned short h = f2bf(v);
            size_t idx = (size_t)(i0 + ty * 4 + i) * C + j0 + tx * 4 + j;
            Mhi[idx] = h;
            Mlo[idx] = f2bf(v - bf2f(h));
        }
}

// ---------------------------------------------------------------------------
// u[b,m] = wu . zf[b,:,m] + c0
// ---------------------------------------------------------------------------
__global__ void bias_u(const float* __restrict__ zf, const float* __restrict__ wu,
                       const float* __restrict__ c0, float* __restrict__ U)
{
    const int b = blockIdx.x, m = threadIdx.x;
    if (m >= NzP) return;
    float s = 0.f;
    if (m < Nz) {
        const float* zb = zf + (size_t)b * C * Nz + m;
        float s0 = 0.f, s1 = 0.f, s2 = 0.f, s3 = 0.f;
        for (int c = 0; c < C; c += 4) {
            s0 += wu[c]     * zb[(size_t)c * Nz];
            s1 += wu[c + 1] * zb[(size_t)(c + 1) * Nz];
            s2 += wu[c + 2] * zb[(size_t)(c + 2) * Nz];
            s3 += wu[c + 3] * zb[(size_t)(c + 3) * Nz];
        }
        s = (s0 + s1) + (s2 + s3) + c0[0];
    }
    U[(size_t)b * NzP + m] = s;
}

// ---------------------------------------------------------------------------
// zf [b][C][Nz] f32  →  hi/lo bf16 [b][Nz][C]
// ---------------------------------------------------------------------------
__global__ __launch_bounds__(256)
void x2t_split(const float* __restrict__ X, unsigned short* __restrict__ Hi,
               unsigned short* __restrict__ Lo, int N)
{
    __shared__ float T[64][65];
    const int b = blockIdx.z, n0 = blockIdx.x * 64, c0 = blockIdx.y * 64;
    const float* Xb = X + ((size_t)b * C + c0) * N;
    #pragma unroll
    for (int i = 0; i < 16; ++i) {
        int e = threadIdx.x + 256 * i;
        int c = e >> 6, n = e & 63;
        T[c][n] = (n0 + n < N) ? Xb[(size_t)c * N + n0 + n] : 0.f;
    }
    __syncthreads();
    #pragma unroll
    for (int i = 0; i < 16; ++i) {
        int e = threadIdx.x + 256 * i;
        int n = e >> 6, c = e & 63;
        if (n0 + n < N) {
            float v = T[c][n];
            unsigned short h = f2bf(v);
            size_t idx = ((size_t)b * N + n0 + n) * C + c0 + c;
            Hi[idx] = h;
            Lo[idx] = f2bf(v - bf2f(h));
        }
    }
}

// ---------------------------------------------------------------------------
// Split-bf16 MFMA GEMM — z-side zq' = M zf + wv.
// ---------------------------------------------------------------------------
__global__ __launch_bounds__(256)
void mfma_split(const unsigned short* __restrict__ Ahi,
                const unsigned short* __restrict__ Alo, size_t aStride,
                const unsigned short* __restrict__ Bhi,
                const unsigned short* __restrict__ Blo,
                const float* __restrict__ bias,
                unsigned short* __restrict__ Yhi, unsigned short* __restrict__ Ylo,
                int N, int Nout, int K, int O)
{
    __shared__ unsigned short Ah[64][40], Al[64][40], Bh[64][40], Bl[64][40];

    const int b   = blockIdx.z;
    const int n0  = blockIdx.x * 64;
    const int o0  = blockIdx.y * 64;
    const int tid = threadIdx.x;
    const int lane = tid & 63, wid = tid >> 6;
    const int wr = wid >> 1, wc = wid & 1;

    const unsigned short* Ahb = Ahi + (size_t)b * aStride;
    const unsigned short* Alb = Alo + (size_t)b * aStride;
    const unsigned short* Bhb = Bhi + (size_t)b * N * K;
    const unsigned short* Blb = Blo + (size_t)b * N * K;

    f32x4 acc[2][2];
    #pragma unroll
    for (int i = 0; i < 2; ++i)
        #pragma unroll
        for (int j = 0; j < 2; ++j)
            #pragma unroll
            for (int e = 0; e < 4; ++e) acc[i][j][e] = 0.f;

    const int srow = tid >> 2, sseg = tid & 3;
    const int lr = lane & 15, lk = (lane >> 4) * 8;

    for (int kc = 0; kc < K; kc += 32) {
        const int gk = kc + sseg * 8;
        *(int4*)&Ah[srow][sseg * 8] = *(const int4*)&Ahb[(size_t)(o0 + srow) * K + gk];
        *(int4*)&Al[srow][sseg * 8] = *(const int4*)&Alb[(size_t)(o0 + srow) * K + gk];

        const int gn = n0 + srow;
        int4 bv = make_int4(0, 0, 0, 0), blv = make_int4(0, 0, 0, 0);
        if (gn < N) {
            bv  = *(const int4*)&Bhb[(size_t)gn * K + gk];
            blv = *(const int4*)&Blb[(size_t)gn * K + gk];
        }
        *(int4*)&Bh[srow][sseg * 8] = bv;
        *(int4*)&Bl[srow][sseg * 8] = blv;
        __syncthreads();

        bf16x8 ah[2], al[2], bh[2], bl[2];
        #pragma unroll
        for (int i = 0; i < 2; ++i) {
            ah[i] = *(const bf16x8*)&Ah[wr * 32 + i * 16 + lr][lk];
            al[i] = *(const bf16x8*)&Al[wr * 32 + i * 16 + lr][lk];
            bh[i] = *(const bf16x8*)&Bh[wc * 32 + i * 16 + lr][lk];
            bl[i] = *(const bf16x8*)&Bl[wc * 32 + i * 16 + lr][lk];
        }
        #pragma unroll
        for (int i = 0; i < 2; ++i)
            #pragma unroll
            for (int j = 0; j < 2; ++j) {
                acc[i][j] = __builtin_amdgcn_mfma_f32_16x16x32_bf16(al[i], bh[j], acc[i][j], 0, 0, 0);
                acc[i][j] = __builtin_amdgcn_mfma_f32_16x16x32_bf16(ah[i], bl[j], acc[i][j], 0, 0, 0);
                acc[i][j] = __builtin_amdgcn_mfma_f32_16x16x32_bf16(ah[i], bh[j], acc[i][j], 0, 0, 0);
            }
        __syncthreads();
    }

    const int lg = lane >> 4;
    #pragma unroll
    for (int i = 0; i < 2; ++i) {
        const int ob = o0 + wr * 32 + i * 16 + lg * 4;
        float bi[4];
        #pragma unroll
        for (int r = 0; r < 4; ++r) bi[r] = bias[ob + r];
        #pragma unroll
        for (int j = 0; j < 2; ++j) {
            const int gn = n0 + wc * 32 + j * 16 + lr;
            if (gn < Nout) {
                uint2 ph = make_uint2(0, 0), pl = make_uint2(0, 0);
                if (gn < N) {
                    unsigned short h[4], l[4];
                    #pragma unroll
                    for (int r = 0; r < 4; ++r) {
                        float v = acc[i][j][r] + bi[r];
                        h[r] = f2bf(v);
                        l[r] = f2bf(v - bf2f(h[r]));
                    }
                    ph.x = (unsigned)h[0] | ((unsigned)h[1] << 16);
                    ph.y = (unsigned)h[2] | ((unsigned)h[3] << 16);
                    pl.x = (unsigned)l[0] | ((unsigned)l[1] << 16);
                    pl.y = (unsigned)l[2] | ((unsigned)l[3] << 16);
                }
                size_t idx = ((size_t)b * Nout + gn) * O + ob;
                *(uint2*)&Yhi[idx] = ph;
                *(uint2*)&Ylo[idx] = pl;
            }
        }
    }
}

// ---------------------------------------------------------------------------
// Plain bf16 MFMA GEMM (z-side small: zf_g conv, zg2).
// ---------------------------------------------------------------------------
template<int MODE, int EPI>
__global__ __launch_bounds__(256)
void mfma_conv(const unsigned short* __restrict__ A, int aLd, size_t aStride,
               const unsigned short* __restrict__ B1,
               const float* __restrict__ bias, const float* __restrict__ gamma,
               const float* __restrict__ beta, const float* __restrict__ mean,
               const float* __restrict__ var,
               unsigned short* __restrict__ Y, int N, int Nout, int K, int O)
{
    __shared__ unsigned short As[64][40];
    __shared__ unsigned short Bs[64][40];

    const int b   = blockIdx.z;
    const int n0  = blockIdx.x * 64;
    const int o0  = blockIdx.y * 64;
    const int tid = threadIdx.x;
    const int lane = tid & 63, wid = tid >> 6;
    const int wr = wid >> 1, wc = wid & 1;

    const unsigned short* Ab  = A + (size_t)b * aStride;
    const unsigned short* B1b = B1 + (size_t)b * N * K;

    f32x4 acc[2][2];
    #pragma unroll
    for (int i = 0; i < 2; ++i)
        #pragma unroll
        for (int j = 0; j < 2; ++j)
            #pragma unroll
            for (int e = 0; e < 4; ++e) acc[i][j][e] = 0.f;

    const int srow = tid >> 2, sseg = tid & 3;
    const int lr = lane & 15, lk = (lane >> 4) * 8;

    for (int kc = 0; kc < K; kc += 32) {
        const int gk = kc + sseg * 8;
        *(int4*)&As[srow][sseg * 8] = *(const int4*)&Ab[(size_t)(o0 + srow) * aLd + gk];

        const int gn = n0 + srow;
        int4 bv = make_int4(0, 0, 0, 0);
        if (gn < N) bv = *(const int4*)&B1b[(size_t)gn * K + gk];
        *(int4*)&Bs[srow][sseg * 8] = bv;
        __syncthreads();

        bf16x8 a0 = *(const bf16x8*)&As[wr * 32 +      lr][lk];
        bf16x8 a1 = *(const bf16x8*)&As[wr * 32 + 16 + lr][lk];
        bf16x8 b0 = *(const bf16x8*)&Bs[wc * 32 +      lr][lk];
        bf16x8 b1 = *(const bf16x8*)&Bs[wc * 32 + 16 + lr][lk];

        acc[0][0] = __builtin_amdgcn_mfma_f32_16x16x32_bf16(a0, b0, acc[0][0], 0, 0, 0);
        acc[0][1] = __builtin_amdgcn_mfma_f32_16x16x32_bf16(a0, b1, acc[0][1], 0, 0, 0);
        acc[1][0] = __builtin_amdgcn_mfma_f32_16x16x32_bf16(a1, b0, acc[1][0], 0, 0, 0);
        acc[1][1] = __builtin_amdgcn_mfma_f32_16x16x32_bf16(a1, b1, acc[1][1], 0, 0, 0);
        __syncthreads();
    }

    const int lg = lane >> 4;
    #pragma unroll
    for (int i = 0; i < 2; ++i) {
        const int ob = o0 + wr * 32 + i * 16 + lg * 4;
        float inv[4], sh[4], bi[4];
        if (EPI) {
            #pragma unroll
            for (int r = 0; r < 4; ++r) {
                int o = ob + r;
                float iv = gamma[o] * rsqrtf(var[o] + EPS);
                inv[r] = iv; sh[r] = beta[o] - mean[o] * iv; bi[r] = bias[o];
            }
        }
        #pragma unroll
        for (int j = 0; j < 2; ++j) {
            const int gn = n0 + wc * 32 + j * 16 + lr;
            float v[4];
            #pragma unroll
            for (int r = 0; r < 4; ++r) {
                v[r] = acc[i][j][r];
                if (EPI) v[r] = fmaxf(fmaf(v[r] + bi[r], inv[r], sh[r]), 0.f);
            }
            if (MODE == 0) {
                if (gn < Nout) {
                    uint2 pk = make_uint2(0, 0);
                    if (gn < N) {
                        pk.x = (unsigned)f2bf(v[0]) | ((unsigned)f2bf(v[1]) << 16);
                        pk.y = (unsigned)f2bf(v[2]) | ((unsigned)f2bf(v[3]) << 16);
                    }
                    *(uint2*)&Y[((size_t)b * Nout + gn) * O + ob] = pk;
                }
            } else {
                if (gn < Nout) {
                    #pragma unroll
                    for (int r = 0; r < 4; ++r)
                        Y[((size_t)b * O + ob + r) * Nout + gn] =
                            (gn < N) ? f2bf(v[r]) : (unsigned short)0;
                }
            }
        }
    }
}

// ---------------------------------------------------------------------------
// X-side megakernel, per (b, 64-n tile):
//  sim : S = xf^T zq' + u   (split x3 MFMA, K=256)
//  sparsemax over m (169) -> scores bf16 in LDS
//  G   : XG = bn_relu(Wg . xf)   kept transposed in LDS
//  P1  : acc  = zg2 . score      (K=192, score from LDS)
//  P2  : acc += Wf2 . XG         (K=256, XG from LDS)
//  out = bn_relu(acc + bf)       f32 [b][256][Nx]
// LDS overlaid to 79,872 B (2 blocks/CU). XCD-swizzled block id.
// ---------------------------------------------------------------------------
__global__ __launch_bounds__(256)
void mega_x(const float* __restrict__ Xf,
            const unsigned short* __restrict__ Zqh,   // [b][192][256]
            const unsigned short* __restrict__ Zql,
            const unsigned short* __restrict__ Wg,    // [256][256]
            const unsigned short* __restrict__ Zg2,   // [b][256][192]
            const unsigned short* __restrict__ Wf2,   // [256][512] base+256
            const float* __restrict__ U,              // [b][192]
            const float* __restrict__ bg, const float* __restrict__ g_gamma,
            const float* __restrict__ g_beta, const float* __restrict__ g_mean,
            const float* __restrict__ g_var,
            const float* __restrict__ bf, const float* __restrict__ f_gamma,
            const float* __restrict__ f_beta, const float* __restrict__ f_mean,
            const float* __restrict__ f_var,
            float* __restrict__ out)
{
    __shared__ __attribute__((aligned(16))) char pool[79872];
    __shared__ float Us[192];

    // region S [0, 25600): sim XFh/XFl/Bzh; later Ssc[64][200]
    unsigned short* XFh = (unsigned short*)(pool);            // [64][40]
    unsigned short* XFl = (unsigned short*)(pool + 5120);     // [64][40]
    unsigned short* Bzh = (unsigned short*)(pool + 10240);    // [192][40]
    unsigned short* Ssc = (unsigned short*)(pool);            // [64][200]
    // region A [25600, 46080): sim Bzl; later As[256][40]
    unsigned short* Bzl = (unsigned short*)(pool + 25600);    // [192][40]
    unsigned short* As  = (unsigned short*)(pool + 25600);    // [256][40]
    // region X [46080, 79872): G-phase XFg[64][40]; later XG[64][264]
    unsigned short* XFg = (unsigned short*)(pool + 46080);    // [64][40]
    unsigned short* XG  = (unsigned short*)(pool + 46080);    // [64][264]

    // XCD-aware swizzle: 1280 blocks, 1280 % 8 == 0 -> bijective
    const int g0  = blockIdx.z * gridDim.x + blockIdx.x;
    const int rid = (g0 & 7) * 160 + (g0 >> 3);
    const int b   = rid / 10;
    const int n0  = (rid % 10) * 64;

    const int tid = threadIdx.x;
    const int lane = tid & 63, w = tid >> 6;
    const int lr = lane & 15, lg = lane >> 4, lk = lg * 8;
    const int brow = tid >> 2, bseg = tid & 3;

    const unsigned short* Zqhb = Zqh + (size_t)b * NzP * C;
    const unsigned short* Zqlb = Zql + (size_t)b * NzP * C;
    const unsigned short* Zg2b = Zg2 + (size_t)b * C * NzP;

    if (tid < 192) Us[tid] = U[(size_t)b * NzP + tid];

    // ================= sim phase =================
    f32x4 sacc[12];
    #pragma unroll
    for (int j = 0; j < 12; ++j)
        #pragma unroll
        for (int e = 0; e < 4; ++e) sacc[j][e] = 0.f;

    for (int kc = 0; kc < C; kc += 32) {
        // stage xf tile from f32, split hi/lo
        {
            const int gn = min(n0 + brow, Nx - 1);
            const float* src = Xf + ((size_t)b * C + kc + bseg * 8) * Nx + gn;
            unsigned short h[8], l[8];
            #pragma unroll
            for (int e = 0; e < 8; ++e) {
                float v = src[(size_t)e * Nx];
                h[e] = f2bf(v);
                l[e] = f2bf(v - bf2f(h[e]));
            }
            uint4 ph, pl;
            ph.x = (unsigned)h[0] | ((unsigned)h[1] << 16);
            ph.y = (unsigned)h[2] | ((unsigned)h[3] << 16);
            ph.z = (unsigned)h[4] | ((unsigned)h[5] << 16);
            ph.w = (unsigned)h[6] | ((unsigned)h[7] << 16);
            pl.x = (unsigned)l[0] | ((unsigned)l[1] << 16);
            pl.y = (unsigned)l[2] | ((unsigned)l[3] << 16);
            pl.z = (unsigned)l[4] | ((unsigned)l[5] << 16);
            pl.w = (unsigned)l[6] | ((unsigned)l[7] << 16);
            *(uint4*)&XFh[brow * 40 + bseg * 8] = ph;
            *(uint4*)&XFl[brow * 40 + bseg * 8] = pl;
        }
        // stage zq' hi/lo (192 rows x 32 k) — 3 slots/thread
        #pragma unroll
        for (int i = 0; i < 3; ++i) {
            const int slot = tid + 256 * i;
            const int r = slot >> 2, s = slot & 3;
            const int gk = kc + s * 8;
            *(int4*)&Bzh[r * 40 + s * 8] = *(const int4*)&Zqhb[(size_t)r * C + gk];
            *(int4*)&Bzl[r * 40 + s * 8] = *(const int4*)&Zqlb[(size_t)r * C + gk];
        }
        __syncthreads();

        bf16x8 a0h = *(const bf16x8*)&XFh[(w * 16 + lr) * 40 + lk];
        bf16x8 a0l = *(const bf16x8*)&XFl[(w * 16 + lr) * 40 + lk];
        #pragma unroll
        for (int j = 0; j < 12; ++j) {
            bf16x8 bh = *(const bf16x8*)&Bzh[(j * 16 + lr) * 40 + lk];
            bf16x8 bl = *(const bf16x8*)&Bzl[(j * 16 + lr) * 40 + lk];
            sacc[j] = __builtin_amdgcn_mfma_f32_16x16x32_bf16(a0l, bh, sacc[j], 0, 0, 0);
            sacc[j] = __builtin_amdgcn_mfma_f32_16x16x32_bf16(a0h, bl, sacc[j], 0, 0, 0);
            sacc[j] = __builtin_amdgcn_mfma_f32_16x16x32_bf16(a0h, bh, sacc[j], 0, 0, 0);
        }
        __syncthreads();
    }

    // add u[m], mask padded m
    #pragma unroll
    for (int j = 0; j < 12; ++j) {
        const int m = j * 16 + lr;
        const float uv = Us[m];
        const bool bad = (m >= Nz);
        #pragma unroll
        for (int q = 0; q < 4; ++q)
            sacc[j][q] = bad ? -1e30f : (sacc[j][q] + uv);
    }

    // row max over 12 regs + 16 lanes (m dimension)
    f32x4 mx = sacc[0];
    #pragma unroll
    for (int j = 1; j < 12; ++j)
        #pragma unroll
        for (int q = 0; q < 4; ++q) mx[q] = fmaxf(mx[q], sacc[j][q]);
    #pragma unroll
    for (int off = 1; off < 16; off <<= 1)
        #pragma unroll
        for (int q = 0; q < 4; ++q) mx[q] = fmaxf(mx[q], __shfl_xor(mx[q], off));

    // Newton on tau
    f32x4 tau;
    #pragma unroll
    for (int q = 0; q < 4; ++q) tau[q] = mx[q] - 1.0f;

    for (int it = 0; it < 16; ++it) {
        f32x4 s, cnt;
        #pragma unroll
        for (int q = 0; q < 4; ++q) { s[q] = 0.f; cnt[q] = 0.f; }
        #pragma unroll
        for (int j = 0; j < 12; ++j)
            #pragma unroll
            for (int q = 0; q < 4; ++q)
                if (sacc[j][q] > tau[q]) { s[q] += sacc[j][q]; cnt[q] += 1.f; }
        #pragma unroll
        for (int off = 1; off < 16; off <<= 1)
            #pragma unroll
            for (int q = 0; q < 4; ++q) {
                s[q]   += __shfl_xor(s[q], off);
                cnt[q] += __shfl_xor(cnt[q], off);
            }
        bool adv = false;
        #pragma unroll
        for (int q = 0; q < 4; ++q) {
            float nt = (s[q] - 1.0f) / cnt[q];
            if (nt > tau[q]) { tau[q] = nt; adv = true; }
        }
        if (!__any(adv ? 1 : 0)) break;
    }

    // scores -> Ssc LDS (overwrites sim staging; safe after last sync)
    #pragma unroll
    for (int q = 0; q < 4; ++q) {
        const int n = w * 16 + 4 * lg + q;
        #pragma unroll
        for (int j = 0; j < 12; ++j) {
            const int m = j * 16 + lr;
            float sv = (m < Nz) ? fmaxf(sacc[j][q] - tau[q], 0.f) : 0.f;
            Ssc[n * 200 + m] = f2bf(sv);
        }
    }

    // ================= G phase =================
    f32x4 acc[4][4];
    #pragma unroll
    for (int i = 0; i < 4; ++i)
        #pragma unroll
        for (int j = 0; j < 4; ++j)
            #pragma unroll
            for (int e = 0; e < 4; ++e) acc[i][j][e] = 0.f;

    for (int kc = 0; kc < C; kc += 32) {
        #pragma unroll
        for (int s = 0; s < 4; ++s) {
            int e = tid + 256 * s;
            int row = e >> 2, seg = e & 3;
            *(int4*)&As[row * 40 + seg * 8] = *(const int4*)&Wg[(size_t)row * C + kc + seg * 8];
        }
        {
            const int gn = min(n0 + brow, Nx - 1);
            const float* src = Xf + ((size_t)b * C + kc + bseg * 8) * Nx + gn;
            unsigned short h[8];
            #pragma unroll
            for (int e = 0; e < 8; ++e) h[e] = f2bf(src[(size_t)e * Nx]);
            uint4 ph;
            ph.x = (unsigned)h[0] | ((unsigned)h[1] << 16);
            ph.y = (unsigned)h[2] | ((unsigned)h[3] << 16);
            ph.z = (unsigned)h[4] | ((unsigned)h[5] << 16);
            ph.w = (unsigned)h[6] | ((unsigned)h[7] << 16);
            *(uint4*)&XFg[brow * 40 + bseg * 8] = ph;
        }
        __syncthreads();

        bf16x8 a[4], bfr[4];
        #pragma unroll
        for (int i = 0; i < 4; ++i) a[i]   = *(const bf16x8*)&As[(w * 64 + i * 16 + lr) * 40 + lk];
        #pragma unroll
        for (int j = 0; j < 4; ++j) bfr[j] = *(const bf16x8*)&XFg[(j * 16 + lr) * 40 + lk];
        #pragma unroll
        for (int i = 0; i < 4; ++i)
            #pragma unroll
            for (int j = 0; j < 4; ++j)
                acc[i][j] = __builtin_amdgcn_mfma_f32_16x16x32_bf16(a[i], bfr[j], acc[i][j], 0, 0, 0);
        __syncthreads();
    }

    // G epilogue: bn_relu -> XG[n][o] bf16 (overwrites XFg; safe after sync)
    #pragma unroll
    for (int i = 0; i < 4; ++i) {
        const int ob = w * 64 + i * 16 + lg * 4;
        float inv[4], sh[4], bi[4];
        #pragma unroll
        for (int r = 0; r < 4; ++r) {
            int o = ob + r;
            float iv = g_gamma[o] * rsqrtf(g_var[o] + EPS);
            inv[r] = iv; sh[r] = g_beta[o] - g_mean[o] * iv; bi[r] = bg[o];
        }
        #pragma unroll
        for (int j = 0; j < 4; ++j) {
            unsigned short h[4];
            #pragma unroll
            for (int r = 0; r < 4; ++r)
                h[r] = f2bf(fmaxf(fmaf(acc[i][j][r] + bi[r], inv[r], sh[r]), 0.f));
            uint2 pk;
            pk.x = (unsigned)h[0] | ((unsigned)h[1] << 16);
            pk.y = (unsigned)h[2] | ((unsigned)h[3] << 16);
            *(uint2*)&XG[(j * 16 + lr) * 264 + ob] = pk;
        }
    }
    #pragma unroll
    for (int i = 0; i < 4; ++i)
        #pragma unroll
        for (int j = 0; j < 4; ++j)
            #pragma unroll
            for (int e = 0; e < 4; ++e) acc[i][j][e] = 0.f;
    __syncthreads();

    // ================= P1: zg2 x score (K=192, B from LDS) =================
    for (int kc = 0; kc < NzP; kc += 32) {
        #pragma unroll
        for (int s = 0; s < 4; ++s) {
            int e = tid + 256 * s;
            int row = e >> 2, seg = e & 3;
            *(int4*)&As[row * 40 + seg * 8] = *(const int4*)&Zg2b[(size_t)row * NzP + kc + seg * 8];
        }
        __syncthreads();

        bf16x8 a[4], bfr[4];
        #pragma unroll
        for (int i = 0; i < 4; ++i) a[i]   = *(const bf16x8*)&As[(w * 64 + i * 16 + lr) * 40 + lk];
        #pragma unroll
        for (int j = 0; j < 4; ++j) bfr[j] = *(const bf16x8*)&Ssc[(j * 16 + lr) * 200 + kc + lk];
        #pragma unroll
        for (int i = 0; i < 4; ++i)
            #pragma unroll
            for (int j = 0; j < 4; ++j)
                acc[i][j] = __builtin_amdgcn_mfma_f32_16x16x32_bf16(a[i], bfr[j], acc[i][j], 0, 0, 0);
        __syncthreads();
    }

    // ================= P2: Wf2 x XG (K=256, B from LDS) =================
    for (int kc = 0; kc < C; kc += 32) {
        #pragma unroll
        for (int s = 0; s < 4; ++s) {
            int e = tid + 256 * s;
            int row = e >> 2, seg = e & 3;
            *(int4*)&As[row * 40 + seg * 8] = *(const int4*)&Wf2[(size_t)row * 512 + kc + seg * 8];
        }
        __syncthreads();

        bf16x8 a[4], bfr[4];
        #pragma unroll
        for (int i = 0; i < 4; ++i) a[i]   = *(const bf16x8*)&As[(w * 64 + i * 16 + lr) * 40 + lk];
        #pragma unroll
        for (int j = 0; j < 4; ++j) bfr[j] = *(const bf16x8*)&XG[(j * 16 + lr) * 264 + kc + lk];
        #pragma unroll
        for (int i = 0; i < 4; ++i)
            #pragma unroll
            for (int j = 0; j < 4; ++j)
                acc[i][j] = __builtin_amdgcn_mfma_f32_16x16x32_bf16(a[i], bfr[j], acc[i][j], 0, 0, 0);
        __syncthreads();
    }

    // final epilogue: bn_relu(f) -> out f32 [b][256][Nx]
    #pragma unroll
    for (int i = 0; i < 4; ++i) {
        const int ob = w * 64 + i * 16 + lg * 4;
        float inv[4], sh[4], bi[4];
        #pragma unroll
        for (int r = 0; r < 4; ++r) {
            int o = ob + r;
            float iv = f_gamma[o] * rsqrtf(f_var[o] + EPS);
            inv[r] = iv; sh[r] = f_beta[o] - f_mean[o] * iv; bi[r] = bf[o];
        }
        #pragma unroll
        for (int j = 0; j < 4; ++j) {
            const int gn = n0 + j * 16 + lr;
            if (gn < Nx) {
                #pragma unroll
                for (int r = 0; r < 4; ++r) {
                    float v = fmaxf(fmaf(acc[i][j][r] + bi[r], inv[r], sh[r]), 0.f);
                    out[((size_t)b * C + ob + r) * Nx + gn] = v;
                }
            }
        }
    }
}

// ---------------------------------------------------------------------------
extern "C" void kernel_launch(void* const* d_in, const int* in_sizes, int n_in,
                              void* d_out, int out_size, void* d_ws, size_t ws_size,
                              hipStream_t stream)
{
    const float* zf      = (const float*)d_in[0];
    const float* xf      = (const float*)d_in[1];
    const float* Wq      = (const float*)d_in[2];
    const float* bq      = (const float*)d_in[3];
    const float* Ws_     = (const float*)d_in[4];
    const float* bs      = (const float*)d_in[5];
    const float* Wg      = (const float*)d_in[6];
    const float* bg      = (const float*)d_in[7];
    const float* g_gamma = (const float*)d_in[8];
    const float* g_beta  = (const float*)d_in[9];
    const float* g_mean  = (const float*)d_in[10];
    const float* g_var   = (const float*)d_in[11];
    const float* Wf      = (const float*)d_in[12];
    const float* bf_     = (const float*)d_in[13];
    const float* f_gamma = (const float*)d_in[14];
    const float* f_beta  = (const float*)d_in[15];
    const float* f_mean  = (const float*)d_in[16];
    const float* f_var   = (const float*)d_in[17];
    float* out = (float*)d_out;

    typedef unsigned short u16;
    char* ws = (char*)d_ws;
    u16*   zfT_hi = (u16*)(ws);                   //  11,075,584
    u16*   zfT_lo = (u16*)(ws +  11075584);       //  11,075,584
    u16*   zqT_hi = (u16*)(ws +  22151168);       //  12,582,912
    u16*   zqT_lo = (u16*)(ws +  34734080);       //  12,582,912
    u16*   zf_gT  = (u16*)(ws +  47316992);       //  12,582,912
    u16*   zg2    = (u16*)(ws +  59899904);       //  12,582,912
    float* U      = (float*)(ws +  72482816);     //      98,304
    u16*   Mhi    = (u16*)(ws +  72581120);       //     131,072
    u16*   Mlo    = (u16*)(ws +  72712192);       //     131,072
    u16*   Wg_bf  = (u16*)(ws +  72843264);       //     131,072
    u16*   Wf_bf  = (u16*)(ws +  72974336);       //     262,144
    float* wv     = (float*)(ws +  73236480);     //       1,024
    float* wu     = (float*)(ws +  73237504);     //       1,024
    float* c0     = (float*)(ws +  73238528);     //         256

    dim3 blk(256);
    const int gx_x = (Nx + 63) / 64;   // 10
    const int gx_z = NzP / 64;         // 3

    // small precomputes
    cvt_wgf<<<dim3((C * 2 * C + 255) / 256), blk, 0, stream>>>(Wg, Wf, Wg_bf, Wf_bf);
    prep_small<<<dim3(1), blk, 0, stream>>>(Wq, Ws_, bq, bs, wv, wu, c0);
    m_gemm<<<dim3(4, 4), blk, 0, stream>>>(Wq, Ws_, Mhi, Mlo);
    bias_u<<<dim3(Bb), blk, 0, stream>>>(zf, wu, c0, U);

    // z-side transpose/split
    x2t_split<<<dim3((Nz + 63) / 64, C / 64, Bb), blk, 0, stream>>>(zf, zfT_hi, zfT_lo, Nz);

    // zq' = M zf + wv  (split)
    mfma_split<<<dim3(gx_z, C / 64, Bb), blk, 0, stream>>>(
        Mhi, Mlo, 0, zfT_hi, zfT_lo, wv, zqT_hi, zqT_lo, Nz, NzP, C, C);

    // zf_g = bn_relu(Wg . zf)
    mfma_conv<0, 1><<<dim3(gx_z, C / 64, Bb), blk, 0, stream>>>(
        Wg_bf, C, 0, zfT_hi, bg, g_gamma, g_beta, g_mean, g_var,
        zf_gT, Nz, NzP, C, C);

    // zg2 = Wf1 . zf_g   -> [b][C][NzP] bf16
    mfma_conv<1, 0><<<dim3(gx_z, C / 64, Bb), blk, 0, stream>>>(
        Wf_bf, 2 * C, 0, zf_gT, nullptr, nullptr, nullptr, nullptr, nullptr,
        zg2, NzP, NzP, C, C);

    // x-side megakernel: sim + sparsemax + g-conv + final conv
    mega_x<<<dim3(gx_x, 1, Bb), blk, 0, stream>>>(
        xf, zqT_hi, zqT_lo, Wg_bf, zg2, Wf_bf + C, U,
        bg, g_gamma, g_beta, g_mean, g_var,
        bf_, f_gamma, f_beta, f_mean, f_var, out);
}